// Round 1
// baseline (645.963 us; speedup 1.0000x reference)
//
#include <hip/hip_runtime.h>
#include <cmath>

#define BB 8
#define NN 5000
#define EE 80000
#define NODE_IN 32
#define EDGE_IN 16
#define HIDDEN 128
#define EMBED 64
#define BN (BB*NN)     // 40000
#define BE (BB*EE)     // 640000

__device__ __forceinline__ float waveSum(float v){
  #pragma unroll
  for(int o=32;o;o>>=1) v += __shfl_xor(v,o);
  return v;
}
__device__ __forceinline__ float waveMax(float v){
  #pragma unroll
  for(int o=32;o;o>>=1) v = fmaxf(v,__shfl_xor(v,o));
  return v;
}

// K1: w_ae0[16] = We0 @ ae0, w_ae1[16] = We1 @ ae1
__global__ void k_wae(const float* We0, const float* ae0,
                      const float* We1, const float* ae1, float* wae){
  int t = threadIdx.x;
  if(t < 16){
    float a = 0.f;
    for(int k=0;k<HIDDEN;k++) a += We0[t*HIDDEN+k]*ae0[k];
    wae[t] = a;
  } else if(t < 32){
    int j = t-16;
    float a = 0.f;
    for(int k=0;k<EMBED;k++) a += We1[j*EMBED+k]*ae1[k];
    wae[16+j] = a;
  }
}

// K2: LayerNorm(node_x) -> h0 = nx@W0, s0 = h0.asrc, d0 = h0.adst
__launch_bounds__(256)
__global__ void k_node(const float* __restrict__ x, const float* __restrict__ g,
                       const float* __restrict__ bb, const float* __restrict__ W,
                       const float* __restrict__ asrc, const float* __restrict__ adst,
                       float* __restrict__ H0o, float* __restrict__ S0o, float* __restrict__ D0o){
  __shared__ float Wl[NODE_IN*HIDDEN];   // 16 KB
  __shared__ float as[HIDDEN], ad[HIDDEN];
  int t = threadIdx.x;
  for(int i=t;i<NODE_IN*HIDDEN;i+=256) Wl[i]=W[i];
  if(t<HIDDEN){ as[t]=asrc[t]; ad[t]=adst[t]; }
  __syncthreads();
  int w = t>>6, lane = t&63;
  float gl = (lane<NODE_IN)? g[lane] : 0.f;
  float bl = (lane<NODE_IN)? bb[lane] : 0.f;
  float asl0 = as[lane], asl1 = as[lane+64];
  float adl0 = ad[lane], adl1 = ad[lane+64];
  for(int nb = blockIdx.x; nb < BN/4; nb += gridDim.x){
    int n = nb*4 + w;
    float xv = (lane<NODE_IN)? x[n*NODE_IN+lane] : 0.f;
    float s  = waveSum(xv);
    float s2 = waveSum(xv*xv);
    float mu = s*(1.f/NODE_IN);
    float var = s2*(1.f/NODE_IN) - mu*mu;
    float inv = 1.0f / sqrtf(var + 1e-5f);
    float nx = (lane<NODE_IN)? ((xv-mu)*inv*gl + bl) : 0.f;
    float a0=0.f, a1=0.f;
    #pragma unroll
    for(int j=0;j<NODE_IN;j++){
      float r = __shfl(nx, j);
      a0 += r*Wl[j*HIDDEN+lane];
      a1 += r*Wl[j*HIDDEN+lane+64];
    }
    H0o[n*HIDDEN+lane]    = a0;
    H0o[n*HIDDEN+lane+64] = a1;
    float sv = waveSum(a0*asl0 + a1*asl1);
    float dv = waveSum(a0*adl0 + a1*adl1);
    if(lane==0){ S0o[n]=sv; D0o[n]=dv; }
  }
}

// K3: LayerNorm(edge_attr) -> ea (fp32, stored), e0 = ea.w_ae0, e1 = ea.w_ae1
__launch_bounds__(256)
__global__ void k_edge(const float* __restrict__ ein, const float* __restrict__ g,
                       const float* __restrict__ bb, const float* __restrict__ wae,
                       float* __restrict__ EAo, float* __restrict__ E0o, float* __restrict__ E1o){
  int ge = blockIdx.x*256 + threadIdx.x;   // < BE exactly
  float v[EDGE_IN];
  const float4* p = (const float4*)(ein + (size_t)ge*EDGE_IN);
  float4 q0=p[0], q1=p[1], q2=p[2], q3=p[3];
  v[0]=q0.x; v[1]=q0.y; v[2]=q0.z; v[3]=q0.w;
  v[4]=q1.x; v[5]=q1.y; v[6]=q1.z; v[7]=q1.w;
  v[8]=q2.x; v[9]=q2.y; v[10]=q2.z; v[11]=q2.w;
  v[12]=q3.x; v[13]=q3.y; v[14]=q3.z; v[15]=q3.w;
  float s=0.f, s2=0.f;
  #pragma unroll
  for(int j=0;j<EDGE_IN;j++){ s += v[j]; s2 += v[j]*v[j]; }
  float mu = s*(1.f/EDGE_IN);
  float var = s2*(1.f/EDGE_IN) - mu*mu;
  float inv = 1.0f / sqrtf(var + 1e-5f);
  float e0=0.f, e1=0.f;
  #pragma unroll
  for(int j=0;j<EDGE_IN;j++){
    float nv = (v[j]-mu)*inv*g[j] + bb[j];
    v[j] = nv;
    e0 += nv*wae[j];
    e1 += nv*wae[16+j];
  }
  float4* q = (float4*)(EAo + (size_t)ge*EDGE_IN);
  q[0] = make_float4(v[0],v[1],v[2],v[3]);
  q[1] = make_float4(v[4],v[5],v[6],v[7]);
  q[2] = make_float4(v[8],v[9],v[10],v[11]);
  q[3] = make_float4(v[12],v[13],v[14],v[15]);
  E0o[ge]=e0; E1o[ge]=e1;
}

// K4b: histogram of dst
__global__ void k_count(const int* __restrict__ ei, int* __restrict__ cnt){
  int e = blockIdx.x*256 + threadIdx.x;
  if(e < EE) atomicAdd(&cnt[ei[EE+e]], 1);
}

// K4c: exclusive scan of 5000 counts -> offsets; cursor := offsets
__launch_bounds__(1024)
__global__ void k_scan(int* __restrict__ off, int* __restrict__ cur){
  __shared__ int part[1024];
  int t = threadIdx.x;
  int loc[5]; int s=0;
  int base = t*5;
  #pragma unroll
  for(int k=0;k<5;k++){ int idx=base+k; int c=(idx<NN)? cur[idx]:0; loc[k]=s; s+=c; }
  part[t]=s;
  __syncthreads();
  for(int o=1;o<1024;o<<=1){
    int v = (t>=o)? part[t-o] : 0;
    __syncthreads();
    part[t] += v;
    __syncthreads();
  }
  int pre = (t>0)? part[t-1] : 0;
  #pragma unroll
  for(int k=0;k<5;k++){
    int idx=base+k;
    if(idx<NN){ int o2 = pre+loc[k]; off[idx]=o2; cur[idx]=o2; }
  }
  if(t==0) off[NN] = EE;
}

// K4d: scatter edges into CSR (by dst)
__global__ void k_fill(const int* __restrict__ ei, int* __restrict__ cur,
                       int* __restrict__ csrc, int* __restrict__ ceid){
  int e = blockIdx.x*256 + threadIdx.x;
  if(e < EE){
    int d = ei[EE+e];
    int pos = atomicAdd(&cur[d], 1);
    csrc[pos] = ei[e];
    ceid[pos] = e;
  }
}

// K5: GAT0 aggregation (segment softmax over CSR) + bias + ELU. 4 waves/block, 1 dst node per wave.
__launch_bounds__(256)
__global__ void k_gat0(const float* __restrict__ H0, const float* __restrict__ S0,
                       const float* __restrict__ D0, const float* __restrict__ E0,
                       const int* __restrict__ off, const int* __restrict__ csrc,
                       const int* __restrict__ ceid, const float* __restrict__ bias,
                       float* __restrict__ out){
  int t = threadIdx.x, w = t>>6, lane = t&63;
  int gid = blockIdx.x*4 + w;            // < BN
  int b = gid / NN;
  int n = gid - b*NN;
  int base = off[n], deg = off[n+1]-base;
  const float* s0b = S0 + b*NN;
  const float* e0b = E0 + b*EE;
  const float* h0b = H0 + (size_t)b*NN*HIDDEN;
  float dv = D0[gid];
  float acc0=0.f, acc1=0.f;
  if(deg > 0){
    if(deg <= 64){
      float lg = -INFINITY; int sidx = 0;
      if(lane < deg){
        sidx = csrc[base+lane];
        int eid = ceid[base+lane];
        float xx = s0b[sidx] + dv + e0b[eid];
        lg = xx>0.f ? xx : 0.2f*xx;
      }
      float m = waveMax(lg);
      float ex = (lane<deg)? __expf(lg-m) : 0.f;
      float den = waveSum(ex);
      float al = ex / (den + 1e-16f);
      for(int i=0;i<deg;i++){
        float a = __shfl(al, i);
        int  s = __shfl(sidx, i);
        const float* hp = h0b + (size_t)s*HIDDEN;
        acc0 += a*hp[lane];
        acc1 += a*hp[lane+64];
      }
    } else {
      float m = -INFINITY;
      for(int i=lane;i<deg;i+=64){
        float xx = s0b[csrc[base+i]] + dv + e0b[ceid[base+i]];
        xx = xx>0.f ? xx : 0.2f*xx;
        m = fmaxf(m, xx);
      }
      m = waveMax(m);
      float den = 0.f;
      for(int i=lane;i<deg;i+=64){
        float xx = s0b[csrc[base+i]] + dv + e0b[ceid[base+i]];
        xx = xx>0.f ? xx : 0.2f*xx;
        den += __expf(xx-m);
      }
      den = waveSum(den) + 1e-16f;
      for(int i=0;i<deg;i++){
        int s = csrc[base+i];
        float xx = s0b[s] + dv + e0b[ceid[base+i]];
        xx = xx>0.f ? xx : 0.2f*xx;
        float a = __expf(xx-m)/den;
        const float* hp = h0b + (size_t)s*HIDDEN;
        acc0 += a*hp[lane];
        acc1 += a*hp[lane+64];
      }
    }
  }
  float v0 = acc0 + bias[lane];
  float v1 = acc1 + bias[lane+64];
  v0 = v0>0.f ? v0 : (__expf(v0)-1.f);
  v1 = v1>0.f ? v1 : (__expf(v1)-1.f);
  out[(size_t)gid*HIDDEN+lane]    = v0;
  out[(size_t)gid*HIDDEN+lane+64] = v1;
}

// K6: h1 = helu @ W1g (128->64), s1 = h1.asrc1, d1 = h1.adst1
__launch_bounds__(256)
__global__ void k_gat1prep(const float* __restrict__ HELU, const float* __restrict__ W,
                           const float* __restrict__ asrc, const float* __restrict__ adst,
                           float* __restrict__ H1o, float* __restrict__ S1o, float* __restrict__ D1o){
  __shared__ float Wl[HIDDEN*EMBED];   // 32 KB
  __shared__ float as[EMBED], ad[EMBED];
  int t = threadIdx.x;
  for(int i=t;i<HIDDEN*EMBED;i+=256) Wl[i]=W[i];
  if(t<EMBED){ as[t]=asrc[t]; ad[t]=adst[t]; }
  __syncthreads();
  int w = t>>6, lane = t&63;
  float asl = as[lane], adl = ad[lane];
  for(int nb = blockIdx.x; nb < BN/4; nb += gridDim.x){
    int n = nb*4 + w;
    float r0 = HELU[(size_t)n*HIDDEN+lane];
    float r1 = HELU[(size_t)n*HIDDEN+lane+64];
    float acc = 0.f;
    #pragma unroll
    for(int j=0;j<64;j++){
      float rj = __shfl(r0, j);
      acc += rj*Wl[j*EMBED+lane];
    }
    #pragma unroll
    for(int j=0;j<64;j++){
      float rj = __shfl(r1, j);
      acc += rj*Wl[(64+j)*EMBED+lane];
    }
    H1o[(size_t)n*EMBED+lane] = acc;
    float sv = waveSum(acc*asl);
    float dvv = waveSum(acc*adl);
    if(lane==0){ S1o[n]=sv; D1o[n]=dvv; }
  }
}

// K7: GAT1 aggregation -> node_emb (no activation)
__launch_bounds__(256)
__global__ void k_gat1(const float* __restrict__ H1, const float* __restrict__ S1,
                       const float* __restrict__ D1, const float* __restrict__ E1,
                       const int* __restrict__ off, const int* __restrict__ csrc,
                       const int* __restrict__ ceid, const float* __restrict__ bias,
                       float* __restrict__ out){
  int t = threadIdx.x, w = t>>6, lane = t&63;
  int gid = blockIdx.x*4 + w;
  int b = gid / NN;
  int n = gid - b*NN;
  int base = off[n], deg = off[n+1]-base;
  const float* s1b = S1 + b*NN;
  const float* e1b = E1 + b*EE;
  const float* h1b = H1 + (size_t)b*NN*EMBED;
  float dv = D1[gid];
  float acc = 0.f;
  if(deg > 0){
    if(deg <= 64){
      float lg = -INFINITY; int sidx = 0;
      if(lane < deg){
        sidx = csrc[base+lane];
        int eid = ceid[base+lane];
        float xx = s1b[sidx] + dv + e1b[eid];
        lg = xx>0.f ? xx : 0.2f*xx;
      }
      float m = waveMax(lg);
      float ex = (lane<deg)? __expf(lg-m) : 0.f;
      float den = waveSum(ex);
      float al = ex / (den + 1e-16f);
      for(int i=0;i<deg;i++){
        float a = __shfl(al, i);
        int  s = __shfl(sidx, i);
        acc += a*h1b[(size_t)s*EMBED + lane];
      }
    } else {
      float m = -INFINITY;
      for(int i=lane;i<deg;i+=64){
        float xx = s1b[csrc[base+i]] + dv + e1b[ceid[base+i]];
        xx = xx>0.f ? xx : 0.2f*xx;
        m = fmaxf(m, xx);
      }
      m = waveMax(m);
      float den = 0.f;
      for(int i=lane;i<deg;i+=64){
        float xx = s1b[csrc[base+i]] + dv + e1b[ceid[base+i]];
        xx = xx>0.f ? xx : 0.2f*xx;
        den += __expf(xx-m);
      }
      den = waveSum(den) + 1e-16f;
      for(int i=0;i<deg;i++){
        int s = csrc[base+i];
        float xx = s1b[s] + dv + e1b[ceid[base+i]];
        xx = xx>0.f ? xx : 0.2f*xx;
        float a = __expf(xx-m)/den;
        acc += a*h1b[(size_t)s*EMBED + lane];
      }
    }
  }
  out[(size_t)gid*EMBED + lane] = acc + bias[lane];
}

// K8: per-graph mean/max pooling -> ctx[b, 128]
__launch_bounds__(256)
__global__ void k_pool(const float* __restrict__ EMBp, float* __restrict__ CTX){
  int b = blockIdx.x;
  int t = threadIdx.x;
  int dim = t & 63, chunk = t >> 6;
  float sm = 0.f, mx = -INFINITY;
  int n0 = chunk*(NN/4), n1 = n0 + NN/4;
  for(int n=n0;n<n1;n++){
    float v = EMBp[((size_t)(b*NN+n))*EMBED + dim];
    sm += v; mx = fmaxf(mx, v);
  }
  __shared__ float ssum[256], smax[256];
  ssum[t]=sm; smax[t]=mx;
  __syncthreads();
  if(t < 64){
    float S = ssum[t]+ssum[t+64]+ssum[t+128]+ssum[t+192];
    float M = fmaxf(fmaxf(smax[t],smax[t+64]), fmaxf(smax[t+128],smax[t+192]));
    CTX[b*128+t]    = S*(1.f/NN);
    CTX[b*128+64+t] = M;
  }
}

// K9: ctx_proj[b] = b1 + ctx[b] @ W1[144:272]
__launch_bounds__(128)
__global__ void k_ctxp(const float* __restrict__ CTX, const float* __restrict__ W1,
                       const float* __restrict__ b1, float* __restrict__ CTXP){
  int b = blockIdx.x, c = threadIdx.x;
  __shared__ float cl[128];
  cl[c] = CTX[b*128+c];
  __syncthreads();
  float a = b1[c];
  for(int j=0;j<128;j++) a += cl[j]*W1[(144+j)*HIDDEN + c];
  CTXP[b*128+c] = a;
}

// K10: p_src = emb @ W1[0:64], p_dst = emb @ W1[64:128]
__launch_bounds__(256)
__global__ void k_pp(const float* __restrict__ EMBp, const float* __restrict__ W1,
                     float* __restrict__ PSRC, float* __restrict__ PDST){
  __shared__ float Wl[64*HIDDEN];   // 32 KB
  int t = threadIdx.x, w = t>>6, lane = t&63;
  for(int i=t;i<64*HIDDEN;i+=256) Wl[i]=W1[i];
  __syncthreads();
  for(int nb = blockIdx.x; nb < BN/4; nb += gridDim.x){
    int n = nb*4 + w;
    float r = EMBp[(size_t)n*EMBED+lane];
    float a0=0.f, a1=0.f;
    #pragma unroll
    for(int j=0;j<64;j++){
      float rj = __shfl(r, j);
      a0 += rj*Wl[j*HIDDEN+lane];
      a1 += rj*Wl[j*HIDDEN+lane+64];
    }
    PSRC[(size_t)n*HIDDEN+lane]    = a0;
    PSRC[(size_t)n*HIDDEN+lane+64] = a1;
  }
  __syncthreads();
  for(int i=t;i<64*HIDDEN;i+=256) Wl[i]=W1[64*HIDDEN + i];
  __syncthreads();
  for(int nb = blockIdx.x; nb < BN/4; nb += gridDim.x){
    int n = nb*4 + w;
    float r = EMBp[(size_t)n*EMBED+lane];
    float a0=0.f, a1=0.f;
    #pragma unroll
    for(int j=0;j<64;j++){
      float rj = __shfl(r, j);
      a0 += rj*Wl[j*HIDDEN+lane];
      a1 += rj*Wl[j*HIDDEN+lane+64];
    }
    PDST[(size_t)n*HIDDEN+lane]    = a0;
    PDST[(size_t)n*HIDDEN+lane+64] = a1;
  }
}

// K11: per-edge MLP: q = W2 . relu(ctxp[b] + p_src[gs] + p_dst[gd] + ef@W1e) + b2
__launch_bounds__(256)
__global__ void k_final(const float* __restrict__ EA, const int* __restrict__ ei,
                        const float* __restrict__ PSRC, const float* __restrict__ PDST,
                        const float* __restrict__ CTXP, const float* __restrict__ W1,
                        const float* __restrict__ W2, const float* __restrict__ b2,
                        float* __restrict__ out){
  __shared__ float Wl[EDGE_IN*HIDDEN];   // 8 KB (rows 128..143)
  __shared__ float w2[HIDDEN];
  __shared__ float cp[BB*128];           // 4 KB
  int t = threadIdx.x;
  for(int i=t;i<EDGE_IN*HIDDEN;i+=256) Wl[i]=W1[128*HIDDEN + i];
  if(t<HIDDEN) w2[t]=W2[t];
  for(int i=t;i<BB*128;i+=256) cp[i]=CTXP[i];
  __syncthreads();
  int w = t>>6, lane = t&63;
  int e0 = blockIdx.x*128 + w*32;
  float bias2 = b2[0];
  float myq = 0.f;
  for(int k=0;k<32;k++){
    int ge = e0 + k;
    int b = ge / EE;
    int e = ge - b*EE;
    int gs = b*NN + ei[e];
    int gd = b*NN + ei[EE+e];
    float av = (lane<EDGE_IN)? EA[(size_t)ge*EDGE_IN+lane] : 0.f;
    const float* ps = PSRC + (size_t)gs*HIDDEN;
    const float* pd = PDST + (size_t)gd*HIDDEN;
    float h0 = cp[b*128+lane]    + ps[lane]    + pd[lane];
    float h1 = cp[b*128+lane+64] + ps[lane+64] + pd[lane+64];
    #pragma unroll
    for(int j=0;j<EDGE_IN;j++){
      float aj = __shfl(av, j);
      h0 += aj*Wl[j*HIDDEN+lane];
      h1 += aj*Wl[j*HIDDEN+lane+64];
    }
    h0 = fmaxf(h0, 0.f);
    h1 = fmaxf(h1, 0.f);
    float part = h0*w2[lane] + h1*w2[lane+64];
    float q = waveSum(part);
    if(lane==k) myq = q;
  }
  if(lane < 32) out[e0 + lane] = myq + bias2;
}

extern "C" void kernel_launch(void* const* d_in, const int* in_sizes, int n_in,
                              void* d_out, int out_size, void* d_ws, size_t ws_size,
                              hipStream_t stream) {
  const float* node_x   = (const float*)d_in[0];
  const float* edge_attr= (const float*)d_in[1];
  const int*   edge_idx = (const int*)d_in[2];
  const float* ln_ng    = (const float*)d_in[3];
  const float* ln_nb    = (const float*)d_in[4];
  const float* ln_eg    = (const float*)d_in[5];
  const float* ln_eb    = (const float*)d_in[6];
  const float* g0_W     = (const float*)d_in[7];
  const float* g0_We    = (const float*)d_in[8];
  const float* g0_asrc  = (const float*)d_in[9];
  const float* g0_adst  = (const float*)d_in[10];
  const float* g0_ae    = (const float*)d_in[11];
  const float* g0_b     = (const float*)d_in[12];
  const float* g1_W     = (const float*)d_in[13];
  const float* g1_We    = (const float*)d_in[14];
  const float* g1_asrc  = (const float*)d_in[15];
  const float* g1_adst  = (const float*)d_in[16];
  const float* g1_ae    = (const float*)d_in[17];
  const float* g1_b     = (const float*)d_in[18];
  const float* mlp_W1   = (const float*)d_in[19];
  const float* mlp_b1   = (const float*)d_in[20];
  const float* mlp_W2   = (const float*)d_in[21];
  const float* mlp_b2   = (const float*)d_in[22];
  float* out = (float*)d_out;

  // workspace layout (floats)
  float* ws   = (float*)d_ws;
  float* EA   = ws;                       // 10,240,000
  float* E0   = EA   + (size_t)BE*EDGE_IN;// 640,000
  float* E1   = E0   + BE;                // 640,000
  float* H0   = E1   + BE;                // 5,120,000  (reused as PSRC)
  float* HELU = H0   + (size_t)BN*HIDDEN; // 5,120,000  (reused as PDST)
  float* H1   = HELU + (size_t)BN*HIDDEN; // 2,560,000
  float* EMBa = H1   + (size_t)BN*EMBED;  // 2,560,000
  float* S0   = EMBa + (size_t)BN*EMBED;  // 40,000
  float* D0   = S0 + BN;
  float* S1   = D0 + BN;
  float* D1   = S1 + BN;
  float* CTX  = D1 + BN;                  // 1024
  float* CTXP = CTX + 1024;               // 1024
  float* WAE  = CTXP + 1024;              // 32
  int* CSR_OFF = (int*)(WAE + 32);        // 5001
  int* CSR_CUR = CSR_OFF + (NN+1);        // 5000 (counts, then cursor)
  int* CSR_SRC = CSR_CUR + NN;            // 80000
  int* CSR_EID = CSR_SRC + EE;            // 80000
  float* PSRC = H0;
  float* PDST = HELU;

  hipMemsetAsync(CSR_CUR, 0, NN*sizeof(int), stream);
  k_wae<<<1, 64, 0, stream>>>(g0_We, g0_ae, g1_We, g1_ae, WAE);
  k_node<<<1024, 256, 0, stream>>>(node_x, ln_ng, ln_nb, g0_W, g0_asrc, g0_adst, H0, S0, D0);
  k_edge<<<BE/256, 256, 0, stream>>>(edge_attr, ln_eg, ln_eb, WAE, EA, E0, E1);
  k_count<<<(EE+255)/256, 256, 0, stream>>>(edge_idx, CSR_CUR);
  k_scan<<<1, 1024, 0, stream>>>(CSR_OFF, CSR_CUR);
  k_fill<<<(EE+255)/256, 256, 0, stream>>>(edge_idx, CSR_CUR, CSR_SRC, CSR_EID);
  k_gat0<<<BN/4, 256, 0, stream>>>(H0, S0, D0, E0, CSR_OFF, CSR_SRC, CSR_EID, g0_b, HELU);
  k_gat1prep<<<512, 256, 0, stream>>>(HELU, g1_W, g1_asrc, g1_adst, H1, S1, D1);
  k_gat1<<<BN/4, 256, 0, stream>>>(H1, S1, D1, E1, CSR_OFF, CSR_SRC, CSR_EID, g1_b, EMBa);
  k_pool<<<BB, 256, 0, stream>>>(EMBa, CTX);
  k_ctxp<<<BB, 128, 0, stream>>>(CTX, mlp_W1, mlp_b1, CTXP);
  k_pp<<<512, 256, 0, stream>>>(EMBa, mlp_W1, PSRC, PDST);
  k_final<<<BE/128, 256, 0, stream>>>(EA, edge_idx, PSRC, PDST, CTXP, mlp_W1, mlp_W2, mlp_b2, out);
}

// Round 3
// 638.795 us; speedup vs baseline: 1.0112x; 1.0112x over previous
//
#include <hip/hip_runtime.h>
#include <cmath>

#define BB 8
#define NN 5000
#define EE 80000
#define NODE_IN 32
#define EDGE_IN 16
#define HIDDEN 128
#define EMBED 64
#define BN (BB*NN)     // 40000
#define BE (BB*EE)     // 640000

__device__ __forceinline__ float waveSum(float v){
  #pragma unroll
  for(int o=32;o;o>>=1) v += __shfl_xor(v,o);
  return v;
}
__device__ __forceinline__ float waveMax(float v){
  #pragma unroll
  for(int o=32;o;o>>=1) v = fmaxf(v,__shfl_xor(v,o));
  return v;
}
__device__ __forceinline__ unsigned pack_bf2(float a0, float a1){
  unsigned u0 = __float_as_uint(a0), u1 = __float_as_uint(a1);
  unsigned r0 = (u0 + 0x7fffu + ((u0>>16)&1u)) >> 16;
  unsigned r1 = (u1 + 0x7fffu + ((u1>>16)&1u)) & 0xffff0000u;
  return r0 | r1;
}

// K1: w_ae0[16] = We0 @ ae0, w_ae1[16] = We1 @ ae1
__global__ void k_wae(const float* We0, const float* ae0,
                      const float* We1, const float* ae1, float* wae){
  int t = threadIdx.x;
  if(t < 16){
    float a = 0.f;
    for(int k=0;k<HIDDEN;k++) a += We0[t*HIDDEN+k]*ae0[k];
    wae[t] = a;
  } else if(t < 32){
    int j = t-16;
    float a = 0.f;
    for(int k=0;k<EMBED;k++) a += We1[j*EMBED+k]*ae1[k];
    wae[16+j] = a;
  }
}

// K2: LayerNorm(node_x) -> h0 = nx@W0 (natural order), s0, d0
__launch_bounds__(256)
__global__ void k_node(const float* __restrict__ x, const float* __restrict__ g,
                       const float* __restrict__ bb, const float* __restrict__ W,
                       const float* __restrict__ asrc, const float* __restrict__ adst,
                       float* __restrict__ H0o, float* __restrict__ S0o, float* __restrict__ D0o){
  __shared__ float Wl[NODE_IN*HIDDEN];   // 16 KB
  __shared__ float as[HIDDEN], ad[HIDDEN];
  int t = threadIdx.x;
  for(int i=t;i<NODE_IN*HIDDEN;i+=256) Wl[i]=W[i];
  if(t<HIDDEN){ as[t]=asrc[t]; ad[t]=adst[t]; }
  __syncthreads();
  int w = t>>6, lane = t&63;
  float gl = (lane<NODE_IN)? g[lane] : 0.f;
  float bl = (lane<NODE_IN)? bb[lane] : 0.f;
  float asl0 = as[lane], asl1 = as[lane+64];
  float adl0 = ad[lane], adl1 = ad[lane+64];
  for(int nb = blockIdx.x; nb < BN/4; nb += gridDim.x){
    int n = nb*4 + w;
    float xv = (lane<NODE_IN)? x[n*NODE_IN+lane] : 0.f;
    float s  = waveSum(xv);
    float s2 = waveSum(xv*xv);
    float mu = s*(1.f/NODE_IN);
    float var = s2*(1.f/NODE_IN) - mu*mu;
    float inv = 1.0f / sqrtf(var + 1e-5f);
    float nx = (lane<NODE_IN)? ((xv-mu)*inv*gl + bl) : 0.f;
    float a0=0.f, a1=0.f;
    #pragma unroll
    for(int j=0;j<NODE_IN;j++){
      float r = __shfl(nx, j);
      a0 += r*Wl[j*HIDDEN+lane];
      a1 += r*Wl[j*HIDDEN+lane+64];
    }
    H0o[n*HIDDEN+lane]    = a0;
    H0o[n*HIDDEN+lane+64] = a1;
    float sv = waveSum(a0*asl0 + a1*asl1);
    float dv = waveSum(a0*adl0 + a1*adl1);
    if(lane==0){ S0o[n]=sv; D0o[n]=dv; }
  }
}

// K3: LayerNorm(edge_attr) scattered into CSR position order
__launch_bounds__(256)
__global__ void k_edge(const float* __restrict__ ein, const float* __restrict__ g,
                       const float* __restrict__ bb, const float* __restrict__ wae,
                       const int* __restrict__ EPOS,
                       float* __restrict__ EAp, float* __restrict__ E0p, float* __restrict__ E1p){
  int ge = blockIdx.x*256 + threadIdx.x;   // < BE exactly
  int b = ge / EE, e = ge - b*EE;
  int gp = b*EE + EPOS[e];
  float v[EDGE_IN];
  const float4* p = (const float4*)(ein + (size_t)ge*EDGE_IN);
  float4 q0=p[0], q1=p[1], q2=p[2], q3=p[3];
  v[0]=q0.x; v[1]=q0.y; v[2]=q0.z; v[3]=q0.w;
  v[4]=q1.x; v[5]=q1.y; v[6]=q1.z; v[7]=q1.w;
  v[8]=q2.x; v[9]=q2.y; v[10]=q2.z; v[11]=q2.w;
  v[12]=q3.x; v[13]=q3.y; v[14]=q3.z; v[15]=q3.w;
  float s=0.f, s2=0.f;
  #pragma unroll
  for(int j=0;j<EDGE_IN;j++){ s += v[j]; s2 += v[j]*v[j]; }
  float mu = s*(1.f/EDGE_IN);
  float var = s2*(1.f/EDGE_IN) - mu*mu;
  float inv = 1.0f / sqrtf(var + 1e-5f);
  float e0=0.f, e1=0.f;
  #pragma unroll
  for(int j=0;j<EDGE_IN;j++){
    float nv = (v[j]-mu)*inv*g[j] + bb[j];
    v[j] = nv;
    e0 += nv*wae[j];
    e1 += nv*wae[16+j];
  }
  float4* q = (float4*)(EAp + (size_t)gp*EDGE_IN);
  q[0] = make_float4(v[0],v[1],v[2],v[3]);
  q[1] = make_float4(v[4],v[5],v[6],v[7]);
  q[2] = make_float4(v[8],v[9],v[10],v[11]);
  q[3] = make_float4(v[12],v[13],v[14],v[15]);
  E0p[gp]=e0; E1p[gp]=e1;
}

// K4b: histogram of dst
__global__ void k_count(const int* __restrict__ ei, int* __restrict__ cnt){
  int e = blockIdx.x*256 + threadIdx.x;
  if(e < EE) atomicAdd(&cnt[ei[EE+e]], 1);
}

// K4c: exclusive scan of 5000 counts -> offsets; cursor := offsets
__launch_bounds__(1024)
__global__ void k_scan(int* __restrict__ off, int* __restrict__ cur){
  __shared__ int part[1024];
  int t = threadIdx.x;
  int loc[5]; int s=0;
  int base = t*5;
  #pragma unroll
  for(int k=0;k<5;k++){ int idx=base+k; int c=(idx<NN)? cur[idx]:0; loc[k]=s; s+=c; }
  part[t]=s;
  __syncthreads();
  for(int o=1;o<1024;o<<=1){
    int v = (t>=o)? part[t-o] : 0;
    __syncthreads();
    part[t] += v;
    __syncthreads();
  }
  int pre = (t>0)? part[t-1] : 0;
  #pragma unroll
  for(int k=0;k<5;k++){
    int idx=base+k;
    if(idx<NN){ int o2 = pre+loc[k]; off[idx]=o2; cur[idx]=o2; }
  }
  if(t==0) off[NN] = EE;
}

// K4d: scatter edges into CSR (by dst); also dst per pos and inverse perm
__global__ void k_fill(const int* __restrict__ ei, int* __restrict__ cur,
                       int* __restrict__ csrc, int* __restrict__ cdst,
                       int* __restrict__ ceid, int* __restrict__ epos){
  int e = blockIdx.x*256 + threadIdx.x;
  if(e < EE){
    int d = ei[EE+e];
    int pos = atomicAdd(&cur[d], 1);
    csrc[pos] = ei[e];
    cdst[pos] = d;
    ceid[pos] = e;
    epos[e] = pos;
  }
}

// K5: GAT0 aggregation. XCD swizzle: graph = blockIdx&7. float2 H loads, coalesced E.
__launch_bounds__(256)
__global__ void k_gat0(const float* __restrict__ H0, const float* __restrict__ S0,
                       const float* __restrict__ D0, const float* __restrict__ E0p,
                       const int* __restrict__ off, const int* __restrict__ csrc,
                       const float* __restrict__ bias, float* __restrict__ out){
  int t = threadIdx.x, w = t>>6, lane = t&63;
  int b = blockIdx.x & 7, c = blockIdx.x >> 3;
  int n = c*4 + w;                    // node within graph
  int gid = b*NN + n;
  int base = off[n], deg = off[n+1]-base;
  const float* s0b = S0 + b*NN;
  const float* e0b = E0p + b*EE;
  const float2* h0b = (const float2*)(H0 + (size_t)b*NN*HIDDEN);
  float dv = D0[gid];
  float acc0=0.f, acc1=0.f;
  if(deg > 0){
    if(deg <= 64){
      float lg = -INFINITY; int sidx = 0;
      if(lane < deg){
        sidx = csrc[base+lane];
        float xx = s0b[sidx] + dv + e0b[base+lane];
        lg = xx>0.f ? xx : 0.2f*xx;
      }
      float m = waveMax(lg);
      float ex = (lane<deg)? __expf(lg-m) : 0.f;
      float den = waveSum(ex);
      float al = ex / (den + 1e-16f);
      for(int i=0;i<deg;i++){
        float a = __shfl(al, i);
        int  s = __shfl(sidx, i);
        float2 h = h0b[s*64 + lane];
        acc0 += a*h.x;
        acc1 += a*h.y;
      }
    } else {
      float m = -INFINITY;
      for(int i=lane;i<deg;i+=64){
        float xx = s0b[csrc[base+i]] + dv + e0b[base+i];
        xx = xx>0.f ? xx : 0.2f*xx;
        m = fmaxf(m, xx);
      }
      m = waveMax(m);
      float den = 0.f;
      for(int i=lane;i<deg;i+=64){
        float xx = s0b[csrc[base+i]] + dv + e0b[base+i];
        xx = xx>0.f ? xx : 0.2f*xx;
        den += __expf(xx-m);
      }
      den = waveSum(den) + 1e-16f;
      for(int i=0;i<deg;i++){
        int s = csrc[base+i];
        float xx = s0b[s] + dv + e0b[base+i];
        xx = xx>0.f ? xx : 0.2f*xx;
        float a = __expf(xx-m)/den;
        float2 h = h0b[s*64 + lane];
        acc0 += a*h.x;
        acc1 += a*h.y;
      }
    }
  }
  float2 bi = *(const float2*)&bias[2*lane];
  float v0 = acc0 + bi.x;
  float v1 = acc1 + bi.y;
  v0 = v0>0.f ? v0 : (__expf(v0)-1.f);
  v1 = v1>0.f ? v1 : (__expf(v1)-1.f);
  *(float2*)&out[(size_t)gid*HIDDEN + 2*lane] = make_float2(v0, v1);
}

// K6: h1 = helu @ W1g (128->64), s1, d1. HELU read as float2 pairs.
__launch_bounds__(256)
__global__ void k_gat1prep(const float* __restrict__ HELU, const float* __restrict__ W,
                           const float* __restrict__ asrc, const float* __restrict__ adst,
                           float* __restrict__ H1o, float* __restrict__ S1o, float* __restrict__ D1o){
  __shared__ float Wl[HIDDEN*EMBED];   // 32 KB
  __shared__ float as[EMBED], ad[EMBED];
  int t = threadIdx.x;
  for(int i=t;i<HIDDEN*EMBED;i+=256) Wl[i]=W[i];
  if(t<EMBED){ as[t]=asrc[t]; ad[t]=adst[t]; }
  __syncthreads();
  int w = t>>6, lane = t&63;
  float asl = as[lane], adl = ad[lane];
  for(int nb = blockIdx.x; nb < BN/4; nb += gridDim.x){
    int n = nb*4 + w;
    float2 r = *(const float2*)&HELU[(size_t)n*HIDDEN + 2*lane];
    float acc = 0.f;
    #pragma unroll
    for(int j=0;j<64;j++){
      float rx = __shfl(r.x, j);
      float ry = __shfl(r.y, j);
      acc += rx*Wl[(2*j)*EMBED+lane] + ry*Wl[(2*j+1)*EMBED+lane];
    }
    H1o[(size_t)n*EMBED+lane] = acc;
    float sv = waveSum(acc*asl);
    float dvv = waveSum(acc*adl);
    if(lane==0){ S1o[n]=sv; D1o[n]=dvv; }
  }
}

// K7: GAT1 aggregation -> node_emb
__launch_bounds__(256)
__global__ void k_gat1(const float* __restrict__ H1, const float* __restrict__ S1,
                       const float* __restrict__ D1, const float* __restrict__ E1p,
                       const int* __restrict__ off, const int* __restrict__ csrc,
                       const float* __restrict__ bias, float* __restrict__ out){
  int t = threadIdx.x, w = t>>6, lane = t&63;
  int b = blockIdx.x & 7, c = blockIdx.x >> 3;
  int n = c*4 + w;
  int gid = b*NN + n;
  int base = off[n], deg = off[n+1]-base;
  const float* s1b = S1 + b*NN;
  const float* e1b = E1p + b*EE;
  const float* h1b = H1 + (size_t)b*NN*EMBED;
  float dv = D1[gid];
  float acc = 0.f;
  if(deg > 0){
    if(deg <= 64){
      float lg = -INFINITY; int sidx = 0;
      if(lane < deg){
        sidx = csrc[base+lane];
        float xx = s1b[sidx] + dv + e1b[base+lane];
        lg = xx>0.f ? xx : 0.2f*xx;
      }
      float m = waveMax(lg);
      float ex = (lane<deg)? __expf(lg-m) : 0.f;
      float den = waveSum(ex);
      float al = ex / (den + 1e-16f);
      for(int i=0;i<deg;i++){
        float a = __shfl(al, i);
        int  s = __shfl(sidx, i);
        acc += a*h1b[s*EMBED + lane];
      }
    } else {
      float m = -INFINITY;
      for(int i=lane;i<deg;i+=64){
        float xx = s1b[csrc[base+i]] + dv + e1b[base+i];
        xx = xx>0.f ? xx : 0.2f*xx;
        m = fmaxf(m, xx);
      }
      m = waveMax(m);
      float den = 0.f;
      for(int i=lane;i<deg;i+=64){
        float xx = s1b[csrc[base+i]] + dv + e1b[base+i];
        xx = xx>0.f ? xx : 0.2f*xx;
        den += __expf(xx-m);
      }
      den = waveSum(den) + 1e-16f;
      for(int i=0;i<deg;i++){
        int s = csrc[base+i];
        float xx = s1b[s] + dv + e1b[base+i];
        xx = xx>0.f ? xx : 0.2f*xx;
        float a = __expf(xx-m)/den;
        acc += a*h1b[s*EMBED + lane];
      }
    }
  }
  out[(size_t)gid*EMBED + lane] = acc + bias[lane];
}

// K8: per-graph mean/max pooling -> ctx[b, 128]
__launch_bounds__(256)
__global__ void k_pool(const float* __restrict__ EMBp, float* __restrict__ CTX){
  int b = blockIdx.x;
  int t = threadIdx.x;
  int dim = t & 63, chunk = t >> 6;
  float sm = 0.f, mx = -INFINITY;
  int n0 = chunk*(NN/4), n1 = n0 + NN/4;
  for(int n=n0;n<n1;n++){
    float v = EMBp[((size_t)(b*NN+n))*EMBED + dim];
    sm += v; mx = fmaxf(mx, v);
  }
  __shared__ float ssum[256], smax[256];
  ssum[t]=sm; smax[t]=mx;
  __syncthreads();
  if(t < 64){
    float S = ssum[t]+ssum[t+64]+ssum[t+128]+ssum[t+192];
    float M = fmaxf(fmaxf(smax[t],smax[t+64]), fmaxf(smax[t+128],smax[t+192]));
    CTX[b*128+t]    = S*(1.f/NN);
    CTX[b*128+64+t] = M;
  }
}

// K9: ctx_proj[b] = b1 + ctx[b] @ W1[144:272]
__launch_bounds__(128)
__global__ void k_ctxp(const float* __restrict__ CTX, const float* __restrict__ W1,
                       const float* __restrict__ b1, float* __restrict__ CTXP){
  int b = blockIdx.x, c = threadIdx.x;
  __shared__ float cl[128];
  cl[c] = CTX[b*128+c];
  __syncthreads();
  float a = b1[c];
  for(int j=0;j<128;j++) a += cl[j]*W1[(144+j)*HIDDEN + c];
  CTXP[b*128+c] = a;
}

// K10: p_src/p_dst projections, bf16x2 packed, lane l holds dims (2l, 2l+1)
__launch_bounds__(256)
__global__ void k_pp(const float* __restrict__ EMBp, const float* __restrict__ W1,
                     unsigned* __restrict__ PS, unsigned* __restrict__ PD){
  __shared__ float Wl[64*HIDDEN];   // 32 KB
  int t = threadIdx.x, w = t>>6, lane = t&63;
  for(int i=t;i<64*HIDDEN;i+=256) Wl[i]=W1[i];
  __syncthreads();
  for(int nb = blockIdx.x; nb < BN/4; nb += gridDim.x){
    int n = nb*4 + w;
    float r = EMBp[(size_t)n*EMBED+lane];
    float a0=0.f, a1=0.f;
    #pragma unroll
    for(int j=0;j<64;j++){
      float rj = __shfl(r, j);
      a0 += rj*Wl[j*HIDDEN+2*lane];
      a1 += rj*Wl[j*HIDDEN+2*lane+1];
    }
    PS[(size_t)n*64+lane] = pack_bf2(a0, a1);
  }
  __syncthreads();
  for(int i=t;i<64*HIDDEN;i+=256) Wl[i]=W1[64*HIDDEN + i];
  __syncthreads();
  for(int nb = blockIdx.x; nb < BN/4; nb += gridDim.x){
    int n = nb*4 + w;
    float r = EMBp[(size_t)n*EMBED+lane];
    float a0=0.f, a1=0.f;
    #pragma unroll
    for(int j=0;j<64;j++){
      float rj = __shfl(r, j);
      a0 += rj*Wl[j*HIDDEN+2*lane];
      a1 += rj*Wl[j*HIDDEN+2*lane+1];
    }
    PD[(size_t)n*64+lane] = pack_bf2(a0, a1);
  }
}

// K11: per-edge MLP in CSR order. Graph = blockIdx&7 (XCD-local p slices).
__launch_bounds__(256)
__global__ void k_final(const float* __restrict__ EAp, const int* __restrict__ csrc,
                        const int* __restrict__ cdst, const int* __restrict__ ceid,
                        const unsigned* __restrict__ PS, const unsigned* __restrict__ PD,
                        const float* __restrict__ CTXP, const float* __restrict__ W1,
                        const float* __restrict__ W2, const float* __restrict__ b2,
                        float* __restrict__ out){
  __shared__ float Wl[EDGE_IN*HIDDEN];   // 8 KB (rows 128..143)
  __shared__ float w2s[HIDDEN];
  __shared__ float cp[BB*128];
  int t = threadIdx.x;
  for(int i=t;i<EDGE_IN*HIDDEN;i+=256) Wl[i]=W1[128*HIDDEN + i];
  if(t<HIDDEN) w2s[t]=W2[t];
  for(int i=t;i<BB*128;i+=256) cp[i]=CTXP[i];
  __syncthreads();
  int w = t>>6, lane = t&63;
  int b = blockIdx.x & 7, c = blockIdx.x >> 3;
  int p0 = c*128 + w*32;                     // CSR position within graph
  int sv=0, dv=0, ev=0;
  if(lane<32){ sv=csrc[p0+lane]; dv=cdst[p0+lane]; ev=ceid[p0+lane]; }
  const unsigned* PSb = PS + (size_t)b*NN*64;
  const unsigned* PDb = PD + (size_t)b*NN*64;
  const float* EAb = EAp + ((size_t)b*EE + p0)*EDGE_IN;
  float cp0 = cp[b*128 + 2*lane], cp1 = cp[b*128 + 2*lane + 1];
  float w20 = w2s[2*lane], w21 = w2s[2*lane+1];
  float bias2 = b2[0];
  float myq = 0.f;
  for(int k4=0;k4<8;k4++){
    float av = EAb[k4*64 + lane];            // 4 edges' EA rows, coalesced
    #pragma unroll
    for(int kk=0;kk<4;kk++){
      int k = k4*4 + kk;
      int s = __shfl(sv, k);
      int d = __shfl(dv, k);
      unsigned ps = PSb[s*64 + lane];
      unsigned pd = PDb[d*64 + lane];
      float h0 = cp0 + __uint_as_float(ps<<16) + __uint_as_float(pd<<16);
      float h1 = cp1 + __uint_as_float(ps & 0xffff0000u) + __uint_as_float(pd & 0xffff0000u);
      #pragma unroll
      for(int j=0;j<EDGE_IN;j++){
        float aj = __shfl(av, kk*16 + j);
        h0 += aj*Wl[j*HIDDEN + 2*lane];
        h1 += aj*Wl[j*HIDDEN + 2*lane + 1];
      }
      h0 = fmaxf(h0, 0.f);
      h1 = fmaxf(h1, 0.f);
      float q = waveSum(h0*w20 + h1*w21);
      if(lane==k) myq = q;
    }
  }
  if(lane < 32) out[(size_t)b*EE + ev] = myq + bias2;
}

extern "C" void kernel_launch(void* const* d_in, const int* in_sizes, int n_in,
                              void* d_out, int out_size, void* d_ws, size_t ws_size,
                              hipStream_t stream) {
  const float* node_x   = (const float*)d_in[0];
  const float* edge_attr= (const float*)d_in[1];
  const int*   edge_idx = (const int*)d_in[2];
  const float* ln_ng    = (const float*)d_in[3];
  const float* ln_nb    = (const float*)d_in[4];
  const float* ln_eg    = (const float*)d_in[5];
  const float* ln_eb    = (const float*)d_in[6];
  const float* g0_W     = (const float*)d_in[7];
  const float* g0_We    = (const float*)d_in[8];
  const float* g0_asrc  = (const float*)d_in[9];
  const float* g0_adst  = (const float*)d_in[10];
  const float* g0_ae    = (const float*)d_in[11];
  const float* g0_b     = (const float*)d_in[12];
  const float* g1_W     = (const float*)d_in[13];
  const float* g1_We    = (const float*)d_in[14];
  const float* g1_asrc  = (const float*)d_in[15];
  const float* g1_adst  = (const float*)d_in[16];
  const float* g1_ae    = (const float*)d_in[17];
  const float* g1_b     = (const float*)d_in[18];
  const float* mlp_W1   = (const float*)d_in[19];
  const float* mlp_b1   = (const float*)d_in[20];
  const float* mlp_W2   = (const float*)d_in[21];
  const float* mlp_b2   = (const float*)d_in[22];
  float* out = (float*)d_out;

  // workspace layout (32-bit words)
  float* ws   = (float*)d_ws;
  float* EAp  = ws;                       // 10,240,000
  float* E0p  = EAp  + (size_t)BE*EDGE_IN;// 640,000
  float* E1p  = E0p  + BE;                // 640,000
  float* H0   = E1p  + BE;                // 5,120,000  (later reused as PS)
  float* HELU = H0   + (size_t)BN*HIDDEN; // 5,120,000  (later reused as PD)
  float* H1   = HELU + (size_t)BN*HIDDEN; // 2,560,000
  float* EMBa = H1   + (size_t)BN*EMBED;  // 2,560,000
  float* S0   = EMBa + (size_t)BN*EMBED;  // 40,000
  float* D0   = S0 + BN;
  float* S1   = D0 + BN;
  float* D1   = S1 + BN;
  float* CTX  = D1 + BN;                  // 1024
  float* CTXP = CTX + 1024;               // 1024
  float* WAE  = CTXP + 1024;              // 32
  int* CSR_OFF = (int*)(WAE + 32);        // 5001
  int* CSR_CUR = CSR_OFF + (NN+1);        // 5000
  int* CSR_SRC = CSR_CUR + NN;            // 80000
  int* CSR_DST = CSR_SRC + EE;            // 80000
  int* CSR_EID = CSR_DST + EE;            // 80000
  int* EPOS    = CSR_EID + EE;            // 80000
  unsigned* PS = (unsigned*)H0;           // BN*64 = 2,560,000
  unsigned* PD = (unsigned*)HELU;

  hipMemsetAsync(CSR_CUR, 0, NN*sizeof(int), stream);
  k_wae<<<1, 64, 0, stream>>>(g0_We, g0_ae, g1_We, g1_ae, WAE);
  k_count<<<(EE+255)/256, 256, 0, stream>>>(edge_idx, CSR_CUR);
  k_scan<<<1, 1024, 0, stream>>>(CSR_OFF, CSR_CUR);
  k_fill<<<(EE+255)/256, 256, 0, stream>>>(edge_idx, CSR_CUR, CSR_SRC, CSR_DST, CSR_EID, EPOS);
  k_node<<<1024, 256, 0, stream>>>(node_x, ln_ng, ln_nb, g0_W, g0_asrc, g0_adst, H0, S0, D0);
  k_edge<<<BE/256, 256, 0, stream>>>(edge_attr, ln_eg, ln_eb, WAE, EPOS, EAp, E0p, E1p);
  k_gat0<<<BN/4, 256, 0, stream>>>(H0, S0, D0, E0p, CSR_OFF, CSR_SRC, g0_b, HELU);
  k_gat1prep<<<512, 256, 0, stream>>>(HELU, g1_W, g1_asrc, g1_adst, H1, S1, D1);
  k_gat1<<<BN/4, 256, 0, stream>>>(H1, S1, D1, E1p, CSR_OFF, CSR_SRC, g1_b, EMBa);
  k_pool<<<BB, 256, 0, stream>>>(EMBa, CTX);
  k_ctxp<<<BB, 128, 0, stream>>>(CTX, mlp_W1, mlp_b1, CTXP);
  k_pp<<<512, 256, 0, stream>>>(EMBa, mlp_W1, PS, PD);
  k_final<<<BE/128, 256, 0, stream>>>(EAp, CSR_SRC, CSR_DST, CSR_EID, PS, PD, CTXP, mlp_W1, mlp_W2, mlp_b2, out);
}

// Round 4
// 620.880 us; speedup vs baseline: 1.0404x; 1.0289x over previous
//
#include <hip/hip_runtime.h>
#include <cmath>

#define BB 8
#define NN 5000
#define EE 80000
#define NODE_IN 32
#define EDGE_IN 16
#define HIDDEN 128
#define EMBED 64
#define BN (BB*NN)     // 40000
#define BE (BB*EE)     // 640000

__device__ __forceinline__ float waveSum(float v){
  #pragma unroll
  for(int o=32;o;o>>=1) v += __shfl_xor(v,o);
  return v;
}
__device__ __forceinline__ float waveMax(float v){
  #pragma unroll
  for(int o=32;o;o>>=1) v = fmaxf(v,__shfl_xor(v,o));
  return v;
}
__device__ __forceinline__ unsigned pack_bf2(float a0, float a1){
  unsigned u0 = __float_as_uint(a0), u1 = __float_as_uint(a1);
  unsigned r0 = (u0 + 0x7fffu + ((u0>>16)&1u)) >> 16;
  unsigned r1 = (u1 + 0x7fffu + ((u1>>16)&1u)) & 0xffff0000u;
  return r0 | r1;
}

// K1: w_ae0[16] = We0 @ ae0, w_ae1[16] = We1 @ ae1
__global__ void k_wae(const float* We0, const float* ae0,
                      const float* We1, const float* ae1, float* wae){
  int t = threadIdx.x;
  if(t < 16){
    float a = 0.f;
    for(int k=0;k<HIDDEN;k++) a += We0[t*HIDDEN+k]*ae0[k];
    wae[t] = a;
  } else if(t < 32){
    int j = t-16;
    float a = 0.f;
    for(int k=0;k<EMBED;k++) a += We1[j*EMBED+k]*ae1[k];
    wae[16+j] = a;
  }
}

// K2: LayerNorm(node_x) -> h0 = nx@W0, s0, d0
__launch_bounds__(256)
__global__ void k_node(const float* __restrict__ x, const float* __restrict__ g,
                       const float* __restrict__ bb, const float* __restrict__ W,
                       const float* __restrict__ asrc, const float* __restrict__ adst,
                       float* __restrict__ H0o, float* __restrict__ S0o, float* __restrict__ D0o){
  __shared__ float Wl[NODE_IN*HIDDEN];   // 16 KB
  __shared__ float as[HIDDEN], ad[HIDDEN];
  int t = threadIdx.x;
  for(int i=t;i<NODE_IN*HIDDEN;i+=256) Wl[i]=W[i];
  if(t<HIDDEN){ as[t]=asrc[t]; ad[t]=adst[t]; }
  __syncthreads();
  int w = t>>6, lane = t&63;
  float gl = (lane<NODE_IN)? g[lane] : 0.f;
  float bl = (lane<NODE_IN)? bb[lane] : 0.f;
  float asl0 = as[lane], asl1 = as[lane+64];
  float adl0 = ad[lane], adl1 = ad[lane+64];
  for(int nb = blockIdx.x; nb < BN/4; nb += gridDim.x){
    int n = nb*4 + w;
    float xv = (lane<NODE_IN)? x[n*NODE_IN+lane] : 0.f;
    float s  = waveSum(xv);
    float s2 = waveSum(xv*xv);
    float mu = s*(1.f/NODE_IN);
    float var = s2*(1.f/NODE_IN) - mu*mu;
    float inv = 1.0f / sqrtf(var + 1e-5f);
    float nx = (lane<NODE_IN)? ((xv-mu)*inv*gl + bl) : 0.f;
    float a0=0.f, a1=0.f;
    #pragma unroll
    for(int j=0;j<NODE_IN;j++){
      float r = __shfl(nx, j);
      a0 += r*Wl[j*HIDDEN+lane];
      a1 += r*Wl[j*HIDDEN+lane+64];
    }
    H0o[n*HIDDEN+lane]    = a0;
    H0o[n*HIDDEN+lane+64] = a1;
    float sv = waveSum(a0*asl0 + a1*asl1);
    float dv = waveSum(a0*adl0 + a1*adl1);
    if(lane==0){ S0o[n]=sv; D0o[n]=dv; }
  }
}

// K3: LayerNorm(edge_attr) scattered into CSR position order
__launch_bounds__(256)
__global__ void k_edge(const float* __restrict__ ein, const float* __restrict__ g,
                       const float* __restrict__ bb, const float* __restrict__ wae,
                       const int* __restrict__ EPOS,
                       float* __restrict__ EAp, float* __restrict__ E0p, float* __restrict__ E1p){
  int ge = blockIdx.x*256 + threadIdx.x;   // < BE exactly
  int b = ge / EE, e = ge - b*EE;
  int gp = b*EE + EPOS[e];
  float v[EDGE_IN];
  const float4* p = (const float4*)(ein + (size_t)ge*EDGE_IN);
  float4 q0=p[0], q1=p[1], q2=p[2], q3=p[3];
  v[0]=q0.x; v[1]=q0.y; v[2]=q0.z; v[3]=q0.w;
  v[4]=q1.x; v[5]=q1.y; v[6]=q1.z; v[7]=q1.w;
  v[8]=q2.x; v[9]=q2.y; v[10]=q2.z; v[11]=q2.w;
  v[12]=q3.x; v[13]=q3.y; v[14]=q3.z; v[15]=q3.w;
  float s=0.f, s2=0.f;
  #pragma unroll
  for(int j=0;j<EDGE_IN;j++){ s += v[j]; s2 += v[j]*v[j]; }
  float mu = s*(1.f/EDGE_IN);
  float var = s2*(1.f/EDGE_IN) - mu*mu;
  float inv = 1.0f / sqrtf(var + 1e-5f);
  float e0=0.f, e1=0.f;
  #pragma unroll
  for(int j=0;j<EDGE_IN;j++){
    float nv = (v[j]-mu)*inv*g[j] + bb[j];
    v[j] = nv;
    e0 += nv*wae[j];
    e1 += nv*wae[16+j];
  }
  float4* q = (float4*)(EAp + (size_t)gp*EDGE_IN);
  q[0] = make_float4(v[0],v[1],v[2],v[3]);
  q[1] = make_float4(v[4],v[5],v[6],v[7]);
  q[2] = make_float4(v[8],v[9],v[10],v[11]);
  q[3] = make_float4(v[12],v[13],v[14],v[15]);
  E0p[gp]=e0; E1p[gp]=e1;
}

// K4b: histogram of dst
__global__ void k_count(const int* __restrict__ ei, int* __restrict__ cnt){
  int e = blockIdx.x*256 + threadIdx.x;
  if(e < EE) atomicAdd(&cnt[ei[EE+e]], 1);
}

// K4c: exclusive scan of 5000 counts -> offsets; cursor := offsets
__launch_bounds__(1024)
__global__ void k_scan(int* __restrict__ off, int* __restrict__ cur){
  __shared__ int part[1024];
  int t = threadIdx.x;
  int loc[5]; int s=0;
  int base = t*5;
  #pragma unroll
  for(int k=0;k<5;k++){ int idx=base+k; int c=(idx<NN)? cur[idx]:0; loc[k]=s; s+=c; }
  part[t]=s;
  __syncthreads();
  for(int o=1;o<1024;o<<=1){
    int v = (t>=o)? part[t-o] : 0;
    __syncthreads();
    part[t] += v;
    __syncthreads();
  }
  int pre = (t>0)? part[t-1] : 0;
  #pragma unroll
  for(int k=0;k<5;k++){
    int idx=base+k;
    if(idx<NN){ int o2 = pre+loc[k]; off[idx]=o2; cur[idx]=o2; }
  }
  if(t==0) off[NN] = EE;
}

// K4d: scatter edges into CSR (by dst); also dst per pos and inverse perm
__global__ void k_fill(const int* __restrict__ ei, int* __restrict__ cur,
                       int* __restrict__ csrc, int* __restrict__ cdst,
                       int* __restrict__ ceid, int* __restrict__ epos){
  int e = blockIdx.x*256 + threadIdx.x;
  if(e < EE){
    int d = ei[EE+e];
    int pos = atomicAdd(&cur[d], 1);
    csrc[pos] = ei[e];
    cdst[pos] = d;
    ceid[pos] = e;
    epos[e] = pos;
  }
}

// K5: GAT0 aggregation, batch-8 prefetched gathers.
__launch_bounds__(256)
__global__ void k_gat0(const float* __restrict__ H0, const float* __restrict__ S0,
                       const float* __restrict__ D0, const float* __restrict__ E0p,
                       const int* __restrict__ off, const int* __restrict__ csrc,
                       const float* __restrict__ bias, float* __restrict__ out){
  int t = threadIdx.x, w = t>>6, lane = t&63;
  int b = blockIdx.x & 7, c = blockIdx.x >> 3;
  int n = c*4 + w;                    // node within graph
  int gid = b*NN + n;
  int base = off[n], deg = off[n+1]-base;
  const float* s0b = S0 + b*NN;
  const float* e0b = E0p + b*EE;
  const float2* h0b = (const float2*)(H0 + (size_t)b*NN*HIDDEN);
  float dv = D0[gid];
  float acc0=0.f, acc1=0.f;
  if(deg > 0){
    if(deg <= 64){
      float lg = -INFINITY; int sidx = 0;
      if(lane < deg){
        sidx = csrc[base+lane];
        float xx = s0b[sidx] + dv + e0b[base+lane];
        lg = xx>0.f ? xx : 0.2f*xx;
      }
      float m = waveMax(lg);
      float ex = (lane<deg)? __expf(lg-m) : 0.f;
      float den = waveSum(ex);
      float al = ex / (den + 1e-16f);   // 0 for lane>=deg; sidx 0 there
      int nb8 = (deg+7)>>3;
      for(int b8=0;b8<nb8;b8++){
        int i0 = b8*8;
        int ss[8]; float aa[8]; float2 hh[8];
        #pragma unroll
        for(int kk=0;kk<8;kk++){ ss[kk]=__shfl(sidx, i0+kk); aa[kk]=__shfl(al, i0+kk); }
        #pragma unroll
        for(int kk=0;kk<8;kk++){ hh[kk]=h0b[ss[kk]*64 + lane]; }
        #pragma unroll
        for(int kk=0;kk<8;kk++){ acc0 += aa[kk]*hh[kk].x; acc1 += aa[kk]*hh[kk].y; }
      }
    } else {
      float m = -INFINITY;
      for(int i=lane;i<deg;i+=64){
        float xx = s0b[csrc[base+i]] + dv + e0b[base+i];
        xx = xx>0.f ? xx : 0.2f*xx;
        m = fmaxf(m, xx);
      }
      m = waveMax(m);
      float den = 0.f;
      for(int i=lane;i<deg;i+=64){
        float xx = s0b[csrc[base+i]] + dv + e0b[base+i];
        xx = xx>0.f ? xx : 0.2f*xx;
        den += __expf(xx-m);
      }
      den = waveSum(den) + 1e-16f;
      for(int i=0;i<deg;i++){
        int s = csrc[base+i];
        float xx = s0b[s] + dv + e0b[base+i];
        xx = xx>0.f ? xx : 0.2f*xx;
        float a = __expf(xx-m)/den;
        float2 h = h0b[s*64 + lane];
        acc0 += a*h.x;
        acc1 += a*h.y;
      }
    }
  }
  float2 bi = *(const float2*)&bias[2*lane];
  float v0 = acc0 + bi.x;
  float v1 = acc1 + bi.y;
  v0 = v0>0.f ? v0 : (__expf(v0)-1.f);
  v1 = v1>0.f ? v1 : (__expf(v1)-1.f);
  *(float2*)&out[(size_t)gid*HIDDEN + 2*lane] = make_float2(v0, v1);
}

// K6: h1 = helu @ W1g (128->64), s1, d1. HELU read as float2 pairs.
__launch_bounds__(256)
__global__ void k_gat1prep(const float* __restrict__ HELU, const float* __restrict__ W,
                           const float* __restrict__ asrc, const float* __restrict__ adst,
                           float* __restrict__ H1o, float* __restrict__ S1o, float* __restrict__ D1o){
  __shared__ float Wl[HIDDEN*EMBED];   // 32 KB
  __shared__ float as[EMBED], ad[EMBED];
  int t = threadIdx.x;
  for(int i=t;i<HIDDEN*EMBED;i+=256) Wl[i]=W[i];
  if(t<EMBED){ as[t]=asrc[t]; ad[t]=adst[t]; }
  __syncthreads();
  int w = t>>6, lane = t&63;
  float asl = as[lane], adl = ad[lane];
  for(int nb = blockIdx.x; nb < BN/4; nb += gridDim.x){
    int n = nb*4 + w;
    float2 r = *(const float2*)&HELU[(size_t)n*HIDDEN + 2*lane];
    float acc = 0.f;
    #pragma unroll
    for(int j=0;j<64;j++){
      float rx = __shfl(r.x, j);
      float ry = __shfl(r.y, j);
      acc += rx*Wl[(2*j)*EMBED+lane] + ry*Wl[(2*j+1)*EMBED+lane];
    }
    H1o[(size_t)n*EMBED+lane] = acc;
    float sv = waveSum(acc*asl);
    float dvv = waveSum(acc*adl);
    if(lane==0){ S1o[n]=sv; D1o[n]=dvv; }
  }
}

// K7: GAT1 aggregation, batch-8 prefetched gathers.
__launch_bounds__(256)
__global__ void k_gat1(const float* __restrict__ H1, const float* __restrict__ S1,
                       const float* __restrict__ D1, const float* __restrict__ E1p,
                       const int* __restrict__ off, const int* __restrict__ csrc,
                       const float* __restrict__ bias, float* __restrict__ out){
  int t = threadIdx.x, w = t>>6, lane = t&63;
  int b = blockIdx.x & 7, c = blockIdx.x >> 3;
  int n = c*4 + w;
  int gid = b*NN + n;
  int base = off[n], deg = off[n+1]-base;
  const float* s1b = S1 + b*NN;
  const float* e1b = E1p + b*EE;
  const float* h1b = H1 + (size_t)b*NN*EMBED;
  float dv = D1[gid];
  float acc = 0.f;
  if(deg > 0){
    if(deg <= 64){
      float lg = -INFINITY; int sidx = 0;
      if(lane < deg){
        sidx = csrc[base+lane];
        float xx = s1b[sidx] + dv + e1b[base+lane];
        lg = xx>0.f ? xx : 0.2f*xx;
      }
      float m = waveMax(lg);
      float ex = (lane<deg)? __expf(lg-m) : 0.f;
      float den = waveSum(ex);
      float al = ex / (den + 1e-16f);
      int nb8 = (deg+7)>>3;
      for(int b8=0;b8<nb8;b8++){
        int i0 = b8*8;
        int ss[8]; float aa[8]; float hh[8];
        #pragma unroll
        for(int kk=0;kk<8;kk++){ ss[kk]=__shfl(sidx, i0+kk); aa[kk]=__shfl(al, i0+kk); }
        #pragma unroll
        for(int kk=0;kk<8;kk++){ hh[kk]=h1b[ss[kk]*64 + lane]; }
        #pragma unroll
        for(int kk=0;kk<8;kk++){ acc += aa[kk]*hh[kk]; }
      }
    } else {
      float m = -INFINITY;
      for(int i=lane;i<deg;i+=64){
        float xx = s1b[csrc[base+i]] + dv + e1b[base+i];
        xx = xx>0.f ? xx : 0.2f*xx;
        m = fmaxf(m, xx);
      }
      m = waveMax(m);
      float den = 0.f;
      for(int i=lane;i<deg;i+=64){
        float xx = s1b[csrc[base+i]] + dv + e1b[base+i];
        xx = xx>0.f ? xx : 0.2f*xx;
        den += __expf(xx-m);
      }
      den = waveSum(den) + 1e-16f;
      for(int i=0;i<deg;i++){
        int s = csrc[base+i];
        float xx = s1b[s] + dv + e1b[base+i];
        xx = xx>0.f ? xx : 0.2f*xx;
        float a = __expf(xx-m)/den;
        acc += a*h1b[s*EMBED + lane];
      }
    }
  }
  out[(size_t)gid*EMBED + lane] = acc + bias[lane];
}

// K8: per-graph mean/max pooling -> ctx[b, 128]
__launch_bounds__(256)
__global__ void k_pool(const float* __restrict__ EMBp, float* __restrict__ CTX){
  int b = blockIdx.x;
  int t = threadIdx.x;
  int dim = t & 63, chunk = t >> 6;
  float sm = 0.f, mx = -INFINITY;
  int n0 = chunk*(NN/4), n1 = n0 + NN/4;
  for(int n=n0;n<n1;n++){
    float v = EMBp[((size_t)(b*NN+n))*EMBED + dim];
    sm += v; mx = fmaxf(mx, v);
  }
  __shared__ float ssum[256], smax[256];
  ssum[t]=sm; smax[t]=mx;
  __syncthreads();
  if(t < 64){
    float S = ssum[t]+ssum[t+64]+ssum[t+128]+ssum[t+192];
    float M = fmaxf(fmaxf(smax[t],smax[t+64]), fmaxf(smax[t+128],smax[t+192]));
    CTX[b*128+t]    = S*(1.f/NN);
    CTX[b*128+64+t] = M;
  }
}

// K9: ctx_proj[b] = b1 + ctx[b] @ W1[144:272]
__launch_bounds__(128)
__global__ void k_ctxp(const float* __restrict__ CTX, const float* __restrict__ W1,
                       const float* __restrict__ b1, float* __restrict__ CTXP){
  int b = blockIdx.x, c = threadIdx.x;
  __shared__ float cl[128];
  cl[c] = CTX[b*128+c];
  __syncthreads();
  float a = b1[c];
  for(int j=0;j<128;j++) a += cl[j]*W1[(144+j)*HIDDEN + c];
  CTXP[b*128+c] = a;
}

// K10: p_src/p_dst projections, bf16x2 packed, lane l holds dims (2l, 2l+1)
__launch_bounds__(256)
__global__ void k_pp(const float* __restrict__ EMBp, const float* __restrict__ W1,
                     unsigned* __restrict__ PS, unsigned* __restrict__ PD){
  __shared__ float Wl[64*HIDDEN];   // 32 KB
  int t = threadIdx.x, w = t>>6, lane = t&63;
  for(int i=t;i<64*HIDDEN;i+=256) Wl[i]=W1[i];
  __syncthreads();
  for(int nb = blockIdx.x; nb < BN/4; nb += gridDim.x){
    int n = nb*4 + w;
    float r = EMBp[(size_t)n*EMBED+lane];
    float a0=0.f, a1=0.f;
    #pragma unroll
    for(int j=0;j<64;j++){
      float rj = __shfl(r, j);
      a0 += rj*Wl[j*HIDDEN+2*lane];
      a1 += rj*Wl[j*HIDDEN+2*lane+1];
    }
    PS[(size_t)n*64+lane] = pack_bf2(a0, a1);
  }
  __syncthreads();
  for(int i=t;i<64*HIDDEN;i+=256) Wl[i]=W1[64*HIDDEN + i];
  __syncthreads();
  for(int nb = blockIdx.x; nb < BN/4; nb += gridDim.x){
    int n = nb*4 + w;
    float r = EMBp[(size_t)n*EMBED+lane];
    float a0=0.f, a1=0.f;
    #pragma unroll
    for(int j=0;j<64;j++){
      float rj = __shfl(r, j);
      a0 += rj*Wl[j*HIDDEN+2*lane];
      a1 += rj*Wl[j*HIDDEN+2*lane+1];
    }
    PD[(size_t)n*64+lane] = pack_bf2(a0, a1);
  }
}

// K11: per-edge MLP in CSR order, batch-8 prefetched ps/pd gathers.
__launch_bounds__(256)
__global__ void k_final(const float* __restrict__ EAp, const int* __restrict__ csrc,
                        const int* __restrict__ cdst, const int* __restrict__ ceid,
                        const unsigned* __restrict__ PS, const unsigned* __restrict__ PD,
                        const float* __restrict__ CTXP, const float* __restrict__ W1,
                        const float* __restrict__ W2, const float* __restrict__ b2,
                        float* __restrict__ out){
  __shared__ float Wl[EDGE_IN*HIDDEN];   // 8 KB (rows 128..143)
  __shared__ float w2s[HIDDEN];
  __shared__ float cp[BB*128];
  int t = threadIdx.x;
  for(int i=t;i<EDGE_IN*HIDDEN;i+=256) Wl[i]=W1[128*HIDDEN + i];
  if(t<HIDDEN) w2s[t]=W2[t];
  for(int i=t;i<BB*128;i+=256) cp[i]=CTXP[i];
  __syncthreads();
  int w = t>>6, lane = t&63;
  int b = blockIdx.x & 7, c = blockIdx.x >> 3;
  int p0 = c*128 + w*32;                     // CSR position within graph
  int sv=0, dvv=0, ev=0;
  if(lane<32){ sv=csrc[p0+lane]; dvv=cdst[p0+lane]; ev=ceid[p0+lane]; }
  const unsigned* PSb = PS + (size_t)b*NN*64;
  const unsigned* PDb = PD + (size_t)b*NN*64;
  const float2* EAb = (const float2*)(EAp + ((size_t)b*EE + p0)*EDGE_IN);
  float cp0 = cp[b*128 + 2*lane], cp1 = cp[b*128 + 2*lane + 1];
  float w20 = w2s[2*lane], w21 = w2s[2*lane+1];
  float bias2 = b2[0];
  float myq = 0.f;
  #pragma unroll
  for(int b8=0;b8<4;b8++){
    int i0 = b8*8;
    int ss[8], dd[8];
    #pragma unroll
    for(int kk=0;kk<8;kk++){ ss[kk]=__shfl(sv, i0+kk); dd[kk]=__shfl(dvv, i0+kk); }
    // EA for 8 edges: 128 floats, lane holds floats (2*lane, 2*lane+1)
    float2 av2 = EAb[b8*64 + lane];
    unsigned ps[8], pd[8];
    #pragma unroll
    for(int kk=0;kk<8;kk++){ ps[kk]=PSb[ss[kk]*64 + lane]; }
    #pragma unroll
    for(int kk=0;kk<8;kk++){ pd[kk]=PDb[dd[kk]*64 + lane]; }
    #pragma unroll
    for(int kk=0;kk<8;kk++){
      float h0 = cp0 + __uint_as_float(ps[kk]<<16) + __uint_as_float(pd[kk]<<16);
      float h1 = cp1 + __uint_as_float(ps[kk] & 0xffff0000u) + __uint_as_float(pd[kk] & 0xffff0000u);
      // edge kk's feature j lives at flat (kk*16+j) -> lane kk*8+j/2, comp j&1
      #pragma unroll
      for(int jj=0;jj<8;jj++){
        float ax = __shfl(av2.x, kk*8+jj);
        float ay = __shfl(av2.y, kk*8+jj);
        h0 += ax*Wl[(2*jj)*HIDDEN + 2*lane]   + ay*Wl[(2*jj+1)*HIDDEN + 2*lane];
        h1 += ax*Wl[(2*jj)*HIDDEN + 2*lane+1] + ay*Wl[(2*jj+1)*HIDDEN + 2*lane+1];
      }
      h0 = fmaxf(h0, 0.f);
      h1 = fmaxf(h1, 0.f);
      float q = waveSum(h0*w20 + h1*w21);
      if(lane==i0+kk) myq = q;
    }
  }
  if(lane < 32) out[(size_t)b*EE + ev] = myq + bias2;
}

extern "C" void kernel_launch(void* const* d_in, const int* in_sizes, int n_in,
                              void* d_out, int out_size, void* d_ws, size_t ws_size,
                              hipStream_t stream) {
  const float* node_x   = (const float*)d_in[0];
  const float* edge_attr= (const float*)d_in[1];
  const int*   edge_idx = (const int*)d_in[2];
  const float* ln_ng    = (const float*)d_in[3];
  const float* ln_nb    = (const float*)d_in[4];
  const float* ln_eg    = (const float*)d_in[5];
  const float* ln_eb    = (const float*)d_in[6];
  const float* g0_W     = (const float*)d_in[7];
  const float* g0_We    = (const float*)d_in[8];
  const float* g0_asrc  = (const float*)d_in[9];
  const float* g0_adst  = (const float*)d_in[10];
  const float* g0_ae    = (const float*)d_in[11];
  const float* g0_b     = (const float*)d_in[12];
  const float* g1_W     = (const float*)d_in[13];
  const float* g1_We    = (const float*)d_in[14];
  const float* g1_asrc  = (const float*)d_in[15];
  const float* g1_adst  = (const float*)d_in[16];
  const float* g1_ae    = (const float*)d_in[17];
  const float* g1_b     = (const float*)d_in[18];
  const float* mlp_W1   = (const float*)d_in[19];
  const float* mlp_b1   = (const float*)d_in[20];
  const float* mlp_W2   = (const float*)d_in[21];
  const float* mlp_b2   = (const float*)d_in[22];
  float* out = (float*)d_out;

  // workspace layout (32-bit words)
  float* ws   = (float*)d_ws;
  float* EAp  = ws;                       // 10,240,000
  float* E0p  = EAp  + (size_t)BE*EDGE_IN;// 640,000
  float* E1p  = E0p  + BE;                // 640,000
  float* H0   = E1p  + BE;                // 5,120,000  (later reused as PS)
  float* HELU = H0   + (size_t)BN*HIDDEN; // 5,120,000  (later reused as PD)
  float* H1   = HELU + (size_t)BN*HIDDEN; // 2,560,000
  float* EMBa = H1   + (size_t)BN*EMBED;  // 2,560,000
  float* S0   = EMBa + (size_t)BN*EMBED;  // 40,000
  float* D0   = S0 + BN;
  float* S1   = D0 + BN;
  float* D1   = S1 + BN;
  float* CTX  = D1 + BN;                  // 1024
  float* CTXP = CTX + 1024;               // 1024
  float* WAE  = CTXP + 1024;              // 32
  int* CSR_OFF = (int*)(WAE + 32);        // 5001
  int* CSR_CUR = CSR_OFF + (NN+1);        // 5000
  int* CSR_SRC = CSR_CUR + NN;            // 80000
  int* CSR_DST = CSR_SRC + EE;            // 80000
  int* CSR_EID = CSR_DST + EE;            // 80000
  int* EPOS    = CSR_EID + EE;            // 80000
  unsigned* PS = (unsigned*)H0;           // BN*64 = 2,560,000
  unsigned* PD = (unsigned*)HELU;

  hipMemsetAsync(CSR_CUR, 0, NN*sizeof(int), stream);
  k_wae<<<1, 64, 0, stream>>>(g0_We, g0_ae, g1_We, g1_ae, WAE);
  k_count<<<(EE+255)/256, 256, 0, stream>>>(edge_idx, CSR_CUR);
  k_scan<<<1, 1024, 0, stream>>>(CSR_OFF, CSR_CUR);
  k_fill<<<(EE+255)/256, 256, 0, stream>>>(edge_idx, CSR_CUR, CSR_SRC, CSR_DST, CSR_EID, EPOS);
  k_node<<<1024, 256, 0, stream>>>(node_x, ln_ng, ln_nb, g0_W, g0_asrc, g0_adst, H0, S0, D0);
  k_edge<<<BE/256, 256, 0, stream>>>(edge_attr, ln_eg, ln_eb, WAE, EPOS, EAp, E0p, E1p);
  k_gat0<<<BN/4, 256, 0, stream>>>(H0, S0, D0, E0p, CSR_OFF, CSR_SRC, g0_b, HELU);
  k_gat1prep<<<512, 256, 0, stream>>>(HELU, g1_W, g1_asrc, g1_adst, H1, S1, D1);
  k_gat1<<<BN/4, 256, 0, stream>>>(H1, S1, D1, E1p, CSR_OFF, CSR_SRC, g1_b, EMBa);
  k_pool<<<BB, 256, 0, stream>>>(EMBa, CTX);
  k_ctxp<<<BB, 128, 0, stream>>>(CTX, mlp_W1, mlp_b1, CTXP);
  k_pp<<<512, 256, 0, stream>>>(EMBa, mlp_W1, PS, PD);
  k_final<<<BE/128, 256, 0, stream>>>(EAp, CSR_SRC, CSR_DST, CSR_EID, PS, PD, CTXP, mlp_W1, mlp_W2, mlp_b2, out);
}

// Round 5
// 447.951 us; speedup vs baseline: 1.4420x; 1.3860x over previous
//
#include <hip/hip_runtime.h>
#include <cmath>

#define BB 8
#define NN 5000
#define EE 80000
#define NODE_IN 32
#define EDGE_IN 16
#define HIDDEN 128
#define EMBED 64
#define BN (BB*NN)     // 40000
#define BE (BB*EE)     // 640000

__device__ __forceinline__ float waveSum(float v){
  #pragma unroll
  for(int o=32;o;o>>=1) v += __shfl_xor(v,o);
  return v;
}
__device__ __forceinline__ float waveMax(float v){
  #pragma unroll
  for(int o=32;o;o>>=1) v = fmaxf(v,__shfl_xor(v,o));
  return v;
}
__device__ __forceinline__ int rlanei(int v, int l){
  return __builtin_amdgcn_readlane(v, l);
}
__device__ __forceinline__ float rlanef(float v, int l){
  return __uint_as_float(__builtin_amdgcn_readlane(__float_as_uint(v), l));
}
__device__ __forceinline__ unsigned pack_bf2(float a0, float a1){
  unsigned u0 = __float_as_uint(a0), u1 = __float_as_uint(a1);
  unsigned r0 = (u0 + 0x7fffu + ((u0>>16)&1u)) >> 16;
  unsigned r1 = (u1 + 0x7fffu + ((u1>>16)&1u)) & 0xffff0000u;
  return r0 | r1;
}

// K1: w_ae0[16] = We0 @ ae0, w_ae1[16] = We1 @ ae1
__global__ void k_wae(const float* We0, const float* ae0,
                      const float* We1, const float* ae1, float* wae){
  int t = threadIdx.x;
  if(t < 16){
    float a = 0.f;
    for(int k=0;k<HIDDEN;k++) a += We0[t*HIDDEN+k]*ae0[k];
    wae[t] = a;
  } else if(t < 32){
    int j = t-16;
    float a = 0.f;
    for(int k=0;k<EMBED;k++) a += We1[j*EMBED+k]*ae1[k];
    wae[16+j] = a;
  }
}

// K2: LayerNorm(node_x) -> h0 = nx@W0, s0, d0. Weights in VGPRs, readlane broadcasts.
__launch_bounds__(256)
__global__ void k_node(const float* __restrict__ x, const float* __restrict__ g,
                       const float* __restrict__ bb, const float* __restrict__ W,
                       const float* __restrict__ asrc, const float* __restrict__ adst,
                       float* __restrict__ H0o, float* __restrict__ S0o, float* __restrict__ D0o){
  int t = threadIdx.x;
  int w = t>>6, lane = t&63;
  float w0r[NODE_IN], w1r[NODE_IN];
  #pragma unroll
  for(int j=0;j<NODE_IN;j++){
    w0r[j] = W[j*HIDDEN+lane];
    w1r[j] = W[j*HIDDEN+lane+64];
  }
  float gl = (lane<NODE_IN)? g[lane] : 0.f;
  float bl = (lane<NODE_IN)? bb[lane] : 0.f;
  float asl0 = asrc[lane], asl1 = asrc[lane+64];
  float adl0 = adst[lane], adl1 = adst[lane+64];
  for(int nb = blockIdx.x; nb < BN/4; nb += gridDim.x){
    int n = nb*4 + w;
    float xv = (lane<NODE_IN)? x[n*NODE_IN+lane] : 0.f;
    float s  = waveSum(xv);
    float s2 = waveSum(xv*xv);
    float mu = s*(1.f/NODE_IN);
    float var = s2*(1.f/NODE_IN) - mu*mu;
    float inv = 1.0f / sqrtf(var + 1e-5f);
    float nx = (lane<NODE_IN)? ((xv-mu)*inv*gl + bl) : 0.f;
    float a0=0.f, a1=0.f;
    #pragma unroll
    for(int j=0;j<NODE_IN;j++){
      float r = rlanef(nx, j);
      a0 += r*w0r[j];
      a1 += r*w1r[j];
    }
    H0o[n*HIDDEN+lane]    = a0;
    H0o[n*HIDDEN+lane+64] = a1;
    float sv = waveSum(a0*asl0 + a1*asl1);
    float dv = waveSum(a0*adl0 + a1*adl1);
    if(lane==0){ S0o[n]=sv; D0o[n]=dv; }
  }
}

// K3: LayerNorm(edge_attr) scattered into CSR position order
__launch_bounds__(256)
__global__ void k_edge(const float* __restrict__ ein, const float* __restrict__ g,
                       const float* __restrict__ bb, const float* __restrict__ wae,
                       const int* __restrict__ EPOS,
                       float* __restrict__ EAp, float* __restrict__ E0p, float* __restrict__ E1p){
  int ge = blockIdx.x*256 + threadIdx.x;   // < BE exactly
  int b = ge / EE, e = ge - b*EE;
  int gp = b*EE + EPOS[e];
  float v[EDGE_IN];
  const float4* p = (const float4*)(ein + (size_t)ge*EDGE_IN);
  float4 q0=p[0], q1=p[1], q2=p[2], q3=p[3];
  v[0]=q0.x; v[1]=q0.y; v[2]=q0.z; v[3]=q0.w;
  v[4]=q1.x; v[5]=q1.y; v[6]=q1.z; v[7]=q1.w;
  v[8]=q2.x; v[9]=q2.y; v[10]=q2.z; v[11]=q2.w;
  v[12]=q3.x; v[13]=q3.y; v[14]=q3.z; v[15]=q3.w;
  float s=0.f, s2=0.f;
  #pragma unroll
  for(int j=0;j<EDGE_IN;j++){ s += v[j]; s2 += v[j]*v[j]; }
  float mu = s*(1.f/EDGE_IN);
  float var = s2*(1.f/EDGE_IN) - mu*mu;
  float inv = 1.0f / sqrtf(var + 1e-5f);
  float e0=0.f, e1=0.f;
  #pragma unroll
  for(int j=0;j<EDGE_IN;j++){
    float nv = (v[j]-mu)*inv*g[j] + bb[j];
    v[j] = nv;
    e0 += nv*wae[j];
    e1 += nv*wae[16+j];
  }
  float4* q = (float4*)(EAp + (size_t)gp*EDGE_IN);
  q[0] = make_float4(v[0],v[1],v[2],v[3]);
  q[1] = make_float4(v[4],v[5],v[6],v[7]);
  q[2] = make_float4(v[8],v[9],v[10],v[11]);
  q[3] = make_float4(v[12],v[13],v[14],v[15]);
  E0p[gp]=e0; E1p[gp]=e1;
}

// K4b: histogram of dst
__global__ void k_count(const int* __restrict__ ei, int* __restrict__ cnt){
  int e = blockIdx.x*256 + threadIdx.x;
  if(e < EE) atomicAdd(&cnt[ei[EE+e]], 1);
}

// K4c: exclusive scan of 5000 counts -> offsets; cursor := offsets
__launch_bounds__(1024)
__global__ void k_scan(int* __restrict__ off, int* __restrict__ cur){
  __shared__ int part[1024];
  int t = threadIdx.x;
  int loc[5]; int s=0;
  int base = t*5;
  #pragma unroll
  for(int k=0;k<5;k++){ int idx=base+k; int c=(idx<NN)? cur[idx]:0; loc[k]=s; s+=c; }
  part[t]=s;
  __syncthreads();
  for(int o=1;o<1024;o<<=1){
    int v = (t>=o)? part[t-o] : 0;
    __syncthreads();
    part[t] += v;
    __syncthreads();
  }
  int pre = (t>0)? part[t-1] : 0;
  #pragma unroll
  for(int k=0;k<5;k++){
    int idx=base+k;
    if(idx<NN){ int o2 = pre+loc[k]; off[idx]=o2; cur[idx]=o2; }
  }
  if(t==0) off[NN] = EE;
}

// K4d: scatter edges into CSR (by dst); also dst per pos and inverse perm
__global__ void k_fill(const int* __restrict__ ei, int* __restrict__ cur,
                       int* __restrict__ csrc, int* __restrict__ cdst,
                       int* __restrict__ ceid, int* __restrict__ epos){
  int e = blockIdx.x*256 + threadIdx.x;
  if(e < EE){
    int d = ei[EE+e];
    int pos = atomicAdd(&cur[d], 1);
    csrc[pos] = ei[e];
    cdst[pos] = d;
    ceid[pos] = e;
    epos[e] = pos;
  }
}

// K5: GAT0 aggregation, readlane broadcasts (no DS in inner loop).
__launch_bounds__(256)
__global__ void k_gat0(const float* __restrict__ H0, const float* __restrict__ S0,
                       const float* __restrict__ D0, const float* __restrict__ E0p,
                       const int* __restrict__ off, const int* __restrict__ csrc,
                       const float* __restrict__ bias, float* __restrict__ out){
  int t = threadIdx.x, w = t>>6, lane = t&63;
  int b = blockIdx.x & 7, c = blockIdx.x >> 3;
  int n = c*4 + w;                    // node within graph
  int gid = b*NN + n;
  int base = off[n], deg = off[n+1]-base;
  const float* s0b = S0 + b*NN;
  const float* e0b = E0p + b*EE;
  const float2* h0b = (const float2*)(H0 + (size_t)b*NN*HIDDEN);
  float dv = D0[gid];
  float acc0=0.f, acc1=0.f;
  if(deg > 0){
    if(deg <= 64){
      float lg = -INFINITY; int sidx = 0;
      if(lane < deg){
        sidx = csrc[base+lane];
        float xx = s0b[sidx] + dv + e0b[base+lane];
        lg = xx>0.f ? xx : 0.2f*xx;
      }
      float m = waveMax(lg);
      float ex = (lane<deg)? __expf(lg-m) : 0.f;
      float den = waveSum(ex);
      float al = ex / (den + 1e-16f);   // 0 for lane>=deg; sidx 0 there
      int nb8 = (deg+7)>>3;
      for(int b8=0;b8<nb8;b8++){
        int i0 = b8*8;
        int ss[8]; float aa[8]; float2 hh[8];
        #pragma unroll
        for(int kk=0;kk<8;kk++){ ss[kk]=rlanei(sidx, i0+kk); aa[kk]=rlanef(al, i0+kk); }
        #pragma unroll
        for(int kk=0;kk<8;kk++){ hh[kk]=h0b[ss[kk]*64 + lane]; }
        #pragma unroll
        for(int kk=0;kk<8;kk++){ acc0 += aa[kk]*hh[kk].x; acc1 += aa[kk]*hh[kk].y; }
      }
    } else {
      float m = -INFINITY;
      for(int i=lane;i<deg;i+=64){
        float xx = s0b[csrc[base+i]] + dv + e0b[base+i];
        xx = xx>0.f ? xx : 0.2f*xx;
        m = fmaxf(m, xx);
      }
      m = waveMax(m);
      float den = 0.f;
      for(int i=lane;i<deg;i+=64){
        float xx = s0b[csrc[base+i]] + dv + e0b[base+i];
        xx = xx>0.f ? xx : 0.2f*xx;
        den += __expf(xx-m);
      }
      den = waveSum(den) + 1e-16f;
      for(int i=0;i<deg;i++){
        int s = csrc[base+i];
        float xx = s0b[s] + dv + e0b[base+i];
        xx = xx>0.f ? xx : 0.2f*xx;
        float a = __expf(xx-m)/den;
        float2 h = h0b[s*64 + lane];
        acc0 += a*h.x;
        acc1 += a*h.y;
      }
    }
  }
  float2 bi = *(const float2*)&bias[2*lane];
  float v0 = acc0 + bi.x;
  float v1 = acc1 + bi.y;
  v0 = v0>0.f ? v0 : (__expf(v0)-1.f);
  v1 = v1>0.f ? v1 : (__expf(v1)-1.f);
  *(float2*)&out[(size_t)gid*HIDDEN + 2*lane] = make_float2(v0, v1);
}

// K6: h1 = helu @ W1g (128->64), s1, d1. readlane broadcasts.
__launch_bounds__(256)
__global__ void k_gat1prep(const float* __restrict__ HELU, const float* __restrict__ W,
                           const float* __restrict__ asrc, const float* __restrict__ adst,
                           float* __restrict__ H1o, float* __restrict__ S1o, float* __restrict__ D1o){
  __shared__ float Wl[HIDDEN*EMBED];   // 32 KB
  int t = threadIdx.x;
  for(int i=t;i<HIDDEN*EMBED;i+=256) Wl[i]=W[i];
  __syncthreads();
  int w = t>>6, lane = t&63;
  float asl = asrc[lane], adl = adst[lane];
  for(int nb = blockIdx.x; nb < BN/4; nb += gridDim.x){
    int n = nb*4 + w;
    float2 r = *(const float2*)&HELU[(size_t)n*HIDDEN + 2*lane];
    float acc = 0.f;
    #pragma unroll
    for(int j=0;j<64;j++){
      float rx = rlanef(r.x, j);
      float ry = rlanef(r.y, j);
      acc += rx*Wl[(2*j)*EMBED+lane] + ry*Wl[(2*j+1)*EMBED+lane];
    }
    H1o[(size_t)n*EMBED+lane] = acc;
    float sv = waveSum(acc*asl);
    float dvv = waveSum(acc*adl);
    if(lane==0){ S1o[n]=sv; D1o[n]=dvv; }
  }
}

// K7: GAT1 aggregation, readlane broadcasts.
__launch_bounds__(256)
__global__ void k_gat1(const float* __restrict__ H1, const float* __restrict__ S1,
                       const float* __restrict__ D1, const float* __restrict__ E1p,
                       const int* __restrict__ off, const int* __restrict__ csrc,
                       const float* __restrict__ bias, float* __restrict__ out){
  int t = threadIdx.x, w = t>>6, lane = t&63;
  int b = blockIdx.x & 7, c = blockIdx.x >> 3;
  int n = c*4 + w;
  int gid = b*NN + n;
  int base = off[n], deg = off[n+1]-base;
  const float* s1b = S1 + b*NN;
  const float* e1b = E1p + b*EE;
  const float* h1b = H1 + (size_t)b*NN*EMBED;
  float dv = D1[gid];
  float acc = 0.f;
  if(deg > 0){
    if(deg <= 64){
      float lg = -INFINITY; int sidx = 0;
      if(lane < deg){
        sidx = csrc[base+lane];
        float xx = s1b[sidx] + dv + e1b[base+lane];
        lg = xx>0.f ? xx : 0.2f*xx;
      }
      float m = waveMax(lg);
      float ex = (lane<deg)? __expf(lg-m) : 0.f;
      float den = waveSum(ex);
      float al = ex / (den + 1e-16f);
      int nb8 = (deg+7)>>3;
      for(int b8=0;b8<nb8;b8++){
        int i0 = b8*8;
        int ss[8]; float aa[8]; float hh[8];
        #pragma unroll
        for(int kk=0;kk<8;kk++){ ss[kk]=rlanei(sidx, i0+kk); aa[kk]=rlanef(al, i0+kk); }
        #pragma unroll
        for(int kk=0;kk<8;kk++){ hh[kk]=h1b[ss[kk]*64 + lane]; }
        #pragma unroll
        for(int kk=0;kk<8;kk++){ acc += aa[kk]*hh[kk]; }
      }
    } else {
      float m = -INFINITY;
      for(int i=lane;i<deg;i+=64){
        float xx = s1b[csrc[base+i]] + dv + e1b[base+i];
        xx = xx>0.f ? xx : 0.2f*xx;
        m = fmaxf(m, xx);
      }
      m = waveMax(m);
      float den = 0.f;
      for(int i=lane;i<deg;i+=64){
        float xx = s1b[csrc[base+i]] + dv + e1b[base+i];
        xx = xx>0.f ? xx : 0.2f*xx;
        den += __expf(xx-m);
      }
      den = waveSum(den) + 1e-16f;
      for(int i=0;i<deg;i++){
        int s = csrc[base+i];
        float xx = s1b[s] + dv + e1b[base+i];
        xx = xx>0.f ? xx : 0.2f*xx;
        float a = __expf(xx-m)/den;
        acc += a*h1b[s*EMBED + lane];
      }
    }
  }
  out[(size_t)gid*EMBED + lane] = acc + bias[lane];
}

// K8: per-graph mean/max pooling -> ctx[b, 128]
__launch_bounds__(256)
__global__ void k_pool(const float* __restrict__ EMBp, float* __restrict__ CTX){
  int b = blockIdx.x;
  int t = threadIdx.x;
  int dim = t & 63, chunk = t >> 6;
  float sm = 0.f, mx = -INFINITY;
  int n0 = chunk*(NN/4), n1 = n0 + NN/4;
  for(int n=n0;n<n1;n++){
    float v = EMBp[((size_t)(b*NN+n))*EMBED + dim];
    sm += v; mx = fmaxf(mx, v);
  }
  __shared__ float ssum[256], smax[256];
  ssum[t]=sm; smax[t]=mx;
  __syncthreads();
  if(t < 64){
    float S = ssum[t]+ssum[t+64]+ssum[t+128]+ssum[t+192];
    float M = fmaxf(fmaxf(smax[t],smax[t+64]), fmaxf(smax[t+128],smax[t+192]));
    CTX[b*128+t]    = S*(1.f/NN);
    CTX[b*128+64+t] = M;
  }
}

// K9: ctx_proj[b] = b1 + ctx[b] @ W1[144:272]
__launch_bounds__(128)
__global__ void k_ctxp(const float* __restrict__ CTX, const float* __restrict__ W1,
                       const float* __restrict__ b1, float* __restrict__ CTXP){
  int b = blockIdx.x, c = threadIdx.x;
  __shared__ float cl[128];
  cl[c] = CTX[b*128+c];
  __syncthreads();
  float a = b1[c];
  for(int j=0;j<128;j++) a += cl[j]*W1[(144+j)*HIDDEN + c];
  CTXP[b*128+c] = a;
}

// K10: p_src/p_dst projections, bf16x2 packed, lane l holds dims (2l, 2l+1)
__launch_bounds__(256)
__global__ void k_pp(const float* __restrict__ EMBp, const float* __restrict__ W1,
                     unsigned* __restrict__ PS, unsigned* __restrict__ PD){
  __shared__ float Wl[64*HIDDEN];   // 32 KB
  int t = threadIdx.x, w = t>>6, lane = t&63;
  for(int i=t;i<64*HIDDEN;i+=256) Wl[i]=W1[i];
  __syncthreads();
  for(int nb = blockIdx.x; nb < BN/4; nb += gridDim.x){
    int n = nb*4 + w;
    float r = EMBp[(size_t)n*EMBED+lane];
    float a0=0.f, a1=0.f;
    #pragma unroll
    for(int j=0;j<64;j++){
      float rj = rlanef(r, j);
      a0 += rj*Wl[j*HIDDEN+2*lane];
      a1 += rj*Wl[j*HIDDEN+2*lane+1];
    }
    PS[(size_t)n*64+lane] = pack_bf2(a0, a1);
  }
  __syncthreads();
  for(int i=t;i<64*HIDDEN;i+=256) Wl[i]=W1[64*HIDDEN + i];
  __syncthreads();
  for(int nb = blockIdx.x; nb < BN/4; nb += gridDim.x){
    int n = nb*4 + w;
    float r = EMBp[(size_t)n*EMBED+lane];
    float a0=0.f, a1=0.f;
    #pragma unroll
    for(int j=0;j<64;j++){
      float rj = rlanef(r, j);
      a0 += rj*Wl[j*HIDDEN+2*lane];
      a1 += rj*Wl[j*HIDDEN+2*lane+1];
    }
    PD[(size_t)n*64+lane] = pack_bf2(a0, a1);
  }
}

// K11: per-edge MLP. W1e in VGPRs, EA via LDS broadcast, readlane indices,
// joint 4-edge reduction. DS ops per edge: ~7 (was ~56).
__launch_bounds__(256)
__global__ void k_final(const float* __restrict__ EAp, const int* __restrict__ csrc,
                        const int* __restrict__ cdst, const int* __restrict__ ceid,
                        const unsigned* __restrict__ PS, const unsigned* __restrict__ PD,
                        const float* __restrict__ CTXP, const float* __restrict__ W1,
                        const float* __restrict__ W2, const float* __restrict__ b2,
                        float* __restrict__ out){
  __shared__ float lds_ea[4*32*16];   // 8 KB: per-wave 32 edges x 16 feats
  int t = threadIdx.x, w = t>>6, lane = t&63;
  int b = blockIdx.x & 7, c = blockIdx.x >> 3;
  int p0 = c*128 + w*32;                     // CSR position within graph
  // W1e columns (2*lane, 2*lane+1) into registers
  float w1r0[16], w1r1[16];
  #pragma unroll
  for(int j=0;j<16;j++){
    float2 wv = *(const float2*)&W1[(128+j)*HIDDEN + 2*lane];
    w1r0[j]=wv.x; w1r1[j]=wv.y;
  }
  float2 w2v = *(const float2*)&W2[2*lane];
  float2 cpv = *(const float2*)&CTXP[b*128 + 2*lane];
  float bias2 = b2[0];
  int sv=0, dvv=0, ev=0;
  if(lane<32){ sv=csrc[p0+lane]; dvv=cdst[p0+lane]; ev=ceid[p0+lane]; }
  const unsigned* PSb = PS + (size_t)b*NN*64;
  const unsigned* PDb = PD + (size_t)b*NN*64;
  // stage this wave's 32 edges' features into LDS (wave-local, no barrier)
  const float4* EAsrc = (const float4*)(EAp + ((size_t)b*EE + p0)*EDGE_IN);
  float4* ldst = (float4*)&lds_ea[w*512];
  ldst[lane*2]   = EAsrc[lane*2];
  ldst[lane*2+1] = EAsrc[lane*2+1];
  float myq = 0.f;
  #pragma unroll 1
  for(int g=0; g<8; g++){            // 8 groups of 4 edges
    int i0 = g*4;
    int ss[4], dd[4];
    #pragma unroll
    for(int kk=0;kk<4;kk++){ ss[kk]=rlanei(sv, i0+kk); dd[kk]=rlanei(dvv, i0+kk); }
    unsigned ps[4], pd[4];
    #pragma unroll
    for(int kk=0;kk<4;kk++){ ps[kk]=PSb[ss[kk]*64 + lane]; }
    #pragma unroll
    for(int kk=0;kk<4;kk++){ pd[kk]=PDb[dd[kk]*64 + lane]; }
    float p[4];
    #pragma unroll
    for(int kk=0;kk<4;kk++){
      const float4* ep = (const float4*)&lds_ea[w*512 + (i0+kk)*16];
      float4 e0=ep[0], e1=ep[1], e2=ep[2], e3=ep[3];   // broadcast reads
      float ea16[16] = {e0.x,e0.y,e0.z,e0.w, e1.x,e1.y,e1.z,e1.w,
                        e2.x,e2.y,e2.z,e2.w, e3.x,e3.y,e3.z,e3.w};
      float h0 = cpv.x + __uint_as_float(ps[kk]<<16) + __uint_as_float(pd[kk]<<16);
      float h1 = cpv.y + __uint_as_float(ps[kk] & 0xffff0000u) + __uint_as_float(pd[kk] & 0xffff0000u);
      #pragma unroll
      for(int j=0;j<16;j++){
        h0 += ea16[j]*w1r0[j];
        h1 += ea16[j]*w1r1[j];
      }
      h0 = fmaxf(h0, 0.f);
      h1 = fmaxf(h1, 0.f);
      p[kk] = h0*w2v.x + h1*w2v.y;
    }
    // joint reduction: 4 edges share the shuffle tree
    #pragma unroll
    for(int kk=0;kk<4;kk++){
      p[kk] += __shfl_xor(p[kk], 32);
      p[kk] += __shfl_xor(p[kk], 16);   // lane holds sum over {l, l^16, l^32, l^48}
    }
    int q = lane>>4;
    float sel = (q==0)? p[0] : (q==1)? p[1] : (q==2)? p[2] : p[3];
    sel += __shfl_xor(sel, 8);
    sel += __shfl_xor(sel, 4);
    sel += __shfl_xor(sel, 2);
    sel += __shfl_xor(sel, 1);          // quarter q holds total for edge i0+q
    #pragma unroll
    for(int kk=0;kk<4;kk++){
      float tot = rlanef(sel, kk*16);
      if(lane == i0+kk) myq = tot;
    }
  }
  if(lane < 32) out[(size_t)b*EE + ev] = myq + bias2;
}

extern "C" void kernel_launch(void* const* d_in, const int* in_sizes, int n_in,
                              void* d_out, int out_size, void* d_ws, size_t ws_size,
                              hipStream_t stream) {
  const float* node_x   = (const float*)d_in[0];
  const float* edge_attr= (const float*)d_in[1];
  const int*   edge_idx = (const int*)d_in[2];
  const float* ln_ng    = (const float*)d_in[3];
  const float* ln_nb    = (const float*)d_in[4];
  const float* ln_eg    = (const float*)d_in[5];
  const float* ln_eb    = (const float*)d_in[6];
  const float* g0_W     = (const float*)d_in[7];
  const float* g0_We    = (const float*)d_in[8];
  const float* g0_asrc  = (const float*)d_in[9];
  const float* g0_adst  = (const float*)d_in[10];
  const float* g0_ae    = (const float*)d_in[11];
  const float* g0_b     = (const float*)d_in[12];
  const float* g1_W     = (const float*)d_in[13];
  const float* g1_We    = (const float*)d_in[14];
  const float* g1_asrc  = (const float*)d_in[15];
  const float* g1_adst  = (const float*)d_in[16];
  const float* g1_ae    = (const float*)d_in[17];
  const float* g1_b     = (const float*)d_in[18];
  const float* mlp_W1   = (const float*)d_in[19];
  const float* mlp_b1   = (const float*)d_in[20];
  const float* mlp_W2   = (const float*)d_in[21];
  const float* mlp_b2   = (const float*)d_in[22];
  float* out = (float*)d_out;

  // workspace layout (32-bit words)
  float* ws   = (float*)d_ws;
  float* EAp  = ws;                       // 10,240,000
  float* E0p  = EAp  + (size_t)BE*EDGE_IN;// 640,000
  float* E1p  = E0p  + BE;                // 640,000
  float* H0   = E1p  + BE;                // 5,120,000  (later reused as PS)
  float* HELU = H0   + (size_t)BN*HIDDEN; // 5,120,000  (later reused as PD)
  float* H1   = HELU + (size_t)BN*HIDDEN; // 2,560,000
  float* EMBa = H1   + (size_t)BN*EMBED;  // 2,560,000
  float* S0   = EMBa + (size_t)BN*EMBED;  // 40,000
  float* D0   = S0 + BN;
  float* S1   = D0 + BN;
  float* D1   = S1 + BN;
  float* CTX  = D1 + BN;                  // 1024
  float* CTXP = CTX + 1024;               // 1024
  float* WAE  = CTXP + 1024;              // 32
  int* CSR_OFF = (int*)(WAE + 32);        // 5001
  int* CSR_CUR = CSR_OFF + (NN+1);        // 5000
  int* CSR_SRC = CSR_CUR + NN;            // 80000
  int* CSR_DST = CSR_SRC + EE;            // 80000
  int* CSR_EID = CSR_DST + EE;            // 80000
  int* EPOS    = CSR_EID + EE;            // 80000
  unsigned* PS = (unsigned*)H0;           // BN*64 = 2,560,000
  unsigned* PD = (unsigned*)HELU;

  hipMemsetAsync(CSR_CUR, 0, NN*sizeof(int), stream);
  k_wae<<<1, 64, 0, stream>>>(g0_We, g0_ae, g1_We, g1_ae, WAE);
  k_count<<<(EE+255)/256, 256, 0, stream>>>(edge_idx, CSR_CUR);
  k_scan<<<1, 1024, 0, stream>>>(CSR_OFF, CSR_CUR);
  k_fill<<<(EE+255)/256, 256, 0, stream>>>(edge_idx, CSR_CUR, CSR_SRC, CSR_DST, CSR_EID, EPOS);
  k_node<<<1024, 256, 0, stream>>>(node_x, ln_ng, ln_nb, g0_W, g0_asrc, g0_adst, H0, S0, D0);
  k_edge<<<BE/256, 256, 0, stream>>>(edge_attr, ln_eg, ln_eb, WAE, EPOS, EAp, E0p, E1p);
  k_gat0<<<BN/4, 256, 0, stream>>>(H0, S0, D0, E0p, CSR_OFF, CSR_SRC, g0_b, HELU);
  k_gat1prep<<<512, 256, 0, stream>>>(HELU, g1_W, g1_asrc, g1_adst, H1, S1, D1);
  k_gat1<<<BN/4, 256, 0, stream>>>(H1, S1, D1, E1p, CSR_OFF, CSR_SRC, g1_b, EMBa);
  k_pool<<<BB, 256, 0, stream>>>(EMBa, CTX);
  k_ctxp<<<BB, 128, 0, stream>>>(CTX, mlp_W1, mlp_b1, CTXP);
  k_pp<<<512, 256, 0, stream>>>(EMBa, mlp_W1, PS, PD);
  k_final<<<BE/128, 256, 0, stream>>>(EAp, CSR_SRC, CSR_DST, CSR_EID, PS, PD, CTXP, mlp_W1, mlp_W2, mlp_b2, out);
}

// Round 6
// 400.845 us; speedup vs baseline: 1.6115x; 1.1175x over previous
//
#include <hip/hip_runtime.h>
#include <cmath>

#define BB 8
#define NN 5000
#define EE 80000
#define NODE_IN 32
#define EDGE_IN 16
#define HIDDEN 128
#define EMBED 64
#define BN (BB*NN)     // 40000
#define BE (BB*EE)     // 640000

typedef unsigned short u16;
typedef __attribute__((ext_vector_type(8))) __bf16 bf16x8;
typedef __attribute__((ext_vector_type(4))) float f32x4;

__device__ __forceinline__ float waveSum(float v){
  #pragma unroll
  for(int o=32;o;o>>=1) v += __shfl_xor(v,o);
  return v;
}
__device__ __forceinline__ float waveMax(float v){
  #pragma unroll
  for(int o=32;o;o>>=1) v = fmaxf(v,__shfl_xor(v,o));
  return v;
}
__device__ __forceinline__ int rlanei(int v, int l){
  return __builtin_amdgcn_readlane(v, l);
}
__device__ __forceinline__ float rlanef(float v, int l){
  return __uint_as_float(__builtin_amdgcn_readlane(__float_as_uint(v), l));
}
__device__ __forceinline__ unsigned pack_bf2(float a0, float a1){
  unsigned u0 = __float_as_uint(a0), u1 = __float_as_uint(a1);
  unsigned r0 = (u0 + 0x7fffu + ((u0>>16)&1u)) >> 16;
  unsigned r1 = (u1 + 0x7fffu + ((u1>>16)&1u)) & 0xffff0000u;
  return r0 | r1;
}
__device__ __forceinline__ u16 bf16r(float x){
  unsigned u = __float_as_uint(x);
  return (u16)((u + 0x7fffu + ((u>>16)&1u)) >> 16);
}

// K1: prep — wae (edge attn vectors), w_s1/w_d1 = W1g @ asrc1/adst1,
// BT1 = W1g^T bf16 padded [64][136], BT2 = [W1src|W1dst]^T bf16 padded [256][72]
__launch_bounds__(256)
__global__ void k_prep(const float* We0, const float* ae0,
                       const float* We1, const float* ae1,
                       const float* W1g, const float* asrc1, const float* adst1,
                       const float* mlpW1,
                       float* wae, float* ws1, float* wd1,
                       u16* BT1u, u16* BT2u){
  int t = threadIdx.x;
  if(blockIdx.x == 0){
    if(t < 16){
      float a = 0.f;
      for(int k=0;k<HIDDEN;k++) a += We0[t*HIDDEN+k]*ae0[k];
      wae[t] = a;
    } else if(t < 32){
      int j = t-16;
      float a = 0.f;
      for(int k=0;k<EMBED;k++) a += We1[j*EMBED+k]*ae1[k];
      wae[16+j] = a;
    }
    if(t < 128){
      float s = 0.f, d = 0.f;
      for(int k=0;k<EMBED;k++){
        float w = W1g[t*EMBED+k];
        s += w*asrc1[k];
        d += w*adst1[k];
      }
      ws1[t] = s; wd1[t] = d;
    }
  } else {
    // 16 blocks × 1536 items = 24576 = 8192 (BT1) + 16384 (BT2)
    #pragma unroll
    for(int ii=0; ii<6; ii++){
      int idx = (blockIdx.x-1)*1536 + ii*256 + t;
      if(idx < 8192){
        int c = idx >> 7, k = idx & 127;           // BT1[c][k] = W1g[k][c]
        BT1u[c*136 + k] = bf16r(W1g[k*EMBED + c]);
      } else {
        int i2 = idx - 8192;
        int d = i2 >> 6, j = i2 & 63;              // BT2[d][j]
        float v = (d < 128) ? mlpW1[j*HIDDEN + d] : mlpW1[(64+j)*HIDDEN + (d-128)];
        BT2u[d*72 + j] = bf16r(v);
      }
    }
  }
}

// K2: LayerNorm(node_x) -> h0 = nx@W0, s0, d0. Weights in VGPRs, readlane broadcasts.
__launch_bounds__(256)
__global__ void k_node(const float* __restrict__ x, const float* __restrict__ g,
                       const float* __restrict__ bb, const float* __restrict__ W,
                       const float* __restrict__ asrc, const float* __restrict__ adst,
                       float* __restrict__ H0o, float* __restrict__ S0o, float* __restrict__ D0o){
  int t = threadIdx.x;
  int w = t>>6, lane = t&63;
  float w0r[NODE_IN], w1r[NODE_IN];
  #pragma unroll
  for(int j=0;j<NODE_IN;j++){
    w0r[j] = W[j*HIDDEN+lane];
    w1r[j] = W[j*HIDDEN+lane+64];
  }
  float gl = (lane<NODE_IN)? g[lane] : 0.f;
  float bl = (lane<NODE_IN)? bb[lane] : 0.f;
  float asl0 = asrc[lane], asl1 = asrc[lane+64];
  float adl0 = adst[lane], adl1 = adst[lane+64];
  for(int nb = blockIdx.x; nb < BN/4; nb += gridDim.x){
    int n = nb*4 + w;
    float xv = (lane<NODE_IN)? x[n*NODE_IN+lane] : 0.f;
    float s  = waveSum(xv);
    float s2 = waveSum(xv*xv);
    float mu = s*(1.f/NODE_IN);
    float var = s2*(1.f/NODE_IN) - mu*mu;
    float inv = 1.0f / sqrtf(var + 1e-5f);
    float nx = (lane<NODE_IN)? ((xv-mu)*inv*gl + bl) : 0.f;
    float a0=0.f, a1=0.f;
    #pragma unroll
    for(int j=0;j<NODE_IN;j++){
      float r = rlanef(nx, j);
      a0 += r*w0r[j];
      a1 += r*w1r[j];
    }
    H0o[n*HIDDEN+lane]    = a0;
    H0o[n*HIDDEN+lane+64] = a1;
    float sv = waveSum(a0*asl0 + a1*asl1);
    float dv = waveSum(a0*adl0 + a1*adl1);
    if(lane==0){ S0o[n]=sv; D0o[n]=dv; }
  }
}

// K3: LayerNorm(edge_attr) scattered into CSR position order
__launch_bounds__(256)
__global__ void k_edge(const float* __restrict__ ein, const float* __restrict__ g,
                       const float* __restrict__ bb, const float* __restrict__ wae,
                       const int* __restrict__ EPOS,
                       float* __restrict__ EAp, float* __restrict__ E0p, float* __restrict__ E1p){
  int ge = blockIdx.x*256 + threadIdx.x;   // < BE exactly
  int b = ge / EE, e = ge - b*EE;
  int gp = b*EE + EPOS[e];
  float v[EDGE_IN];
  const float4* p = (const float4*)(ein + (size_t)ge*EDGE_IN);
  float4 q0=p[0], q1=p[1], q2=p[2], q3=p[3];
  v[0]=q0.x; v[1]=q0.y; v[2]=q0.z; v[3]=q0.w;
  v[4]=q1.x; v[5]=q1.y; v[6]=q1.z; v[7]=q1.w;
  v[8]=q2.x; v[9]=q2.y; v[10]=q2.z; v[11]=q2.w;
  v[12]=q3.x; v[13]=q3.y; v[14]=q3.z; v[15]=q3.w;
  float s=0.f, s2=0.f;
  #pragma unroll
  for(int j=0;j<EDGE_IN;j++){ s += v[j]; s2 += v[j]*v[j]; }
  float mu = s*(1.f/EDGE_IN);
  float var = s2*(1.f/EDGE_IN) - mu*mu;
  float inv = 1.0f / sqrtf(var + 1e-5f);
  float e0=0.f, e1=0.f;
  #pragma unroll
  for(int j=0;j<EDGE_IN;j++){
    float nv = (v[j]-mu)*inv*g[j] + bb[j];
    v[j] = nv;
    e0 += nv*wae[j];
    e1 += nv*wae[16+j];
  }
  float4* q = (float4*)(EAp + (size_t)gp*EDGE_IN);
  q[0] = make_float4(v[0],v[1],v[2],v[3]);
  q[1] = make_float4(v[4],v[5],v[6],v[7]);
  q[2] = make_float4(v[8],v[9],v[10],v[11]);
  q[3] = make_float4(v[12],v[13],v[14],v[15]);
  E0p[gp]=e0; E1p[gp]=e1;
}

// K4b: histogram of dst
__global__ void k_count(const int* __restrict__ ei, int* __restrict__ cnt){
  int e = blockIdx.x*256 + threadIdx.x;
  if(e < EE) atomicAdd(&cnt[ei[EE+e]], 1);
}

// K4c: exclusive scan of 5000 counts -> offsets; cursor := offsets
__launch_bounds__(1024)
__global__ void k_scan(int* __restrict__ off, int* __restrict__ cur){
  __shared__ int part[1024];
  int t = threadIdx.x;
  int loc[5]; int s=0;
  int base = t*5;
  #pragma unroll
  for(int k=0;k<5;k++){ int idx=base+k; int c=(idx<NN)? cur[idx]:0; loc[k]=s; s+=c; }
  part[t]=s;
  __syncthreads();
  for(int o=1;o<1024;o<<=1){
    int v = (t>=o)? part[t-o] : 0;
    __syncthreads();
    part[t] += v;
    __syncthreads();
  }
  int pre = (t>0)? part[t-1] : 0;
  #pragma unroll
  for(int k=0;k<5;k++){
    int idx=base+k;
    if(idx<NN){ int o2 = pre+loc[k]; off[idx]=o2; cur[idx]=o2; }
  }
  if(t==0) off[NN] = EE;
}

// K4d: scatter edges into CSR (by dst); also dst per pos and inverse perm
__global__ void k_fill(const int* __restrict__ ei, int* __restrict__ cur,
                       int* __restrict__ csrc, int* __restrict__ cdst,
                       int* __restrict__ ceid, int* __restrict__ epos){
  int e = blockIdx.x*256 + threadIdx.x;
  if(e < EE){
    int d = ei[EE+e];
    int pos = atomicAdd(&cur[d], 1);
    csrc[pos] = ei[e];
    cdst[pos] = d;
    ceid[pos] = e;
    epos[e] = pos;
  }
}

// K5: GAT0 aggregation + ELU + fused S1/D1 epilogue (s1 = helu . (W1g@asrc1)).
__launch_bounds__(256)
__global__ void k_gat0(const float* __restrict__ H0, const float* __restrict__ S0,
                       const float* __restrict__ D0, const float* __restrict__ E0p,
                       const int* __restrict__ off, const int* __restrict__ csrc,
                       const float* __restrict__ bias,
                       const float* __restrict__ WS1, const float* __restrict__ WD1,
                       float* __restrict__ out, float* __restrict__ S1o, float* __restrict__ D1o){
  int t = threadIdx.x, w = t>>6, lane = t&63;
  int b = blockIdx.x & 7, c = blockIdx.x >> 3;
  int n = c*4 + w;                    // node within graph
  int gid = b*NN + n;
  int base = off[n], deg = off[n+1]-base;
  const float* s0b = S0 + b*NN;
  const float* e0b = E0p + b*EE;
  const float2* h0b = (const float2*)(H0 + (size_t)b*NN*HIDDEN);
  float dv = D0[gid];
  float acc0=0.f, acc1=0.f;
  if(deg > 0){
    if(deg <= 64){
      float lg = -INFINITY; int sidx = 0;
      if(lane < deg){
        sidx = csrc[base+lane];
        float xx = s0b[sidx] + dv + e0b[base+lane];
        lg = xx>0.f ? xx : 0.2f*xx;
      }
      float m = waveMax(lg);
      float ex = (lane<deg)? __expf(lg-m) : 0.f;
      float den = waveSum(ex);
      float al = ex / (den + 1e-16f);   // 0 for lane>=deg; sidx 0 there
      int nb8 = (deg+7)>>3;
      for(int b8=0;b8<nb8;b8++){
        int i0 = b8*8;
        int ss[8]; float aa[8]; float2 hh[8];
        #pragma unroll
        for(int kk=0;kk<8;kk++){ ss[kk]=rlanei(sidx, i0+kk); aa[kk]=rlanef(al, i0+kk); }
        #pragma unroll
        for(int kk=0;kk<8;kk++){ hh[kk]=h0b[ss[kk]*64 + lane]; }
        #pragma unroll
        for(int kk=0;kk<8;kk++){ acc0 += aa[kk]*hh[kk].x; acc1 += aa[kk]*hh[kk].y; }
      }
    } else {
      float m = -INFINITY;
      for(int i=lane;i<deg;i+=64){
        float xx = s0b[csrc[base+i]] + dv + e0b[base+i];
        xx = xx>0.f ? xx : 0.2f*xx;
        m = fmaxf(m, xx);
      }
      m = waveMax(m);
      float den = 0.f;
      for(int i=lane;i<deg;i+=64){
        float xx = s0b[csrc[base+i]] + dv + e0b[base+i];
        xx = xx>0.f ? xx : 0.2f*xx;
        den += __expf(xx-m);
      }
      den = waveSum(den) + 1e-16f;
      for(int i=0;i<deg;i++){
        int s = csrc[base+i];
        float xx = s0b[s] + dv + e0b[base+i];
        xx = xx>0.f ? xx : 0.2f*xx;
        float a = __expf(xx-m)/den;
        float2 h = h0b[s*64 + lane];
        acc0 += a*h.x;
        acc1 += a*h.y;
      }
    }
  }
  float2 bi = *(const float2*)&bias[2*lane];
  float v0 = acc0 + bi.x;
  float v1 = acc1 + bi.y;
  v0 = v0>0.f ? v0 : (__expf(v0)-1.f);
  v1 = v1>0.f ? v1 : (__expf(v1)-1.f);
  *(float2*)&out[(size_t)gid*HIDDEN + 2*lane] = make_float2(v0, v1);
  float2 wsv = *(const float2*)&WS1[2*lane];
  float2 wdv = *(const float2*)&WD1[2*lane];
  float sv1 = waveSum(v0*wsv.x + v1*wsv.y);
  float dv1 = waveSum(v0*wdv.x + v1*wdv.y);
  if(lane==0){ S1o[gid]=sv1; D1o[gid]=dv1; }
}

// K6: H1 = HELU(40000x128) @ W1g(128x64) via MFMA. 64-row tile per block.
__launch_bounds__(256)
__global__ void k_h1(const float* __restrict__ HELU, const u16* __restrict__ BT1,
                     float* __restrict__ H1){
  __shared__ u16 Ald[64*136];   // padded rows: 136 bf16
  __shared__ u16 Bld[64*136];
  int t = threadIdx.x;
  int n0 = blockIdx.x*64;
  // stage A: 64x128 fp32 -> bf16
  #pragma unroll
  for(int ii=0; ii<4; ii++){
    int c2 = ii*256 + t;               // 1024 chunks of 8 floats
    int r = c2 >> 4, q = c2 & 15;
    const float4* src = (const float4*)(HELU + (size_t)(n0+r)*HIDDEN + q*8);
    float4 f0 = src[0], f1 = src[1];
    uint4 pk = make_uint4(pack_bf2(f0.x,f0.y), pack_bf2(f0.z,f0.w),
                          pack_bf2(f1.x,f1.y), pack_bf2(f1.z,f1.w));
    *(uint4*)&Ald[r*136 + q*8] = pk;
  }
  // stage B: linear copy 17408 B = 1088 uint4
  for(int i=t; i<1088; i+=256) ((uint4*)Bld)[i] = ((const uint4*)BT1)[i];
  __syncthreads();
  int w = t>>6, lane = t&63;
  int lo = lane & 15, hi = lane >> 4;
  f32x4 acc0 = {0.f,0.f,0.f,0.f}, acc1 = acc0, acc2 = acc0, acc3 = acc0;
  #pragma unroll
  for(int ks=0; ks<4; ks++){
    bf16x8 a = *(const bf16x8*)&Ald[(w*16+lo)*136 + ks*32 + hi*8];
    bf16x8 b0 = *(const bf16x8*)&Bld[(0*16+lo)*136 + ks*32 + hi*8];
    bf16x8 b1 = *(const bf16x8*)&Bld[(1*16+lo)*136 + ks*32 + hi*8];
    bf16x8 b2 = *(const bf16x8*)&Bld[(2*16+lo)*136 + ks*32 + hi*8];
    bf16x8 b3 = *(const bf16x8*)&Bld[(3*16+lo)*136 + ks*32 + hi*8];
    acc0 = __builtin_amdgcn_mfma_f32_16x16x32_bf16(a, b0, acc0, 0,0,0);
    acc1 = __builtin_amdgcn_mfma_f32_16x16x32_bf16(a, b1, acc1, 0,0,0);
    acc2 = __builtin_amdgcn_mfma_f32_16x16x32_bf16(a, b2, acc2, 0,0,0);
    acc3 = __builtin_amdgcn_mfma_f32_16x16x32_bf16(a, b3, acc3, 0,0,0);
  }
  int rowb = n0 + w*16 + hi*4;
  #pragma unroll
  for(int r=0;r<4;r++){
    H1[(size_t)(rowb+r)*EMBED +  0 + lo] = acc0[r];
    H1[(size_t)(rowb+r)*EMBED + 16 + lo] = acc1[r];
    H1[(size_t)(rowb+r)*EMBED + 32 + lo] = acc2[r];
    H1[(size_t)(rowb+r)*EMBED + 48 + lo] = acc3[r];
  }
}

// K7: GAT1 aggregation, readlane broadcasts.
__launch_bounds__(256)
__global__ void k_gat1(const float* __restrict__ H1, const float* __restrict__ S1,
                       const float* __restrict__ D1, const float* __restrict__ E1p,
                       const int* __restrict__ off, const int* __restrict__ csrc,
                       const float* __restrict__ bias, float* __restrict__ out){
  int t = threadIdx.x, w = t>>6, lane = t&63;
  int b = blockIdx.x & 7, c = blockIdx.x >> 3;
  int n = c*4 + w;
  int gid = b*NN + n;
  int base = off[n], deg = off[n+1]-base;
  const float* s1b = S1 + b*NN;
  const float* e1b = E1p + b*EE;
  const float* h1b = H1 + (size_t)b*NN*EMBED;
  float dv = D1[gid];
  float acc = 0.f;
  if(deg > 0){
    if(deg <= 64){
      float lg = -INFINITY; int sidx = 0;
      if(lane < deg){
        sidx = csrc[base+lane];
        float xx = s1b[sidx] + dv + e1b[base+lane];
        lg = xx>0.f ? xx : 0.2f*xx;
      }
      float m = waveMax(lg);
      float ex = (lane<deg)? __expf(lg-m) : 0.f;
      float den = waveSum(ex);
      float al = ex / (den + 1e-16f);
      int nb8 = (deg+7)>>3;
      for(int b8=0;b8<nb8;b8++){
        int i0 = b8*8;
        int ss[8]; float aa[8]; float hh[8];
        #pragma unroll
        for(int kk=0;kk<8;kk++){ ss[kk]=rlanei(sidx, i0+kk); aa[kk]=rlanef(al, i0+kk); }
        #pragma unroll
        for(int kk=0;kk<8;kk++){ hh[kk]=h1b[ss[kk]*64 + lane]; }
        #pragma unroll
        for(int kk=0;kk<8;kk++){ acc += aa[kk]*hh[kk]; }
      }
    } else {
      float m = -INFINITY;
      for(int i=lane;i<deg;i+=64){
        float xx = s1b[csrc[base+i]] + dv + e1b[base+i];
        xx = xx>0.f ? xx : 0.2f*xx;
        m = fmaxf(m, xx);
      }
      m = waveMax(m);
      float den = 0.f;
      for(int i=lane;i<deg;i+=64){
        float xx = s1b[csrc[base+i]] + dv + e1b[base+i];
        xx = xx>0.f ? xx : 0.2f*xx;
        den += __expf(xx-m);
      }
      den = waveSum(den) + 1e-16f;
      for(int i=0;i<deg;i++){
        int s = csrc[base+i];
        float xx = s1b[s] + dv + e1b[base+i];
        xx = xx>0.f ? xx : 0.2f*xx;
        float a = __expf(xx-m)/den;
        acc += a*h1b[s*EMBED + lane];
      }
    }
  }
  out[(size_t)gid*EMBED + lane] = acc + bias[lane];
}

// K8: per-graph mean/max pooling -> ctx[b, 128]
__launch_bounds__(256)
__global__ void k_pool(const float* __restrict__ EMBp, float* __restrict__ CTX){
  int b = blockIdx.x;
  int t = threadIdx.x;
  int dim = t & 63, chunk = t >> 6;
  float sm = 0.f, mx = -INFINITY;
  int n0 = chunk*(NN/4), n1 = n0 + NN/4;
  for(int n=n0;n<n1;n++){
    float v = EMBp[((size_t)(b*NN+n))*EMBED + dim];
    sm += v; mx = fmaxf(mx, v);
  }
  __shared__ float ssum[256], smax[256];
  ssum[t]=sm; smax[t]=mx;
  __syncthreads();
  if(t < 64){
    float S = ssum[t]+ssum[t+64]+ssum[t+128]+ssum[t+192];
    float M = fmaxf(fmaxf(smax[t],smax[t+64]), fmaxf(smax[t+128],smax[t+192]));
    CTX[b*128+t]    = S*(1.f/NN);
    CTX[b*128+64+t] = M;
  }
}

// K9: ctx_proj[b] = b1 + ctx[b] @ W1[144:272]
__launch_bounds__(128)
__global__ void k_ctxp(const float* __restrict__ CTX, const float* __restrict__ W1,
                       const float* __restrict__ b1, float* __restrict__ CTXP){
  int b = blockIdx.x, c = threadIdx.x;
  __shared__ float cl[128];
  cl[c] = CTX[b*128+c];
  __syncthreads();
  float a = b1[c];
  for(int j=0;j<128;j++) a += cl[j]*W1[(144+j)*HIDDEN + c];
  CTXP[b*128+c] = a;
}

// K10: PS/PD = EMB(40000x64) @ BT2^T (64x256) via MFMA; outputs bf16 ushort[n][128].
__launch_bounds__(256)
__global__ void k_psd(const float* __restrict__ EMB, const u16* __restrict__ BT2,
                      u16* __restrict__ PSu, u16* __restrict__ PDu){
  __shared__ u16 Ald[64*72];    // 9216 B
  __shared__ u16 Bld[256*72];   // 36864 B
  int t = threadIdx.x;
  int n0 = blockIdx.x*64;
  // stage A: 64x64 fp32 -> bf16 (512 chunks of 8 floats)
  #pragma unroll
  for(int ii=0; ii<2; ii++){
    int c2 = ii*256 + t;
    int r = c2 >> 3, q = c2 & 7;
    const float4* src = (const float4*)(EMB + (size_t)(n0+r)*EMBED + q*8);
    float4 f0 = src[0], f1 = src[1];
    uint4 pk = make_uint4(pack_bf2(f0.x,f0.y), pack_bf2(f0.z,f0.w),
                          pack_bf2(f1.x,f1.y), pack_bf2(f1.z,f1.w));
    *(uint4*)&Ald[r*72 + q*8] = pk;
  }
  // stage B: 36864 B = 2304 uint4
  for(int i=t; i<2304; i+=256) ((uint4*)Bld)[i] = ((const uint4*)BT2)[i];
  __syncthreads();
  int w = t>>6, lane = t&63;
  int lo = lane & 15, hi = lane >> 4;
  f32x4 acc[16];
  #pragma unroll
  for(int i=0;i<16;i++) acc[i] = (f32x4){0.f,0.f,0.f,0.f};
  #pragma unroll
  for(int ks=0; ks<2; ks++){
    bf16x8 a = *(const bf16x8*)&Ald[(w*16+lo)*72 + ks*32 + hi*8];
    #pragma unroll
    for(int nt=0; nt<16; nt++){
      bf16x8 b = *(const bf16x8*)&Bld[(nt*16+lo)*72 + ks*32 + hi*8];
      acc[nt] = __builtin_amdgcn_mfma_f32_16x16x32_bf16(a, b, acc[nt], 0,0,0);
    }
  }
  int rowb = n0 + w*16 + hi*4;
  #pragma unroll
  for(int nt=0; nt<16; nt++){
    #pragma unroll
    for(int r=0;r<4;r++){
      u16 u = bf16r(acc[nt][r]);
      if(nt < 8) PSu[(size_t)(rowb+r)*HIDDEN + nt*16 + lo] = u;
      else       PDu[(size_t)(rowb+r)*HIDDEN + (nt-8)*16 + lo] = u;
    }
  }
}

// K11: per-edge MLP. W1e in VGPRs, EA via LDS broadcast, readlane indices,
// joint 4-edge reduction.
__launch_bounds__(256)
__global__ void k_final(const float* __restrict__ EAp, const int* __restrict__ csrc,
                        const int* __restrict__ cdst, const int* __restrict__ ceid,
                        const unsigned* __restrict__ PS, const unsigned* __restrict__ PD,
                        const float* __restrict__ CTXP, const float* __restrict__ W1,
                        const float* __restrict__ W2, const float* __restrict__ b2,
                        float* __restrict__ out){
  __shared__ float lds_ea[4*32*16];   // 8 KB: per-wave 32 edges x 16 feats
  int t = threadIdx.x, w = t>>6, lane = t&63;
  int b = blockIdx.x & 7, c = blockIdx.x >> 3;
  int p0 = c*128 + w*32;                     // CSR position within graph
  float w1r0[16], w1r1[16];
  #pragma unroll
  for(int j=0;j<16;j++){
    float2 wv = *(const float2*)&W1[(128+j)*HIDDEN + 2*lane];
    w1r0[j]=wv.x; w1r1[j]=wv.y;
  }
  float2 w2v = *(const float2*)&W2[2*lane];
  float2 cpv = *(const float2*)&CTXP[b*128 + 2*lane];
  float bias2 = b2[0];
  int sv=0, dvv=0, ev=0;
  if(lane<32){ sv=csrc[p0+lane]; dvv=cdst[p0+lane]; ev=ceid[p0+lane]; }
  const unsigned* PSb = PS + (size_t)b*NN*64;
  const unsigned* PDb = PD + (size_t)b*NN*64;
  const float4* EAsrc = (const float4*)(EAp + ((size_t)b*EE + p0)*EDGE_IN);
  float4* ldst = (float4*)&lds_ea[w*512];
  ldst[lane*2]   = EAsrc[lane*2];
  ldst[lane*2+1] = EAsrc[lane*2+1];
  float myq = 0.f;
  #pragma unroll 1
  for(int g=0; g<8; g++){            // 8 groups of 4 edges
    int i0 = g*4;
    int ss[4], dd[4];
    #pragma unroll
    for(int kk=0;kk<4;kk++){ ss[kk]=rlanei(sv, i0+kk); dd[kk]=rlanei(dvv, i0+kk); }
    unsigned ps[4], pd[4];
    #pragma unroll
    for(int kk=0;kk<4;kk++){ ps[kk]=PSb[ss[kk]*64 + lane]; }
    #pragma unroll
    for(int kk=0;kk<4;kk++){ pd[kk]=PDb[dd[kk]*64 + lane]; }
    float p[4];
    #pragma unroll
    for(int kk=0;kk<4;kk++){
      const float4* ep = (const float4*)&lds_ea[w*512 + (i0+kk)*16];
      float4 e0=ep[0], e1=ep[1], e2=ep[2], e3=ep[3];   // broadcast reads
      float ea16[16] = {e0.x,e0.y,e0.z,e0.w, e1.x,e1.y,e1.z,e1.w,
                        e2.x,e2.y,e2.z,e2.w, e3.x,e3.y,e3.z,e3.w};
      float h0 = cpv.x + __uint_as_float(ps[kk]<<16) + __uint_as_float(pd[kk]<<16);
      float h1 = cpv.y + __uint_as_float(ps[kk] & 0xffff0000u) + __uint_as_float(pd[kk] & 0xffff0000u);
      #pragma unroll
      for(int j=0;j<16;j++){
        h0 += ea16[j]*w1r0[j];
        h1 += ea16[j]*w1r1[j];
      }
      h0 = fmaxf(h0, 0.f);
      h1 = fmaxf(h1, 0.f);
      p[kk] = h0*w2v.x + h1*w2v.y;
    }
    #pragma unroll
    for(int kk=0;kk<4;kk++){
      p[kk] += __shfl_xor(p[kk], 32);
      p[kk] += __shfl_xor(p[kk], 16);
    }
    int q = lane>>4;
    float sel = (q==0)? p[0] : (q==1)? p[1] : (q==2)? p[2] : p[3];
    sel += __shfl_xor(sel, 8);
    sel += __shfl_xor(sel, 4);
    sel += __shfl_xor(sel, 2);
    sel += __shfl_xor(sel, 1);
    #pragma unroll
    for(int kk=0;kk<4;kk++){
      float tot = rlanef(sel, kk*16);
      if(lane == i0+kk) myq = tot;
    }
  }
  if(lane < 32) out[(size_t)b*EE + ev] = myq + bias2;
}

extern "C" void kernel_launch(void* const* d_in, const int* in_sizes, int n_in,
                              void* d_out, int out_size, void* d_ws, size_t ws_size,
                              hipStream_t stream) {
  const float* node_x   = (const float*)d_in[0];
  const float* edge_attr= (const float*)d_in[1];
  const int*   edge_idx = (const int*)d_in[2];
  const float* ln_ng    = (const float*)d_in[3];
  const float* ln_nb    = (const float*)d_in[4];
  const float* ln_eg    = (const float*)d_in[5];
  const float* ln_eb    = (const float*)d_in[6];
  const float* g0_W     = (const float*)d_in[7];
  const float* g0_We    = (const float*)d_in[8];
  const float* g0_asrc  = (const float*)d_in[9];
  const float* g0_adst  = (const float*)d_in[10];
  const float* g0_ae    = (const float*)d_in[11];
  const float* g0_b     = (const float*)d_in[12];
  const float* g1_W     = (const float*)d_in[13];
  const float* g1_We    = (const float*)d_in[14];
  const float* g1_asrc  = (const float*)d_in[15];
  const float* g1_adst  = (const float*)d_in[16];
  const float* g1_ae    = (const float*)d_in[17];
  const float* g1_b     = (const float*)d_in[18];
  const float* mlp_W1   = (const float*)d_in[19];
  const float* mlp_b1   = (const float*)d_in[20];
  const float* mlp_W2   = (const float*)d_in[21];
  const float* mlp_b2   = (const float*)d_in[22];
  float* out = (float*)d_out;

  // workspace layout (32-bit words)
  float* ws   = (float*)d_ws;
  float* EAp  = ws;                       // 10,240,000
  float* E0p  = EAp  + (size_t)BE*EDGE_IN;// 640,000
  float* E1p  = E0p  + BE;                // 640,000
  float* H0   = E1p  + BE;                // 5,120,000  (later reused as PS)
  float* HELU = H0   + (size_t)BN*HIDDEN; // 5,120,000  (later reused as PD)
  float* H1   = HELU + (size_t)BN*HIDDEN; // 2,560,000
  float* EMBa = H1   + (size_t)BN*EMBED;  // 2,560,000
  float* S0   = EMBa + (size_t)BN*EMBED;  // 40,000
  float* D0   = S0 + BN;
  float* S1   = D0 + BN;
  float* D1   = S1 + BN;
  float* CTX  = D1 + BN;                  // 1024
  float* CTXP = CTX + 1024;               // 1024
  float* WAE  = CTXP + 1024;              // 32
  int* CSR_OFF = (int*)(WAE + 32);        // 5004 (padded for alignment)
  int* CSR_CUR = CSR_OFF + (NN+4);        // 5000
  int* CSR_SRC = CSR_CUR + NN;            // 80000
  int* CSR_DST = CSR_SRC + EE;            // 80000
  int* CSR_EID = CSR_DST + EE;            // 80000
  int* EPOS    = CSR_EID + EE;            // 80000
  float* WS1   = (float*)(EPOS + EE);     // 128
  float* WD1   = WS1 + 128;               // 128
  u16* BT1u    = (u16*)(WD1 + 128);       // 64*136 u16 = 4352 dwords
  u16* BT2u    = BT1u + 64*136;           // 256*72 u16 = 9216 dwords
  unsigned* PS = (unsigned*)H0;           // bf16 pairs, BN*64 dwords
  unsigned* PD = (unsigned*)HELU;

  hipMemsetAsync(CSR_CUR, 0, NN*sizeof(int), stream);
  k_prep<<<17, 256, 0, stream>>>(g0_We, g0_ae, g1_We, g1_ae, g1_W, g1_asrc, g1_adst,
                                 mlp_W1, WAE, WS1, WD1, BT1u, BT2u);
  k_count<<<(EE+255)/256, 256, 0, stream>>>(edge_idx, CSR_CUR);
  k_scan<<<1, 1024, 0, stream>>>(CSR_OFF, CSR_CUR);
  k_fill<<<(EE+255)/256, 256, 0, stream>>>(edge_idx, CSR_CUR, CSR_SRC, CSR_DST, CSR_EID, EPOS);
  k_node<<<1024, 256, 0, stream>>>(node_x, ln_ng, ln_nb, g0_W, g0_asrc, g0_adst, H0, S0, D0);
  k_edge<<<BE/256, 256, 0, stream>>>(edge_attr, ln_eg, ln_eb, WAE, EPOS, EAp, E0p, E1p);
  k_gat0<<<BN/4, 256, 0, stream>>>(H0, S0, D0, E0p, CSR_OFF, CSR_SRC, g0_b, WS1, WD1, HELU, S1, D1);
  k_h1<<<BN/64, 256, 0, stream>>>(HELU, BT1u, H1);
  k_gat1<<<BN/4, 256, 0, stream>>>(H1, S1, D1, E1p, CSR_OFF, CSR_SRC, g1_b, EMBa);
  k_pool<<<BB, 256, 0, stream>>>(EMBa, CTX);
  k_ctxp<<<BB, 128, 0, stream>>>(CTX, mlp_W1, mlp_b1, CTXP);
  k_psd<<<BN/64, 256, 0, stream>>>(EMBa, BT2u, (u16*)PS, (u16*)PD);
  k_final<<<BE/128, 256, 0, stream>>>(EAp, CSR_SRC, CSR_DST, CSR_EID, PS, PD, CTXP, mlp_W1, mlp_W2, mlp_b2, out);
}

// Round 7
// 362.365 us; speedup vs baseline: 1.7826x; 1.1062x over previous
//
#include <hip/hip_runtime.h>
#include <cmath>

#define BB 8
#define NN 5000
#define EE 80000
#define NODE_IN 32
#define EDGE_IN 16
#define HIDDEN 128
#define EMBED 64
#define BN (BB*NN)     // 40000
#define BE (BB*EE)     // 640000

typedef unsigned short u16;
typedef __attribute__((ext_vector_type(8))) __bf16 bf16x8;
typedef __attribute__((ext_vector_type(4))) float f32x4;

__device__ __forceinline__ float waveSum(float v){
  #pragma unroll
  for(int o=32;o;o>>=1) v += __shfl_xor(v,o);
  return v;
}
__device__ __forceinline__ float waveMax(float v){
  #pragma unroll
  for(int o=32;o;o>>=1) v = fmaxf(v,__shfl_xor(v,o));
  return v;
}
__device__ __forceinline__ int rlanei(int v, int l){
  return __builtin_amdgcn_readlane(v, l);
}
__device__ __forceinline__ float rlanef(float v, int l){
  return __uint_as_float(__builtin_amdgcn_readlane(__float_as_uint(v), l));
}
__device__ __forceinline__ unsigned pack_bf2(float a0, float a1){
  unsigned u0 = __float_as_uint(a0), u1 = __float_as_uint(a1);
  unsigned r0 = (u0 + 0x7fffu + ((u0>>16)&1u)) >> 16;
  unsigned r1 = (u1 + 0x7fffu + ((u1>>16)&1u)) & 0xffff0000u;
  return r0 | r1;
}
__device__ __forceinline__ u16 bf16r(float x){
  unsigned u = __float_as_uint(x);
  return (u16)((u + 0x7fffu + ((u>>16)&1u)) >> 16);
}
__device__ __forceinline__ float bflo(unsigned h){ return __uint_as_float(h<<16); }
__device__ __forceinline__ float bfhi(unsigned h){ return __uint_as_float(h & 0xffff0000u); }

// K1: prep — wae, w_s1/w_d1 = W1g @ asrc1/adst1, BT1 [64][136] bf16, BT2 [256][72] bf16
__launch_bounds__(256)
__global__ void k_prep(const float* We0, const float* ae0,
                       const float* We1, const float* ae1,
                       const float* W1g, const float* asrc1, const float* adst1,
                       const float* mlpW1,
                       float* wae, float* ws1, float* wd1,
                       u16* BT1u, u16* BT2u){
  int t = threadIdx.x;
  if(blockIdx.x == 0){
    if(t < 16){
      float a = 0.f;
      for(int k=0;k<HIDDEN;k++) a += We0[t*HIDDEN+k]*ae0[k];
      wae[t] = a;
    } else if(t < 32){
      int j = t-16;
      float a = 0.f;
      for(int k=0;k<EMBED;k++) a += We1[j*EMBED+k]*ae1[k];
      wae[16+j] = a;
    }
    if(t < 128){
      float s = 0.f, d = 0.f;
      for(int k=0;k<EMBED;k++){
        float w = W1g[t*EMBED+k];
        s += w*asrc1[k];
        d += w*adst1[k];
      }
      ws1[t] = s; wd1[t] = d;
    }
  } else {
    #pragma unroll
    for(int ii=0; ii<6; ii++){
      int idx = (blockIdx.x-1)*1536 + ii*256 + t;
      if(idx < 8192){
        int c = idx >> 7, k = idx & 127;           // BT1[c][k] = W1g[k][c]
        BT1u[c*136 + k] = bf16r(W1g[k*EMBED + c]);
      } else {
        int i2 = idx - 8192;
        int d = i2 >> 6, j = i2 & 63;              // BT2[d][j]
        float v = (d < 128) ? mlpW1[j*HIDDEN + d] : mlpW1[(64+j)*HIDDEN + (d-128)];
        BT2u[d*72 + j] = bf16r(v);
      }
    }
  }
}

// K2: LayerNorm(node_x) -> H0 bf16-packed (lane l holds dims 2l,2l+1), s0, d0.
__launch_bounds__(256)
__global__ void k_node(const float* __restrict__ x, const float* __restrict__ g,
                       const float* __restrict__ bb, const float* __restrict__ W,
                       const float* __restrict__ asrc, const float* __restrict__ adst,
                       unsigned* __restrict__ H0u, float* __restrict__ S0o, float* __restrict__ D0o){
  int t = threadIdx.x;
  int w = t>>6, lane = t&63;
  float w0r[NODE_IN], w1r[NODE_IN];
  #pragma unroll
  for(int j=0;j<NODE_IN;j++){
    w0r[j] = W[j*HIDDEN + 2*lane];
    w1r[j] = W[j*HIDDEN + 2*lane + 1];
  }
  float gl = (lane<NODE_IN)? g[lane] : 0.f;
  float bl = (lane<NODE_IN)? bb[lane] : 0.f;
  float asl0 = asrc[2*lane], asl1 = asrc[2*lane+1];
  float adl0 = adst[2*lane], adl1 = adst[2*lane+1];
  for(int nb = blockIdx.x; nb < BN/4; nb += gridDim.x){
    int n = nb*4 + w;
    float xv = (lane<NODE_IN)? x[n*NODE_IN+lane] : 0.f;
    float s  = waveSum(xv);
    float s2 = waveSum(xv*xv);
    float mu = s*(1.f/NODE_IN);
    float var = s2*(1.f/NODE_IN) - mu*mu;
    float inv = 1.0f / sqrtf(var + 1e-5f);
    float nx = (lane<NODE_IN)? ((xv-mu)*inv*gl + bl) : 0.f;
    float a0=0.f, a1=0.f;
    #pragma unroll
    for(int j=0;j<NODE_IN;j++){
      float r = rlanef(nx, j);
      a0 += r*w0r[j];
      a1 += r*w1r[j];
    }
    H0u[(size_t)n*64 + lane] = pack_bf2(a0, a1);
    float sv = waveSum(a0*asl0 + a1*asl1);
    float dv = waveSum(a0*adl0 + a1*adl1);
    if(lane==0){ S0o[n]=sv; D0o[n]=dv; }
  }
}

// K3: LayerNorm(edge_attr) scattered into CSR position order
__launch_bounds__(256)
__global__ void k_edge(const float* __restrict__ ein, const float* __restrict__ g,
                       const float* __restrict__ bb, const float* __restrict__ wae,
                       const int* __restrict__ EPOS,
                       float* __restrict__ EAp, float* __restrict__ E0p, float* __restrict__ E1p){
  int ge = blockIdx.x*256 + threadIdx.x;   // < BE exactly
  int b = ge / EE, e = ge - b*EE;
  int gp = b*EE + EPOS[e];
  float v[EDGE_IN];
  const float4* p = (const float4*)(ein + (size_t)ge*EDGE_IN);
  float4 q0=p[0], q1=p[1], q2=p[2], q3=p[3];
  v[0]=q0.x; v[1]=q0.y; v[2]=q0.z; v[3]=q0.w;
  v[4]=q1.x; v[5]=q1.y; v[6]=q1.z; v[7]=q1.w;
  v[8]=q2.x; v[9]=q2.y; v[10]=q2.z; v[11]=q2.w;
  v[12]=q3.x; v[13]=q3.y; v[14]=q3.z; v[15]=q3.w;
  float s=0.f, s2=0.f;
  #pragma unroll
  for(int j=0;j<EDGE_IN;j++){ s += v[j]; s2 += v[j]*v[j]; }
  float mu = s*(1.f/EDGE_IN);
  float var = s2*(1.f/EDGE_IN) - mu*mu;
  float inv = 1.0f / sqrtf(var + 1e-5f);
  float e0=0.f, e1=0.f;
  #pragma unroll
  for(int j=0;j<EDGE_IN;j++){
    float nv = (v[j]-mu)*inv*g[j] + bb[j];
    v[j] = nv;
    e0 += nv*wae[j];
    e1 += nv*wae[16+j];
  }
  float4* q = (float4*)(EAp + (size_t)gp*EDGE_IN);
  q[0] = make_float4(v[0],v[1],v[2],v[3]);
  q[1] = make_float4(v[4],v[5],v[6],v[7]);
  q[2] = make_float4(v[8],v[9],v[10],v[11]);
  q[3] = make_float4(v[12],v[13],v[14],v[15]);
  E0p[gp]=e0; E1p[gp]=e1;
}

// K4b: histogram of dst
__global__ void k_count(const int* __restrict__ ei, int* __restrict__ cnt){
  int e = blockIdx.x*256 + threadIdx.x;
  if(e < EE) atomicAdd(&cnt[ei[EE+e]], 1);
}

// K4c: exclusive scan of 5000 counts
__launch_bounds__(1024)
__global__ void k_scan(int* __restrict__ off, int* __restrict__ cur){
  __shared__ int part[1024];
  int t = threadIdx.x;
  int loc[5]; int s=0;
  int base = t*5;
  #pragma unroll
  for(int k=0;k<5;k++){ int idx=base+k; int c=(idx<NN)? cur[idx]:0; loc[k]=s; s+=c; }
  part[t]=s;
  __syncthreads();
  for(int o=1;o<1024;o<<=1){
    int v = (t>=o)? part[t-o] : 0;
    __syncthreads();
    part[t] += v;
    __syncthreads();
  }
  int pre = (t>0)? part[t-1] : 0;
  #pragma unroll
  for(int k=0;k<5;k++){
    int idx=base+k;
    if(idx<NN){ int o2 = pre+loc[k]; off[idx]=o2; cur[idx]=o2; }
  }
  if(t==0) off[NN] = EE;
}

// K4d: scatter edges into CSR
__global__ void k_fill(const int* __restrict__ ei, int* __restrict__ cur,
                       int* __restrict__ csrc, int* __restrict__ cdst,
                       int* __restrict__ ceid, int* __restrict__ epos){
  int e = blockIdx.x*256 + threadIdx.x;
  if(e < EE){
    int d = ei[EE+e];
    int pos = atomicAdd(&cur[d], 1);
    csrc[pos] = ei[e];
    cdst[pos] = d;
    ceid[pos] = e;
    epos[e] = pos;
  }
}

// K5: GAT0 aggregation over bf16 H0 + ELU + fused S1/D1 epilogue. HELU out bf16-packed.
__launch_bounds__(256)
__global__ void k_gat0(const unsigned* __restrict__ H0u, const float* __restrict__ S0,
                       const float* __restrict__ D0, const float* __restrict__ E0p,
                       const int* __restrict__ off, const int* __restrict__ csrc,
                       const float* __restrict__ bias,
                       const float* __restrict__ WS1, const float* __restrict__ WD1,
                       unsigned* __restrict__ HELUu, float* __restrict__ S1o, float* __restrict__ D1o){
  int t = threadIdx.x, w = t>>6, lane = t&63;
  int b = blockIdx.x & 7, c = blockIdx.x >> 3;
  int n = c*4 + w;
  int gid = b*NN + n;
  int base = off[n], deg = off[n+1]-base;
  const float* s0b = S0 + b*NN;
  const float* e0b = E0p + b*EE;
  const unsigned* h0b = H0u + (size_t)b*NN*64;
  float dv = D0[gid];
  float acc0=0.f, acc1=0.f;
  if(deg > 0){
    if(deg <= 64){
      float lg = -INFINITY; int sidx = 0;
      if(lane < deg){
        sidx = csrc[base+lane];
        float xx = s0b[sidx] + dv + e0b[base+lane];
        lg = xx>0.f ? xx : 0.2f*xx;
      }
      float m = waveMax(lg);
      float ex = (lane<deg)? __expf(lg-m) : 0.f;
      float den = waveSum(ex);
      float al = ex / (den + 1e-16f);
      int nb8 = (deg+7)>>3;
      for(int b8=0;b8<nb8;b8++){
        int i0 = b8*8;
        int ss[8]; float aa[8]; unsigned hh[8];
        #pragma unroll
        for(int kk=0;kk<8;kk++){ ss[kk]=rlanei(sidx, i0+kk); aa[kk]=rlanef(al, i0+kk); }
        #pragma unroll
        for(int kk=0;kk<8;kk++){ hh[kk]=h0b[ss[kk]*64 + lane]; }
        #pragma unroll
        for(int kk=0;kk<8;kk++){ acc0 += aa[kk]*bflo(hh[kk]); acc1 += aa[kk]*bfhi(hh[kk]); }
      }
    } else {
      float m = -INFINITY;
      for(int i=lane;i<deg;i+=64){
        float xx = s0b[csrc[base+i]] + dv + e0b[base+i];
        xx = xx>0.f ? xx : 0.2f*xx;
        m = fmaxf(m, xx);
      }
      m = waveMax(m);
      float den = 0.f;
      for(int i=lane;i<deg;i+=64){
        float xx = s0b[csrc[base+i]] + dv + e0b[base+i];
        xx = xx>0.f ? xx : 0.2f*xx;
        den += __expf(xx-m);
      }
      den = waveSum(den) + 1e-16f;
      for(int i=0;i<deg;i++){
        int s = csrc[base+i];
        float xx = s0b[s] + dv + e0b[base+i];
        xx = xx>0.f ? xx : 0.2f*xx;
        float a = __expf(xx-m)/den;
        unsigned h = h0b[s*64 + lane];
        acc0 += a*bflo(h);
        acc1 += a*bfhi(h);
      }
    }
  }
  float2 bi = *(const float2*)&bias[2*lane];
  float v0 = acc0 + bi.x;
  float v1 = acc1 + bi.y;
  v0 = v0>0.f ? v0 : (__expf(v0)-1.f);
  v1 = v1>0.f ? v1 : (__expf(v1)-1.f);
  HELUu[(size_t)gid*64 + lane] = pack_bf2(v0, v1);
  float2 wsv = *(const float2*)&WS1[2*lane];
  float2 wdv = *(const float2*)&WD1[2*lane];
  float sv1 = waveSum(v0*wsv.x + v1*wsv.y);
  float dv1 = waveSum(v0*wdv.x + v1*wdv.y);
  if(lane==0){ S1o[gid]=sv1; D1o[gid]=dv1; }
}

// K6: H1 = HELU(40000x128 bf16) @ W1g(128x64) via MFMA. H1 out bf16 u16[n][64].
__launch_bounds__(256)
__global__ void k_h1(const unsigned* __restrict__ HELUu, const u16* __restrict__ BT1,
                     u16* __restrict__ H1u){
  __shared__ u16 Ald[64*136];
  __shared__ u16 Bld[64*136];
  int t = threadIdx.x;
  int n0 = blockIdx.x*64;
  // stage A: copy 64 rows x 64 dwords (already bf16 row-major)
  #pragma unroll
  for(int ii=0; ii<4; ii++){
    int c2 = ii*256 + t;               // 1024 uint4 chunks
    int r = c2 >> 4, q = c2 & 15;
    *(uint4*)&Ald[r*136 + q*8] = ((const uint4*)(HELUu + (size_t)(n0+r)*64))[q];
  }
  for(int i=t; i<1088; i+=256) ((uint4*)Bld)[i] = ((const uint4*)BT1)[i];
  __syncthreads();
  int w = t>>6, lane = t&63;
  int lo = lane & 15, hi = lane >> 4;
  f32x4 acc0 = {0.f,0.f,0.f,0.f}, acc1 = acc0, acc2 = acc0, acc3 = acc0;
  #pragma unroll
  for(int ks=0; ks<4; ks++){
    bf16x8 a = *(const bf16x8*)&Ald[(w*16+lo)*136 + ks*32 + hi*8];
    bf16x8 b0 = *(const bf16x8*)&Bld[(0*16+lo)*136 + ks*32 + hi*8];
    bf16x8 b1 = *(const bf16x8*)&Bld[(1*16+lo)*136 + ks*32 + hi*8];
    bf16x8 b2 = *(const bf16x8*)&Bld[(2*16+lo)*136 + ks*32 + hi*8];
    bf16x8 b3 = *(const bf16x8*)&Bld[(3*16+lo)*136 + ks*32 + hi*8];
    acc0 = __builtin_amdgcn_mfma_f32_16x16x32_bf16(a, b0, acc0, 0,0,0);
    acc1 = __builtin_amdgcn_mfma_f32_16x16x32_bf16(a, b1, acc1, 0,0,0);
    acc2 = __builtin_amdgcn_mfma_f32_16x16x32_bf16(a, b2, acc2, 0,0,0);
    acc3 = __builtin_amdgcn_mfma_f32_16x16x32_bf16(a, b3, acc3, 0,0,0);
  }
  int rowb = n0 + w*16 + hi*4;
  #pragma unroll
  for(int r=0;r<4;r++){
    H1u[(size_t)(rowb+r)*64 +  0 + lo] = bf16r(acc0[r]);
    H1u[(size_t)(rowb+r)*64 + 16 + lo] = bf16r(acc1[r]);
    H1u[(size_t)(rowb+r)*64 + 32 + lo] = bf16r(acc2[r]);
    H1u[(size_t)(rowb+r)*64 + 48 + lo] = bf16r(acc3[r]);
  }
}

// K7: GAT1 aggregation over bf16 H1.
__launch_bounds__(256)
__global__ void k_gat1(const u16* __restrict__ H1u, const float* __restrict__ S1,
                       const float* __restrict__ D1, const float* __restrict__ E1p,
                       const int* __restrict__ off, const int* __restrict__ csrc,
                       const float* __restrict__ bias, float* __restrict__ out){
  int t = threadIdx.x, w = t>>6, lane = t&63;
  int b = blockIdx.x & 7, c = blockIdx.x >> 3;
  int n = c*4 + w;
  int gid = b*NN + n;
  int base = off[n], deg = off[n+1]-base;
  const float* s1b = S1 + b*NN;
  const float* e1b = E1p + b*EE;
  const u16* h1b = H1u + (size_t)b*NN*64;
  float dv = D1[gid];
  float acc = 0.f;
  if(deg > 0){
    if(deg <= 64){
      float lg = -INFINITY; int sidx = 0;
      if(lane < deg){
        sidx = csrc[base+lane];
        float xx = s1b[sidx] + dv + e1b[base+lane];
        lg = xx>0.f ? xx : 0.2f*xx;
      }
      float m = waveMax(lg);
      float ex = (lane<deg)? __expf(lg-m) : 0.f;
      float den = waveSum(ex);
      float al = ex / (den + 1e-16f);
      int nb8 = (deg+7)>>3;
      for(int b8=0;b8<nb8;b8++){
        int i0 = b8*8;
        int ss[8]; float aa[8]; unsigned hh[8];
        #pragma unroll
        for(int kk=0;kk<8;kk++){ ss[kk]=rlanei(sidx, i0+kk); aa[kk]=rlanef(al, i0+kk); }
        #pragma unroll
        for(int kk=0;kk<8;kk++){ hh[kk]=h1b[ss[kk]*64 + lane]; }
        #pragma unroll
        for(int kk=0;kk<8;kk++){ acc += aa[kk]*__uint_as_float(hh[kk]<<16); }
      }
    } else {
      float m = -INFINITY;
      for(int i=lane;i<deg;i+=64){
        float xx = s1b[csrc[base+i]] + dv + e1b[base+i];
        xx = xx>0.f ? xx : 0.2f*xx;
        m = fmaxf(m, xx);
      }
      m = waveMax(m);
      float den = 0.f;
      for(int i=lane;i<deg;i+=64){
        float xx = s1b[csrc[base+i]] + dv + e1b[base+i];
        xx = xx>0.f ? xx : 0.2f*xx;
        den += __expf(xx-m);
      }
      den = waveSum(den) + 1e-16f;
      for(int i=0;i<deg;i++){
        int s = csrc[base+i];
        float xx = s1b[s] + dv + e1b[base+i];
        xx = xx>0.f ? xx : 0.2f*xx;
        float a = __expf(xx-m)/den;
        acc += a*__uint_as_float(((unsigned)h1b[s*64 + lane])<<16);
      }
    }
  }
  out[(size_t)gid*EMBED + lane] = acc + bias[lane];
}

// K8: per-graph mean/max pooling partials. 32 blocks per graph.
__launch_bounds__(256)
__global__ void k_pool(const float* __restrict__ EMBp, float* __restrict__ PSUM,
                       float* __restrict__ PMAX){
  int blk = blockIdx.x & 31, b = blockIdx.x >> 5;
  int t = threadIdx.x;
  int dim = t & 63, chunk = t >> 6;
  int n0 = blk*157, n1 = n0+157 < NN ? n0+157 : NN;
  float sm = 0.f, mx = -INFINITY;
  for(int n=n0+chunk; n<n1; n+=4){
    float v = EMBp[((size_t)(b*NN+n))*EMBED + dim];
    sm += v; mx = fmaxf(mx, v);
  }
  __shared__ float ssum[256], smax[256];
  ssum[t]=sm; smax[t]=mx;
  __syncthreads();
  if(t < 64){
    float S = ssum[t]+ssum[t+64]+ssum[t+128]+ssum[t+192];
    float M = fmaxf(fmaxf(smax[t],smax[t+64]), fmaxf(smax[t+128],smax[t+192]));
    PSUM[(b*32+blk)*64 + t] = S;
    PMAX[(b*32+blk)*64 + t] = M;
  }
}

// K9: reduce partials -> ctx; ctx_proj[b] = b1 + ctx[b] @ W1[144:272]
__launch_bounds__(128)
__global__ void k_ctxp(const float* __restrict__ PSUM, const float* __restrict__ PMAX,
                       const float* __restrict__ W1, const float* __restrict__ b1,
                       float* __restrict__ CTXP){
  int b = blockIdx.x, c = threadIdx.x;
  __shared__ float cl[128];
  if(c < 64){
    float S = 0.f;
    for(int k=0;k<32;k++) S += PSUM[(b*32+k)*64 + c];
    cl[c] = S*(1.f/NN);
  } else {
    float M = -INFINITY;
    for(int k=0;k<32;k++) M = fmaxf(M, PMAX[(b*32+k)*64 + (c-64)]);
    cl[c] = M;
  }
  __syncthreads();
  float a = b1[c];
  for(int j=0;j<128;j++) a += cl[j]*W1[(144+j)*HIDDEN + c];
  CTXP[b*128+c] = a;
}

// K10: PS/PD = EMB(40000x64) @ BT2^T via MFMA; bf16 u16[n][128].
__launch_bounds__(256)
__global__ void k_psd(const float* __restrict__ EMB, const u16* __restrict__ BT2,
                      u16* __restrict__ PSu, u16* __restrict__ PDu){
  __shared__ u16 Ald[64*72];
  __shared__ u16 Bld[256*72];
  int t = threadIdx.x;
  int n0 = blockIdx.x*64;
  #pragma unroll
  for(int ii=0; ii<2; ii++){
    int c2 = ii*256 + t;
    int r = c2 >> 3, q = c2 & 7;
    const float4* src = (const float4*)(EMB + (size_t)(n0+r)*EMBED + q*8);
    float4 f0 = src[0], f1 = src[1];
    uint4 pk = make_uint4(pack_bf2(f0.x,f0.y), pack_bf2(f0.z,f0.w),
                          pack_bf2(f1.x,f1.y), pack_bf2(f1.z,f1.w));
    *(uint4*)&Ald[r*72 + q*8] = pk;
  }
  for(int i=t; i<2304; i+=256) ((uint4*)Bld)[i] = ((const uint4*)BT2)[i];
  __syncthreads();
  int w = t>>6, lane = t&63;
  int lo = lane & 15, hi = lane >> 4;
  f32x4 acc[16];
  #pragma unroll
  for(int i=0;i<16;i++) acc[i] = (f32x4){0.f,0.f,0.f,0.f};
  #pragma unroll
  for(int ks=0; ks<2; ks++){
    bf16x8 a = *(const bf16x8*)&Ald[(w*16+lo)*72 + ks*32 + hi*8];
    #pragma unroll
    for(int nt=0; nt<16; nt++){
      bf16x8 b = *(const bf16x8*)&Bld[(nt*16+lo)*72 + ks*32 + hi*8];
      acc[nt] = __builtin_amdgcn_mfma_f32_16x16x32_bf16(a, b, acc[nt], 0,0,0);
    }
  }
  int rowb = n0 + w*16 + hi*4;
  #pragma unroll
  for(int nt=0; nt<16; nt++){
    #pragma unroll
    for(int r=0;r<4;r++){
      u16 u = bf16r(acc[nt][r]);
      if(nt < 8) PSu[(size_t)(rowb+r)*HIDDEN + nt*16 + lo] = u;
      else       PDu[(size_t)(rowb+r)*HIDDEN + (nt-8)*16 + lo] = u;
    }
  }
}

// K11: per-edge MLP. EA in VGPRs + compile-time readlane broadcasts (zero LDS).
__launch_bounds__(256)
__global__ void k_final(const float* __restrict__ EAp, const int* __restrict__ csrc,
                        const int* __restrict__ cdst, const int* __restrict__ ceid,
                        const unsigned* __restrict__ PS, const unsigned* __restrict__ PD,
                        const float* __restrict__ CTXP, const float* __restrict__ W1,
                        const float* __restrict__ W2, const float* __restrict__ b2,
                        float* __restrict__ out){
  int t = threadIdx.x, w = t>>6, lane = t&63;
  int b = blockIdx.x & 7, c = blockIdx.x >> 3;
  int p0 = c*128 + w*32;
  float w1r0[16], w1r1[16];
  #pragma unroll
  for(int j=0;j<16;j++){
    float2 wv = *(const float2*)&W1[(128+j)*HIDDEN + 2*lane];
    w1r0[j]=wv.x; w1r1[j]=wv.y;
  }
  float2 w2v = *(const float2*)&W2[2*lane];
  float2 cpv = *(const float2*)&CTXP[b*128 + 2*lane];
  float bias2 = b2[0];
  int sv=0, dvv=0, ev=0;
  if(lane<32){ sv=csrc[p0+lane]; dvv=cdst[p0+lane]; ev=ceid[p0+lane]; }
  const unsigned* PSb = PS + (size_t)b*NN*64;
  const unsigned* PDb = PD + (size_t)b*NN*64;
  // wave's 32 edges x 16 feats into 8 VGPRs/lane: lane l holds flats 8l..8l+7
  const float4* EAsrc = (const float4*)(EAp + ((size_t)b*EE + p0)*EDGE_IN);
  float4 f0 = EAsrc[2*lane], f1 = EAsrc[2*lane+1];
  float fr[8] = {f0.x,f0.y,f0.z,f0.w, f1.x,f1.y,f1.z,f1.w};
  float myq = 0.f;
  #pragma unroll
  for(int g=0; g<8; g++){
    int i0 = g*4;
    int ss[4], dd[4];
    #pragma unroll
    for(int kk=0;kk<4;kk++){ ss[kk]=rlanei(sv, i0+kk); dd[kk]=rlanei(dvv, i0+kk); }
    unsigned ps[4], pd[4];
    #pragma unroll
    for(int kk=0;kk<4;kk++){ ps[kk]=PSb[ss[kk]*64 + lane]; }
    #pragma unroll
    for(int kk=0;kk<4;kk++){ pd[kk]=PDb[dd[kk]*64 + lane]; }
    float p[4];
    #pragma unroll
    for(int kk=0;kk<4;kk++){
      float h0 = cpv.x + bflo(ps[kk]) + bflo(pd[kk]);
      float h1 = cpv.y + bfhi(ps[kk]) + bfhi(pd[kk]);
      #pragma unroll
      for(int j=0;j<16;j++){
        int flat = (i0+kk)*16 + j;               // compile-time
        float aj = rlanef(fr[flat & 7], flat >> 3);
        h0 += aj*w1r0[j];
        h1 += aj*w1r1[j];
      }
      h0 = fmaxf(h0, 0.f);
      h1 = fmaxf(h1, 0.f);
      p[kk] = h0*w2v.x + h1*w2v.y;
    }
    #pragma unroll
    for(int kk=0;kk<4;kk++){
      p[kk] += __shfl_xor(p[kk], 32);
      p[kk] += __shfl_xor(p[kk], 16);
    }
    int q = lane>>4;
    float sel = (q==0)? p[0] : (q==1)? p[1] : (q==2)? p[2] : p[3];
    sel += __shfl_xor(sel, 8);
    sel += __shfl_xor(sel, 4);
    sel += __shfl_xor(sel, 2);
    sel += __shfl_xor(sel, 1);
    #pragma unroll
    for(int kk=0;kk<4;kk++){
      float tot = rlanef(sel, kk*16);
      if(lane == i0+kk) myq = tot;
    }
  }
  if(lane < 32) out[(size_t)b*EE + ev] = myq + bias2;
}

extern "C" void kernel_launch(void* const* d_in, const int* in_sizes, int n_in,
                              void* d_out, int out_size, void* d_ws, size_t ws_size,
                              hipStream_t stream) {
  const float* node_x   = (const float*)d_in[0];
  const float* edge_attr= (const float*)d_in[1];
  const int*   edge_idx = (const int*)d_in[2];
  const float* ln_ng    = (const float*)d_in[3];
  const float* ln_nb    = (const float*)d_in[4];
  const float* ln_eg    = (const float*)d_in[5];
  const float* ln_eb    = (const float*)d_in[6];
  const float* g0_W     = (const float*)d_in[7];
  const float* g0_We    = (const float*)d_in[8];
  const float* g0_asrc  = (const float*)d_in[9];
  const float* g0_adst  = (const float*)d_in[10];
  const float* g0_ae    = (const float*)d_in[11];
  const float* g0_b     = (const float*)d_in[12];
  const float* g1_W     = (const float*)d_in[13];
  const float* g1_We    = (const float*)d_in[14];
  const float* g1_asrc  = (const float*)d_in[15];
  const float* g1_adst  = (const float*)d_in[16];
  const float* g1_ae    = (const float*)d_in[17];
  const float* g1_b     = (const float*)d_in[18];
  const float* mlp_W1   = (const float*)d_in[19];
  const float* mlp_b1   = (const float*)d_in[20];
  const float* mlp_W2   = (const float*)d_in[21];
  const float* mlp_b2   = (const float*)d_in[22];
  float* out = (float*)d_out;

  // workspace layout (32-bit words)
  float* ws   = (float*)d_ws;
  float* EAp  = ws;                       // 10,240,000
  float* E0p  = EAp  + (size_t)BE*EDGE_IN;// 640,000
  float* E1p  = E0p  + BE;                // 640,000
  float* H0   = E1p  + BE;                // region (5,120,000 fl) — H0u then PS
  float* HELU = H0   + (size_t)BN*HIDDEN; // region (5,120,000 fl) — HELUu then PD
  float* H1   = HELU + (size_t)BN*HIDDEN; // region (2,560,000 fl) — H1u16
  float* EMBa = H1   + (size_t)BN*EMBED;  // 2,560,000
  float* S0   = EMBa + (size_t)BN*EMBED;  // 40,000
  float* D0   = S0 + BN;
  float* S1   = D0 + BN;
  float* D1   = S1 + BN;
  float* CTX  = D1 + BN;                  // 1024 (unused now)
  float* CTXP = CTX + 1024;               // 1024
  float* WAE  = CTXP + 1024;              // 32
  int* CSR_OFF = (int*)(WAE + 32);        // 5004
  int* CSR_CUR = CSR_OFF + (NN+4);        // 5000
  int* CSR_SRC = CSR_CUR + NN;            // 80000
  int* CSR_DST = CSR_SRC + EE;            // 80000
  int* CSR_EID = CSR_DST + EE;            // 80000
  int* EPOS    = CSR_EID + EE;            // 80000
  float* WS1   = (float*)(EPOS + EE);     // 128
  float* WD1   = WS1 + 128;               // 128
  u16* BT1u    = (u16*)(WD1 + 128);       // 4352 dwords
  u16* BT2u    = BT1u + 64*136;           // 9216 dwords
  float* PSUM  = (float*)(BT2u + 256*72); // 16384
  float* PMAX  = PSUM + 256*64;           // 16384
  unsigned* H0u   = (unsigned*)H0;        // BN*64 dwords
  unsigned* HELUu = (unsigned*)HELU;      // BN*64 dwords
  u16*      H1u   = (u16*)H1;             // BN*64 u16
  unsigned* PS = (unsigned*)H0;           // bf16 pairs (after H0u consumed)
  unsigned* PD = (unsigned*)HELU;

  hipMemsetAsync(CSR_CUR, 0, NN*sizeof(int), stream);
  k_prep<<<17, 256, 0, stream>>>(g0_We, g0_ae, g1_We, g1_ae, g1_W, g1_asrc, g1_adst,
                                 mlp_W1, WAE, WS1, WD1, BT1u, BT2u);
  k_count<<<(EE+255)/256, 256, 0, stream>>>(edge_idx, CSR_CUR);
  k_scan<<<1, 1024, 0, stream>>>(CSR_OFF, CSR_CUR);
  k_fill<<<(EE+255)/256, 256, 0, stream>>>(edge_idx, CSR_CUR, CSR_SRC, CSR_DST, CSR_EID, EPOS);
  k_node<<<1024, 256, 0, stream>>>(node_x, ln_ng, ln_nb, g0_W, g0_asrc, g0_adst, H0u, S0, D0);
  k_edge<<<BE/256, 256, 0, stream>>>(edge_attr, ln_eg, ln_eb, WAE, EPOS, EAp, E0p, E1p);
  k_gat0<<<BN/4, 256, 0, stream>>>(H0u, S0, D0, E0p, CSR_OFF, CSR_SRC, g0_b, WS1, WD1, HELUu, S1, D1);
  k_h1<<<BN/64, 256, 0, stream>>>(HELUu, BT1u, H1u);
  k_gat1<<<BN/4, 256, 0, stream>>>(H1u, S1, D1, E1p, CSR_OFF, CSR_SRC, g1_b, EMBa);
  k_pool<<<256, 256, 0, stream>>>(EMBa, PSUM, PMAX);
  k_ctxp<<<BB, 128, 0, stream>>>(PSUM, PMAX, mlp_W1, mlp_b1, CTXP);
  k_psd<<<BN/64, 256, 0, stream>>>(EMBa, BT2u, (u16*)PS, (u16*)PD);
  k_final<<<BE/128, 256, 0, stream>>>(EAp, CSR_SRC, CSR_DST, CSR_EID, PS, PD, CTXP, mlp_W1, mlp_W2, mlp_b2, out);
}

// Round 8
// 336.136 us; speedup vs baseline: 1.9217x; 1.0780x over previous
//
#include <hip/hip_runtime.h>
#include <cmath>

#define BB 8
#define NN 5000
#define EE 80000
#define NODE_IN 32
#define EDGE_IN 16
#define HIDDEN 128
#define EMBED 64
#define BN (BB*NN)     // 40000
#define BE (BB*EE)     // 640000

typedef unsigned short u16;
typedef __attribute__((ext_vector_type(8))) __bf16 bf16x8;
typedef __attribute__((ext_vector_type(4))) float f32x4;

__device__ __forceinline__ float waveSum(float v){
  #pragma unroll
  for(int o=32;o;o>>=1) v += __shfl_xor(v,o);
  return v;
}
__device__ __forceinline__ float waveMax(float v){
  #pragma unroll
  for(int o=32;o;o>>=1) v = fmaxf(v,__shfl_xor(v,o));
  return v;
}
__device__ __forceinline__ int rlanei(int v, int l){
  return __builtin_amdgcn_readlane(v, l);
}
__device__ __forceinline__ float rlanef(float v, int l){
  return __uint_as_float(__builtin_amdgcn_readlane(__float_as_uint(v), l));
}
__device__ __forceinline__ unsigned pack_bf2(float a0, float a1){
  unsigned u0 = __float_as_uint(a0), u1 = __float_as_uint(a1);
  unsigned r0 = (u0 + 0x7fffu + ((u0>>16)&1u)) >> 16;
  unsigned r1 = (u1 + 0x7fffu + ((u1>>16)&1u)) & 0xffff0000u;
  return r0 | r1;
}
__device__ __forceinline__ u16 bf16r(float x){
  unsigned u = __float_as_uint(x);
  return (u16)((u + 0x7fffu + ((u>>16)&1u)) >> 16);
}
__device__ __forceinline__ float bflo(unsigned h){ return __uint_as_float(h<<16); }
__device__ __forceinline__ float bfhi(unsigned h){ return __uint_as_float(h & 0xffff0000u); }
__device__ __forceinline__ bf16x8 ld8_or_zero(const u16* p, bool pred){
  uint4 v = pred ? *(const uint4*)p : make_uint4(0u,0u,0u,0u);
  return *(bf16x8*)&v;
}

// K1: prep — wae, w_s1/w_d1, BT1 [64][136] bf16, BT2 [256][72] bf16, AT1e [128][16] bf16
__launch_bounds__(256)
__global__ void k_prep(const float* We0, const float* ae0,
                       const float* We1, const float* ae1,
                       const float* W1g, const float* asrc1, const float* adst1,
                       const float* mlpW1,
                       float* wae, float* ws1, float* wd1,
                       u16* BT1u, u16* BT2u, u16* AT1e){
  int t = threadIdx.x;
  if(blockIdx.x == 0){
    if(t < 16){
      float a = 0.f;
      for(int k=0;k<HIDDEN;k++) a += We0[t*HIDDEN+k]*ae0[k];
      wae[t] = a;
    } else if(t < 32){
      int j = t-16;
      float a = 0.f;
      for(int k=0;k<EMBED;k++) a += We1[j*EMBED+k]*ae1[k];
      wae[16+j] = a;
    }
    if(t < 128){
      float s = 0.f, d = 0.f;
      for(int k=0;k<EMBED;k++){
        float w = W1g[t*EMBED+k];
        s += w*asrc1[k];
        d += w*adst1[k];
      }
      ws1[t] = s; wd1[t] = d;
    }
    // AT1e[out][k] = W1[(128+k)*HIDDEN + out], 128x16
    for(int i=t; i<2048; i+=256){
      int o = i >> 4, k = i & 15;
      AT1e[o*16 + k] = bf16r(mlpW1[(128+k)*HIDDEN + o]);
    }
  } else {
    #pragma unroll
    for(int ii=0; ii<6; ii++){
      int idx = (blockIdx.x-1)*1536 + ii*256 + t;
      if(idx < 8192){
        int c = idx >> 7, k = idx & 127;           // BT1[c][k] = W1g[k][c]
        BT1u[c*136 + k] = bf16r(W1g[k*EMBED + c]);
      } else {
        int i2 = idx - 8192;
        int d = i2 >> 6, j = i2 & 63;              // BT2[d][j]
        float v = (d < 128) ? mlpW1[j*HIDDEN + d] : mlpW1[(64+j)*HIDDEN + (d-128)];
        BT2u[d*72 + j] = bf16r(v);
      }
    }
  }
}

// K2: LayerNorm(node_x) -> H0 bf16-packed (lane l holds dims 2l,2l+1), s0, d0.
__launch_bounds__(256)
__global__ void k_node(const float* __restrict__ x, const float* __restrict__ g,
                       const float* __restrict__ bb, const float* __restrict__ W,
                       const float* __restrict__ asrc, const float* __restrict__ adst,
                       unsigned* __restrict__ H0u, float* __restrict__ S0o, float* __restrict__ D0o){
  int t = threadIdx.x;
  int w = t>>6, lane = t&63;
  float w0r[NODE_IN], w1r[NODE_IN];
  #pragma unroll
  for(int j=0;j<NODE_IN;j++){
    w0r[j] = W[j*HIDDEN + 2*lane];
    w1r[j] = W[j*HIDDEN + 2*lane + 1];
  }
  float gl = (lane<NODE_IN)? g[lane] : 0.f;
  float bl = (lane<NODE_IN)? bb[lane] : 0.f;
  float asl0 = asrc[2*lane], asl1 = asrc[2*lane+1];
  float adl0 = adst[2*lane], adl1 = adst[2*lane+1];
  for(int nb = blockIdx.x; nb < BN/4; nb += gridDim.x){
    int n = nb*4 + w;
    float xv = (lane<NODE_IN)? x[n*NODE_IN+lane] : 0.f;
    float s  = waveSum(xv);
    float s2 = waveSum(xv*xv);
    float mu = s*(1.f/NODE_IN);
    float var = s2*(1.f/NODE_IN) - mu*mu;
    float inv = 1.0f / sqrtf(var + 1e-5f);
    float nx = (lane<NODE_IN)? ((xv-mu)*inv*gl + bl) : 0.f;
    float a0=0.f, a1=0.f;
    #pragma unroll
    for(int j=0;j<NODE_IN;j++){
      float r = rlanef(nx, j);
      a0 += r*w0r[j];
      a1 += r*w1r[j];
    }
    H0u[(size_t)n*64 + lane] = pack_bf2(a0, a1);
    float sv = waveSum(a0*asl0 + a1*asl1);
    float dv = waveSum(a0*adl0 + a1*adl1);
    if(lane==0){ S0o[n]=sv; D0o[n]=dv; }
  }
}

// K3: LayerNorm(edge_attr) scattered into CSR position order; EA out bf16 [edge][16]
__launch_bounds__(256)
__global__ void k_edge(const float* __restrict__ ein, const float* __restrict__ g,
                       const float* __restrict__ bb, const float* __restrict__ wae,
                       const int* __restrict__ EPOS,
                       u16* __restrict__ EAb, float* __restrict__ E0p, float* __restrict__ E1p){
  int ge = blockIdx.x*256 + threadIdx.x;   // < BE exactly
  int b = ge / EE, e = ge - b*EE;
  int gp = b*EE + EPOS[e];
  float v[EDGE_IN];
  const float4* p = (const float4*)(ein + (size_t)ge*EDGE_IN);
  float4 q0=p[0], q1=p[1], q2=p[2], q3=p[3];
  v[0]=q0.x; v[1]=q0.y; v[2]=q0.z; v[3]=q0.w;
  v[4]=q1.x; v[5]=q1.y; v[6]=q1.z; v[7]=q1.w;
  v[8]=q2.x; v[9]=q2.y; v[10]=q2.z; v[11]=q2.w;
  v[12]=q3.x; v[13]=q3.y; v[14]=q3.z; v[15]=q3.w;
  float s=0.f, s2=0.f;
  #pragma unroll
  for(int j=0;j<EDGE_IN;j++){ s += v[j]; s2 += v[j]*v[j]; }
  float mu = s*(1.f/EDGE_IN);
  float var = s2*(1.f/EDGE_IN) - mu*mu;
  float inv = 1.0f / sqrtf(var + 1e-5f);
  float e0=0.f, e1=0.f;
  #pragma unroll
  for(int j=0;j<EDGE_IN;j++){
    float nv = (v[j]-mu)*inv*g[j] + bb[j];
    v[j] = nv;
    e0 += nv*wae[j];
    e1 += nv*wae[16+j];
  }
  uint4 w0 = make_uint4(pack_bf2(v[0],v[1]), pack_bf2(v[2],v[3]),
                        pack_bf2(v[4],v[5]), pack_bf2(v[6],v[7]));
  uint4 w1 = make_uint4(pack_bf2(v[8],v[9]), pack_bf2(v[10],v[11]),
                        pack_bf2(v[12],v[13]), pack_bf2(v[14],v[15]));
  uint4* q = (uint4*)&EAb[(size_t)gp*16];
  q[0] = w0; q[1] = w1;
  E0p[gp]=e0; E1p[gp]=e1;
}

// K4b: histogram of dst
__global__ void k_count(const int* __restrict__ ei, int* __restrict__ cnt){
  int e = blockIdx.x*256 + threadIdx.x;
  if(e < EE) atomicAdd(&cnt[ei[EE+e]], 1);
}

// K4c: exclusive scan of 5000 counts
__launch_bounds__(1024)
__global__ void k_scan(int* __restrict__ off, int* __restrict__ cur){
  __shared__ int part[1024];
  int t = threadIdx.x;
  int loc[5]; int s=0;
  int base = t*5;
  #pragma unroll
  for(int k=0;k<5;k++){ int idx=base+k; int c=(idx<NN)? cur[idx]:0; loc[k]=s; s+=c; }
  part[t]=s;
  __syncthreads();
  for(int o=1;o<1024;o<<=1){
    int v = (t>=o)? part[t-o] : 0;
    __syncthreads();
    part[t] += v;
    __syncthreads();
  }
  int pre = (t>0)? part[t-1] : 0;
  #pragma unroll
  for(int k=0;k<5;k++){
    int idx=base+k;
    if(idx<NN){ int o2 = pre+loc[k]; off[idx]=o2; cur[idx]=o2; }
  }
  if(t==0) off[NN] = EE;
}

// K4d: scatter edges into CSR
__global__ void k_fill(const int* __restrict__ ei, int* __restrict__ cur,
                       int* __restrict__ csrc, int* __restrict__ cdst,
                       int* __restrict__ ceid, int* __restrict__ epos){
  int e = blockIdx.x*256 + threadIdx.x;
  if(e < EE){
    int d = ei[EE+e];
    int pos = atomicAdd(&cur[d], 1);
    csrc[pos] = ei[e];
    cdst[pos] = d;
    ceid[pos] = e;
    epos[e] = pos;
  }
}

// K5: GAT0 aggregation over bf16 H0 + ELU + fused S1/D1 epilogue.
__launch_bounds__(256)
__global__ void k_gat0(const unsigned* __restrict__ H0u, const float* __restrict__ S0,
                       const float* __restrict__ D0, const float* __restrict__ E0p,
                       const int* __restrict__ off, const int* __restrict__ csrc,
                       const float* __restrict__ bias,
                       const float* __restrict__ WS1, const float* __restrict__ WD1,
                       unsigned* __restrict__ HELUu, float* __restrict__ S1o, float* __restrict__ D1o){
  int t = threadIdx.x, w = t>>6, lane = t&63;
  int b = blockIdx.x & 7, c = blockIdx.x >> 3;
  int n = c*4 + w;
  int gid = b*NN + n;
  int base = off[n], deg = off[n+1]-base;
  const float* s0b = S0 + b*NN;
  const float* e0b = E0p + b*EE;
  const unsigned* h0b = H0u + (size_t)b*NN*64;
  float dv = D0[gid];
  float acc0=0.f, acc1=0.f;
  if(deg > 0){
    if(deg <= 64){
      float lg = -INFINITY; int sidx = 0;
      if(lane < deg){
        sidx = csrc[base+lane];
        float xx = s0b[sidx] + dv + e0b[base+lane];
        lg = xx>0.f ? xx : 0.2f*xx;
      }
      float m = waveMax(lg);
      float ex = (lane<deg)? __expf(lg-m) : 0.f;
      float den = waveSum(ex);
      float al = ex / (den + 1e-16f);
      int nb8 = (deg+7)>>3;
      for(int b8=0;b8<nb8;b8++){
        int i0 = b8*8;
        int ss[8]; float aa[8]; unsigned hh[8];
        #pragma unroll
        for(int kk=0;kk<8;kk++){ ss[kk]=rlanei(sidx, i0+kk); aa[kk]=rlanef(al, i0+kk); }
        #pragma unroll
        for(int kk=0;kk<8;kk++){ hh[kk]=h0b[ss[kk]*64 + lane]; }
        #pragma unroll
        for(int kk=0;kk<8;kk++){ acc0 += aa[kk]*bflo(hh[kk]); acc1 += aa[kk]*bfhi(hh[kk]); }
      }
    } else {
      float m = -INFINITY;
      for(int i=lane;i<deg;i+=64){
        float xx = s0b[csrc[base+i]] + dv + e0b[base+i];
        xx = xx>0.f ? xx : 0.2f*xx;
        m = fmaxf(m, xx);
      }
      m = waveMax(m);
      float den = 0.f;
      for(int i=lane;i<deg;i+=64){
        float xx = s0b[csrc[base+i]] + dv + e0b[base+i];
        xx = xx>0.f ? xx : 0.2f*xx;
        den += __expf(xx-m);
      }
      den = waveSum(den) + 1e-16f;
      for(int i=0;i<deg;i++){
        int s = csrc[base+i];
        float xx = s0b[s] + dv + e0b[base+i];
        xx = xx>0.f ? xx : 0.2f*xx;
        float a = __expf(xx-m)/den;
        unsigned h = h0b[s*64 + lane];
        acc0 += a*bflo(h);
        acc1 += a*bfhi(h);
      }
    }
  }
  float2 bi = *(const float2*)&bias[2*lane];
  float v0 = acc0 + bi.x;
  float v1 = acc1 + bi.y;
  v0 = v0>0.f ? v0 : (__expf(v0)-1.f);
  v1 = v1>0.f ? v1 : (__expf(v1)-1.f);
  HELUu[(size_t)gid*64 + lane] = pack_bf2(v0, v1);
  float2 wsv = *(const float2*)&WS1[2*lane];
  float2 wdv = *(const float2*)&WD1[2*lane];
  float sv1 = waveSum(v0*wsv.x + v1*wsv.y);
  float dv1 = waveSum(v0*wdv.x + v1*wdv.y);
  if(lane==0){ S1o[gid]=sv1; D1o[gid]=dv1; }
}

// K6: H1 = HELU(40000x128 bf16) @ W1g(128x64) via MFMA. H1 out bf16 u16[n][64].
__launch_bounds__(256)
__global__ void k_h1(const unsigned* __restrict__ HELUu, const u16* __restrict__ BT1,
                     u16* __restrict__ H1u){
  __shared__ u16 Ald[64*136];
  __shared__ u16 Bld[64*136];
  int t = threadIdx.x;
  int n0 = blockIdx.x*64;
  #pragma unroll
  for(int ii=0; ii<4; ii++){
    int c2 = ii*256 + t;               // 1024 uint4 chunks
    int r = c2 >> 4, q = c2 & 15;
    *(uint4*)&Ald[r*136 + q*8] = ((const uint4*)(HELUu + (size_t)(n0+r)*64))[q];
  }
  for(int i=t; i<1088; i+=256) ((uint4*)Bld)[i] = ((const uint4*)BT1)[i];
  __syncthreads();
  int w = t>>6, lane = t&63;
  int lo = lane & 15, hi = lane >> 4;
  f32x4 acc0 = {0.f,0.f,0.f,0.f}, acc1 = acc0, acc2 = acc0, acc3 = acc0;
  #pragma unroll
  for(int ks=0; ks<4; ks++){
    bf16x8 a = *(const bf16x8*)&Ald[(w*16+lo)*136 + ks*32 + hi*8];
    bf16x8 b0 = *(const bf16x8*)&Bld[(0*16+lo)*136 + ks*32 + hi*8];
    bf16x8 b1 = *(const bf16x8*)&Bld[(1*16+lo)*136 + ks*32 + hi*8];
    bf16x8 b2 = *(const bf16x8*)&Bld[(2*16+lo)*136 + ks*32 + hi*8];
    bf16x8 b3 = *(const bf16x8*)&Bld[(3*16+lo)*136 + ks*32 + hi*8];
    acc0 = __builtin_amdgcn_mfma_f32_16x16x32_bf16(a, b0, acc0, 0,0,0);
    acc1 = __builtin_amdgcn_mfma_f32_16x16x32_bf16(a, b1, acc1, 0,0,0);
    acc2 = __builtin_amdgcn_mfma_f32_16x16x32_bf16(a, b2, acc2, 0,0,0);
    acc3 = __builtin_amdgcn_mfma_f32_16x16x32_bf16(a, b3, acc3, 0,0,0);
  }
  int rowb = n0 + w*16 + hi*4;
  #pragma unroll
  for(int r=0;r<4;r++){
    H1u[(size_t)(rowb+r)*64 +  0 + lo] = bf16r(acc0[r]);
    H1u[(size_t)(rowb+r)*64 + 16 + lo] = bf16r(acc1[r]);
    H1u[(size_t)(rowb+r)*64 + 32 + lo] = bf16r(acc2[r]);
    H1u[(size_t)(rowb+r)*64 + 48 + lo] = bf16r(acc3[r]);
  }
}

// K7: GAT1 aggregation over bf16 H1.
__launch_bounds__(256)
__global__ void k_gat1(const u16* __restrict__ H1u, const float* __restrict__ S1,
                       const float* __restrict__ D1, const float* __restrict__ E1p,
                       const int* __restrict__ off, const int* __restrict__ csrc,
                       const float* __restrict__ bias, float* __restrict__ out){
  int t = threadIdx.x, w = t>>6, lane = t&63;
  int b = blockIdx.x & 7, c = blockIdx.x >> 3;
  int n = c*4 + w;
  int gid = b*NN + n;
  int base = off[n], deg = off[n+1]-base;
  const float* s1b = S1 + b*NN;
  const float* e1b = E1p + b*EE;
  const u16* h1b = H1u + (size_t)b*NN*64;
  float dv = D1[gid];
  float acc = 0.f;
  if(deg > 0){
    if(deg <= 64){
      float lg = -INFINITY; int sidx = 0;
      if(lane < deg){
        sidx = csrc[base+lane];
        float xx = s1b[sidx] + dv + e1b[base+lane];
        lg = xx>0.f ? xx : 0.2f*xx;
      }
      float m = waveMax(lg);
      float ex = (lane<deg)? __expf(lg-m) : 0.f;
      float den = waveSum(ex);
      float al = ex / (den + 1e-16f);
      int nb8 = (deg+7)>>3;
      for(int b8=0;b8<nb8;b8++){
        int i0 = b8*8;
        int ss[8]; float aa[8]; unsigned hh[8];
        #pragma unroll
        for(int kk=0;kk<8;kk++){ ss[kk]=rlanei(sidx, i0+kk); aa[kk]=rlanef(al, i0+kk); }
        #pragma unroll
        for(int kk=0;kk<8;kk++){ hh[kk]=h1b[ss[kk]*64 + lane]; }
        #pragma unroll
        for(int kk=0;kk<8;kk++){ acc += aa[kk]*__uint_as_float(hh[kk]<<16); }
      }
    } else {
      float m = -INFINITY;
      for(int i=lane;i<deg;i+=64){
        float xx = s1b[csrc[base+i]] + dv + e1b[base+i];
        xx = xx>0.f ? xx : 0.2f*xx;
        m = fmaxf(m, xx);
      }
      m = waveMax(m);
      float den = 0.f;
      for(int i=lane;i<deg;i+=64){
        float xx = s1b[csrc[base+i]] + dv + e1b[base+i];
        xx = xx>0.f ? xx : 0.2f*xx;
        den += __expf(xx-m);
      }
      den = waveSum(den) + 1e-16f;
      for(int i=0;i<deg;i++){
        int s = csrc[base+i];
        float xx = s1b[s] + dv + e1b[base+i];
        xx = xx>0.f ? xx : 0.2f*xx;
        float a = __expf(xx-m)/den;
        acc += a*__uint_as_float(((unsigned)h1b[s*64 + lane])<<16);
      }
    }
  }
  out[(size_t)gid*EMBED + lane] = acc + bias[lane];
}

// K8: per-graph mean/max pooling partials. 32 blocks per graph.
__launch_bounds__(256)
__global__ void k_pool(const float* __restrict__ EMBp, float* __restrict__ PSUM,
                       float* __restrict__ PMAX){
  int blk = blockIdx.x & 31, b = blockIdx.x >> 5;
  int t = threadIdx.x;
  int dim = t & 63, chunk = t >> 6;
  int n0 = blk*157, n1 = n0+157 < NN ? n0+157 : NN;
  float sm = 0.f, mx = -INFINITY;
  for(int n=n0+chunk; n<n1; n+=4){
    float v = EMBp[((size_t)(b*NN+n))*EMBED + dim];
    sm += v; mx = fmaxf(mx, v);
  }
  __shared__ float ssum[256], smax[256];
  ssum[t]=sm; smax[t]=mx;
  __syncthreads();
  if(t < 64){
    float S = ssum[t]+ssum[t+64]+ssum[t+128]+ssum[t+192];
    float M = fmaxf(fmaxf(smax[t],smax[t+64]), fmaxf(smax[t+128],smax[t+192]));
    PSUM[(b*32+blk)*64 + t] = S;
    PMAX[(b*32+blk)*64 + t] = M;
  }
}

// K9: reduce partials -> ctx; ctx_proj[b] = b1 + ctx[b] @ W1[144:272]
__launch_bounds__(128)
__global__ void k_ctxp(const float* __restrict__ PSUM, const float* __restrict__ PMAX,
                       const float* __restrict__ W1, const float* __restrict__ b1,
                       float* __restrict__ CTXP){
  int b = blockIdx.x, c = threadIdx.x;
  __shared__ float cl[128];
  if(c < 64){
    float S = 0.f;
    for(int k=0;k<32;k++) S += PSUM[(b*32+k)*64 + c];
    cl[c] = S*(1.f/NN);
  } else {
    float M = -INFINITY;
    for(int k=0;k<32;k++) M = fmaxf(M, PMAX[(b*32+k)*64 + (c-64)]);
    cl[c] = M;
  }
  __syncthreads();
  float a = b1[c];
  for(int j=0;j<128;j++) a += cl[j]*W1[(144+j)*HIDDEN + c];
  CTXP[b*128+c] = a;
}

// K10: PS/PD = EMB @ [W1src|W1dst] via MFMA + 0.5*ctxp fold; bf16 u16[n][128].
__launch_bounds__(256)
__global__ void k_psd(const float* __restrict__ EMB, const u16* __restrict__ BT2,
                      const float* __restrict__ CTXP,
                      u16* __restrict__ PSu, u16* __restrict__ PDu){
  __shared__ u16 Ald[64*72];
  __shared__ u16 Bld[256*72];
  int t = threadIdx.x;
  int n0 = blockIdx.x*64;
  #pragma unroll
  for(int ii=0; ii<2; ii++){
    int c2 = ii*256 + t;
    int r = c2 >> 3, q = c2 & 7;
    const float4* src = (const float4*)(EMB + (size_t)(n0+r)*EMBED + q*8);
    float4 f0 = src[0], f1 = src[1];
    uint4 pk = make_uint4(pack_bf2(f0.x,f0.y), pack_bf2(f0.z,f0.w),
                          pack_bf2(f1.x,f1.y), pack_bf2(f1.z,f1.w));
    *(uint4*)&Ald[r*72 + q*8] = pk;
  }
  for(int i=t; i<2304; i+=256) ((uint4*)Bld)[i] = ((const uint4*)BT2)[i];
  __syncthreads();
  int w = t>>6, lane = t&63;
  int lo = lane & 15, hi = lane >> 4;
  f32x4 acc[16];
  #pragma unroll
  for(int i=0;i<16;i++) acc[i] = (f32x4){0.f,0.f,0.f,0.f};
  #pragma unroll
  for(int ks=0; ks<2; ks++){
    bf16x8 a = *(const bf16x8*)&Ald[(w*16+lo)*72 + ks*32 + hi*8];
    #pragma unroll
    for(int nt=0; nt<16; nt++){
      bf16x8 b = *(const bf16x8*)&Bld[(nt*16+lo)*72 + ks*32 + hi*8];
      acc[nt] = __builtin_amdgcn_mfma_f32_16x16x32_bf16(a, b, acc[nt], 0,0,0);
    }
  }
  int rowb = n0 + w*16 + hi*4;
  #pragma unroll
  for(int r=0;r<4;r++){
    int row = rowb + r;
    int bg = row / NN;                         // graph of this node row
    const float* cp = CTXP + bg*128;
    #pragma unroll
    for(int nt=0; nt<16; nt++){
      int dim = (nt & 7)*16 + lo;
      u16 u = bf16r(acc[nt][r] + 0.5f*cp[dim]);
      if(nt < 8) PSu[(size_t)row*HIDDEN + dim] = u;
      else       PDu[(size_t)row*HIDDEN + dim] = u;
    }
  }
}

// K11: per-edge MLP via MFMA. A = W1e^T (8 tiles, K zero-padded), B = bf16 EA (CSR order).
// D: lane holds edge lane&15, dims 16*mt + 4*(lane>>4) + r. ctxp pre-folded into PS/PD.
__launch_bounds__(256)
__global__ void k_final(const u16* __restrict__ EAb, const int* __restrict__ csrc,
                        const int* __restrict__ cdst, const int* __restrict__ ceid,
                        const u16* __restrict__ PS, const u16* __restrict__ PD,
                        const u16* __restrict__ AT1e,
                        const float* __restrict__ W2, const float* __restrict__ b2,
                        float* __restrict__ out){
  int t = threadIdx.x, w = t>>6, lane = t&63;
  int lo = lane & 15, hi = lane >> 4;
  int b = blockIdx.x & 7, c = blockIdx.x >> 3;
  int p0 = c*128 + w*32;                    // wave: 32 edges = 2 groups of 16
  bf16x8 afr[8];
  #pragma unroll
  for(int mt=0;mt<8;mt++) afr[mt] = ld8_or_zero(&AT1e[(mt*16+lo)*16 + hi*8], hi<2);
  float4 w2r[8];
  #pragma unroll
  for(int mt=0;mt<8;mt++) w2r[mt] = *(const float4*)&W2[mt*16 + hi*4];
  float bias2 = b2[0];
  const u16* PSb = PS + (size_t)b*NN*HIDDEN;
  const u16* PDb = PD + (size_t)b*NN*HIDDEN;
  #pragma unroll
  for(int g=0; g<2; g++){
    int pg = p0 + g*16;
    int s = csrc[pg + lo];
    int d = cdst[pg + lo];
    bf16x8 bfr = ld8_or_zero(&EAb[((size_t)b*EE + pg + lo)*16 + hi*8], hi<2);
    const u16* pr = PSb + (size_t)s*HIDDEN + hi*4;
    const u16* qr = PDb + (size_t)d*HIDDEN + hi*4;
    uint2 psv[8], pdv[8];
    #pragma unroll
    for(int mt=0;mt<8;mt++) psv[mt] = *(const uint2*)(pr + mt*16);
    #pragma unroll
    for(int mt=0;mt<8;mt++) pdv[mt] = *(const uint2*)(qr + mt*16);
    f32x4 acc[8];
    #pragma unroll
    for(int mt=0;mt<8;mt++){
      f32x4 z = {0.f,0.f,0.f,0.f};
      acc[mt] = __builtin_amdgcn_mfma_f32_16x16x32_bf16(afr[mt], bfr, z, 0,0,0);
    }
    float qp = 0.f;
    #pragma unroll
    for(int mt=0;mt<8;mt++){
      float h0 = acc[mt][0] + bflo(psv[mt].x) + bflo(pdv[mt].x);
      float h1 = acc[mt][1] + bfhi(psv[mt].x) + bfhi(pdv[mt].x);
      float h2 = acc[mt][2] + bflo(psv[mt].y) + bflo(pdv[mt].y);
      float h3 = acc[mt][3] + bfhi(psv[mt].y) + bfhi(pdv[mt].y);
      qp += fmaxf(h0,0.f)*w2r[mt].x + fmaxf(h1,0.f)*w2r[mt].y
          + fmaxf(h2,0.f)*w2r[mt].z + fmaxf(h3,0.f)*w2r[mt].w;
    }
    qp += __shfl_xor(qp, 16);
    qp += __shfl_xor(qp, 32);
    if(lane < 16){
      int ev = ceid[pg + lane];
      out[(size_t)b*EE + ev] = qp + bias2;
    }
  }
}

extern "C" void kernel_launch(void* const* d_in, const int* in_sizes, int n_in,
                              void* d_out, int out_size, void* d_ws, size_t ws_size,
                              hipStream_t stream) {
  const float* node_x   = (const float*)d_in[0];
  const float* edge_attr= (const float*)d_in[1];
  const int*   edge_idx = (const int*)d_in[2];
  const float* ln_ng    = (const float*)d_in[3];
  const float* ln_nb    = (const float*)d_in[4];
  const float* ln_eg    = (const float*)d_in[5];
  const float* ln_eb    = (const float*)d_in[6];
  const float* g0_W     = (const float*)d_in[7];
  const float* g0_We    = (const float*)d_in[8];
  const float* g0_asrc  = (const float*)d_in[9];
  const float* g0_adst  = (const float*)d_in[10];
  const float* g0_ae    = (const float*)d_in[11];
  const float* g0_b     = (const float*)d_in[12];
  const float* g1_W     = (const float*)d_in[13];
  const float* g1_We    = (const float*)d_in[14];
  const float* g1_asrc  = (const float*)d_in[15];
  const float* g1_adst  = (const float*)d_in[16];
  const float* g1_ae    = (const float*)d_in[17];
  const float* g1_b     = (const float*)d_in[18];
  const float* mlp_W1   = (const float*)d_in[19];
  const float* mlp_b1   = (const float*)d_in[20];
  const float* mlp_W2   = (const float*)d_in[21];
  const float* mlp_b2   = (const float*)d_in[22];
  float* out = (float*)d_out;

  // workspace layout (32-bit words)
  float* ws   = (float*)d_ws;
  float* EAp  = ws;                       // region 10,240,000 fl — EAb16 lives here
  float* E0p  = EAp  + (size_t)BE*EDGE_IN;// 640,000
  float* E1p  = E0p  + BE;                // 640,000
  float* H0   = E1p  + BE;                // region — H0u then PS
  float* HELU = H0   + (size_t)BN*HIDDEN; // region — HELUu then PD
  float* H1   = HELU + (size_t)BN*HIDDEN; // region — H1u16
  float* EMBa = H1   + (size_t)BN*EMBED;  // 2,560,000
  float* S0   = EMBa + (size_t)BN*EMBED;  // 40,000
  float* D0   = S0 + BN;
  float* S1   = D0 + BN;
  float* D1   = S1 + BN;
  float* CTX  = D1 + BN;                  // 1024 (unused)
  float* CTXP = CTX + 1024;               // 1024
  float* WAE  = CTXP + 1024;              // 32
  int* CSR_OFF = (int*)(WAE + 32);        // 5004
  int* CSR_CUR = CSR_OFF + (NN+4);        // 5000
  int* CSR_SRC = CSR_CUR + NN;            // 80000
  int* CSR_DST = CSR_SRC + EE;            // 80000
  int* CSR_EID = CSR_DST + EE;            // 80000
  int* EPOS    = CSR_EID + EE;            // 80000
  float* WS1   = (float*)(EPOS + EE);     // 128
  float* WD1   = WS1 + 128;               // 128
  u16* BT1u    = (u16*)(WD1 + 128);       // 64*136 u16
  u16* BT2u    = BT1u + 64*136;           // 256*72 u16
  float* PSUM  = (float*)(BT2u + 256*72); // 16384
  float* PMAX  = PSUM + 256*64;           // 16384
  u16* AT1e    = (u16*)(PMAX + 256*64);   // 2048 u16
  u16* EAb16      = (u16*)EAp;            // BE*16 u16
  unsigned* H0u   = (unsigned*)H0;        // BN*64 dwords
  unsigned* HELUu = (unsigned*)HELU;      // BN*64 dwords
  u16*      H1u   = (u16*)H1;             // BN*64 u16
  u16* PS = (u16*)H0;                     // bf16 [node][128] (after H0u consumed)
  u16* PD = (u16*)HELU;

  hipMemsetAsync(CSR_CUR, 0, NN*sizeof(int), stream);
  k_prep<<<17, 256, 0, stream>>>(g0_We, g0_ae, g1_We, g1_ae, g1_W, g1_asrc, g1_adst,
                                 mlp_W1, WAE, WS1, WD1, BT1u, BT2u, AT1e);
  k_count<<<(EE+255)/256, 256, 0, stream>>>(edge_idx, CSR_CUR);
  k_scan<<<1, 1024, 0, stream>>>(CSR_OFF, CSR_CUR);
  k_fill<<<(EE+255)/256, 256, 0, stream>>>(edge_idx, CSR_CUR, CSR_SRC, CSR_DST, CSR_EID, EPOS);
  k_node<<<1024, 256, 0, stream>>>(node_x, ln_ng, ln_nb, g0_W, g0_asrc, g0_adst, H0u, S0, D0);
  k_edge<<<BE/256, 256, 0, stream>>>(edge_attr, ln_eg, ln_eb, WAE, EPOS, EAb16, E0p, E1p);
  k_gat0<<<BN/4, 256, 0, stream>>>(H0u, S0, D0, E0p, CSR_OFF, CSR_SRC, g0_b, WS1, WD1, HELUu, S1, D1);
  k_h1<<<BN/64, 256, 0, stream>>>(HELUu, BT1u, H1u);
  k_gat1<<<BN/4, 256, 0, stream>>>(H1u, S1, D1, E1p, CSR_OFF, CSR_SRC, g1_b, EMBa);
  k_pool<<<256, 256, 0, stream>>>(EMBa, PSUM, PMAX);
  k_ctxp<<<BB, 128, 0, stream>>>(PSUM, PMAX, mlp_W1, mlp_b1, CTXP);
  k_psd<<<BN/64, 256, 0, stream>>>(EMBa, BT2u, CTXP, PS, PD);
  k_final<<<BE/128, 256, 0, stream>>>(EAb16, CSR_SRC, CSR_DST, CSR_EID, PS, PD, AT1e, mlp_W2, mlp_b2, out);
}

// Round 9
// 313.447 us; speedup vs baseline: 2.0608x; 1.0724x over previous
//
#include <hip/hip_runtime.h>
#include <cmath>

#define BB 8
#define NN 5000
#define EE 80000
#define NODE_IN 32
#define EDGE_IN 16
#define HIDDEN 128
#define EMBED 64
#define BN (BB*NN)     // 40000
#define BE (BB*EE)     // 640000

typedef unsigned short u16;
typedef __attribute__((ext_vector_type(8))) __bf16 bf16x8;
typedef __attribute__((ext_vector_type(4))) float f32x4;

__device__ __forceinline__ float waveSum(float v){
  #pragma unroll
  for(int o=32;o;o>>=1) v += __shfl_xor(v,o);
  return v;
}
__device__ __forceinline__ float waveMax(float v){
  #pragma unroll
  for(int o=32;o;o>>=1) v = fmaxf(v,__shfl_xor(v,o));
  return v;
}
__device__ __forceinline__ int rlanei(int v, int l){
  return __builtin_amdgcn_readlane(v, l);
}
__device__ __forceinline__ float rlanef(float v, int l){
  return __uint_as_float(__builtin_amdgcn_readlane(__float_as_uint(v), l));
}
__device__ __forceinline__ unsigned pack_bf2(float a0, float a1){
  unsigned u0 = __float_as_uint(a0), u1 = __float_as_uint(a1);
  unsigned r0 = (u0 + 0x7fffu + ((u0>>16)&1u)) >> 16;
  unsigned r1 = (u1 + 0x7fffu + ((u1>>16)&1u)) & 0xffff0000u;
  return r0 | r1;
}
__device__ __forceinline__ u16 bf16r(float x){
  unsigned u = __float_as_uint(x);
  return (u16)((u + 0x7fffu + ((u>>16)&1u)) >> 16);
}
__device__ __forceinline__ float bflo(unsigned h){ return __uint_as_float(h<<16); }
__device__ __forceinline__ float bfhi(unsigned h){ return __uint_as_float(h & 0xffff0000u); }
__device__ __forceinline__ bf16x8 ld8_or_zero(const u16* p, bool pred){
  uint4 v = pred ? *(const uint4*)p : make_uint4(0u,0u,0u,0u);
  return *(bf16x8*)&v;
}

// K1: prep — wae, w_s1/w_d1, BT1 [64][136] bf16, BT2 [256][72] bf16, AT1e [128][16] bf16
__launch_bounds__(256)
__global__ void k_prep(const float* We0, const float* ae0,
                       const float* We1, const float* ae1,
                       const float* W1g, const float* asrc1, const float* adst1,
                       const float* mlpW1,
                       float* wae, float* ws1, float* wd1,
                       u16* BT1u, u16* BT2u, u16* AT1e){
  int t = threadIdx.x;
  if(blockIdx.x == 0){
    if(t < 16){
      float a = 0.f;
      for(int k=0;k<HIDDEN;k++) a += We0[t*HIDDEN+k]*ae0[k];
      wae[t] = a;
    } else if(t < 32){
      int j = t-16;
      float a = 0.f;
      for(int k=0;k<EMBED;k++) a += We1[j*EMBED+k]*ae1[k];
      wae[16+j] = a;
    }
    if(t < 128){
      float s = 0.f, d = 0.f;
      for(int k=0;k<EMBED;k++){
        float w = W1g[t*EMBED+k];
        s += w*asrc1[k];
        d += w*adst1[k];
      }
      ws1[t] = s; wd1[t] = d;
    }
    // AT1e[out][k] = W1[(128+k)*HIDDEN + out], 128x16
    for(int i=t; i<2048; i+=256){
      int o = i >> 4, k = i & 15;
      AT1e[o*16 + k] = bf16r(mlpW1[(128+k)*HIDDEN + o]);
    }
  } else {
    #pragma unroll
    for(int ii=0; ii<6; ii++){
      int idx = (blockIdx.x-1)*1536 + ii*256 + t;
      if(idx < 8192){
        int c = idx >> 7, k = idx & 127;           // BT1[c][k] = W1g[k][c]
        BT1u[c*136 + k] = bf16r(W1g[k*EMBED + c]);
      } else {
        int i2 = idx - 8192;
        int d = i2 >> 6, j = i2 & 63;              // BT2[d][j]
        float v = (d < 128) ? mlpW1[j*HIDDEN + d] : mlpW1[(64+j)*HIDDEN + (d-128)];
        BT2u[d*72 + j] = bf16r(v);
      }
    }
  }
}

// K2: LayerNorm(node_x) -> H0 bf16-packed (lane l holds dims 2l,2l+1), s0, d0.
__launch_bounds__(256)
__global__ void k_node(const float* __restrict__ x, const float* __restrict__ g,
                       const float* __restrict__ bb, const float* __restrict__ W,
                       const float* __restrict__ asrc, const float* __restrict__ adst,
                       unsigned* __restrict__ H0u, float* __restrict__ S0o, float* __restrict__ D0o){
  int t = threadIdx.x;
  int w = t>>6, lane = t&63;
  float w0r[NODE_IN], w1r[NODE_IN];
  #pragma unroll
  for(int j=0;j<NODE_IN;j++){
    w0r[j] = W[j*HIDDEN + 2*lane];
    w1r[j] = W[j*HIDDEN + 2*lane + 1];
  }
  float gl = (lane<NODE_IN)? g[lane] : 0.f;
  float bl = (lane<NODE_IN)? bb[lane] : 0.f;
  float asl0 = asrc[2*lane], asl1 = asrc[2*lane+1];
  float adl0 = adst[2*lane], adl1 = adst[2*lane+1];
  for(int nb = blockIdx.x; nb < BN/4; nb += gridDim.x){
    int n = nb*4 + w;
    float xv = (lane<NODE_IN)? x[n*NODE_IN+lane] : 0.f;
    float s  = waveSum(xv);
    float s2 = waveSum(xv*xv);
    float mu = s*(1.f/NODE_IN);
    float var = s2*(1.f/NODE_IN) - mu*mu;
    float inv = 1.0f / sqrtf(var + 1e-5f);
    float nx = (lane<NODE_IN)? ((xv-mu)*inv*gl + bl) : 0.f;
    float a0=0.f, a1=0.f;
    #pragma unroll
    for(int j=0;j<NODE_IN;j++){
      float r = rlanef(nx, j);
      a0 += r*w0r[j];
      a1 += r*w1r[j];
    }
    H0u[(size_t)n*64 + lane] = pack_bf2(a0, a1);
    float sv = waveSum(a0*asl0 + a1*asl1);
    float dv = waveSum(a0*adl0 + a1*adl1);
    if(lane==0){ S0o[n]=sv; D0o[n]=dv; }
  }
}

// K3: LayerNorm(edge_attr) scattered into CSR position order; EA out bf16 [edge][16]
__launch_bounds__(256)
__global__ void k_edge(const float* __restrict__ ein, const float* __restrict__ g,
                       const float* __restrict__ bb, const float* __restrict__ wae,
                       const int* __restrict__ EPOS,
                       u16* __restrict__ EAb, float* __restrict__ E0p, float* __restrict__ E1p){
  int ge = blockIdx.x*256 + threadIdx.x;   // < BE exactly
  int b = ge / EE, e = ge - b*EE;
  int gp = b*EE + EPOS[e];
  float v[EDGE_IN];
  const float4* p = (const float4*)(ein + (size_t)ge*EDGE_IN);
  float4 q0=p[0], q1=p[1], q2=p[2], q3=p[3];
  v[0]=q0.x; v[1]=q0.y; v[2]=q0.z; v[3]=q0.w;
  v[4]=q1.x; v[5]=q1.y; v[6]=q1.z; v[7]=q1.w;
  v[8]=q2.x; v[9]=q2.y; v[10]=q2.z; v[11]=q2.w;
  v[12]=q3.x; v[13]=q3.y; v[14]=q3.z; v[15]=q3.w;
  float s=0.f, s2=0.f;
  #pragma unroll
  for(int j=0;j<EDGE_IN;j++){ s += v[j]; s2 += v[j]*v[j]; }
  float mu = s*(1.f/EDGE_IN);
  float var = s2*(1.f/EDGE_IN) - mu*mu;
  float inv = 1.0f / sqrtf(var + 1e-5f);
  float e0=0.f, e1=0.f;
  #pragma unroll
  for(int j=0;j<EDGE_IN;j++){
    float nv = (v[j]-mu)*inv*g[j] + bb[j];
    v[j] = nv;
    e0 += nv*wae[j];
    e1 += nv*wae[16+j];
  }
  uint4 w0 = make_uint4(pack_bf2(v[0],v[1]), pack_bf2(v[2],v[3]),
                        pack_bf2(v[4],v[5]), pack_bf2(v[6],v[7]));
  uint4 w1 = make_uint4(pack_bf2(v[8],v[9]), pack_bf2(v[10],v[11]),
                        pack_bf2(v[12],v[13]), pack_bf2(v[14],v[15]));
  uint4* q = (uint4*)&EAb[(size_t)gp*16];
  q[0] = w0; q[1] = w1;
  E0p[gp]=e0; E1p[gp]=e1;
}

// K4b: histogram of dst
__global__ void k_count(const int* __restrict__ ei, int* __restrict__ cnt){
  int e = blockIdx.x*256 + threadIdx.x;
  if(e < EE) atomicAdd(&cnt[ei[EE+e]], 1);
}

// K4c: exclusive scan of 5000 counts
__launch_bounds__(1024)
__global__ void k_scan(int* __restrict__ off, int* __restrict__ cur){
  __shared__ int part[1024];
  int t = threadIdx.x;
  int loc[5]; int s=0;
  int base = t*5;
  #pragma unroll
  for(int k=0;k<5;k++){ int idx=base+k; int c=(idx<NN)? cur[idx]:0; loc[k]=s; s+=c; }
  part[t]=s;
  __syncthreads();
  for(int o=1;o<1024;o<<=1){
    int v = (t>=o)? part[t-o] : 0;
    __syncthreads();
    part[t] += v;
    __syncthreads();
  }
  int pre = (t>0)? part[t-1] : 0;
  #pragma unroll
  for(int k=0;k<5;k++){
    int idx=base+k;
    if(idx<NN){ int o2 = pre+loc[k]; off[idx]=o2; cur[idx]=o2; }
  }
  if(t==0) off[NN] = EE;
}

// K4d: scatter edges into CSR
__global__ void k_fill(const int* __restrict__ ei, int* __restrict__ cur,
                       int* __restrict__ csrc, int* __restrict__ cdst,
                       int* __restrict__ ceid, int* __restrict__ epos){
  int e = blockIdx.x*256 + threadIdx.x;
  if(e < EE){
    int d = ei[EE+e];
    int pos = atomicAdd(&cur[d], 1);
    csrc[pos] = ei[e];
    cdst[pos] = d;
    ceid[pos] = e;
    epos[e] = pos;
  }
}

// K5: GAT0 aggregation over bf16 H0 + ELU + fused S1/D1 epilogue.
__launch_bounds__(256)
__global__ void k_gat0(const unsigned* __restrict__ H0u, const float* __restrict__ S0,
                       const float* __restrict__ D0, const float* __restrict__ E0p,
                       const int* __restrict__ off, const int* __restrict__ csrc,
                       const float* __restrict__ bias,
                       const float* __restrict__ WS1, const float* __restrict__ WD1,
                       unsigned* __restrict__ HELUu, float* __restrict__ S1o, float* __restrict__ D1o){
  int t = threadIdx.x, w = t>>6, lane = t&63;
  int b = blockIdx.x & 7, c = blockIdx.x >> 3;
  int n = c*4 + w;
  int gid = b*NN + n;
  int base = off[n], deg = off[n+1]-base;
  const float* s0b = S0 + b*NN;
  const float* e0b = E0p + b*EE;
  const unsigned* h0b = H0u + (size_t)b*NN*64;
  float dv = D0[gid];
  float acc0=0.f, acc1=0.f;
  if(deg > 0){
    if(deg <= 64){
      float lg = -INFINITY; int sidx = 0;
      if(lane < deg){
        sidx = csrc[base+lane];
        float xx = s0b[sidx] + dv + e0b[base+lane];
        lg = xx>0.f ? xx : 0.2f*xx;
      }
      float m = waveMax(lg);
      float ex = (lane<deg)? __expf(lg-m) : 0.f;
      float den = waveSum(ex);
      float al = ex / (den + 1e-16f);
      int nb8 = (deg+7)>>3;
      for(int b8=0;b8<nb8;b8++){
        int i0 = b8*8;
        int ss[8]; float aa[8]; unsigned hh[8];
        #pragma unroll
        for(int kk=0;kk<8;kk++){ ss[kk]=rlanei(sidx, i0+kk); aa[kk]=rlanef(al, i0+kk); }
        #pragma unroll
        for(int kk=0;kk<8;kk++){ hh[kk]=h0b[ss[kk]*64 + lane]; }
        #pragma unroll
        for(int kk=0;kk<8;kk++){ acc0 += aa[kk]*bflo(hh[kk]); acc1 += aa[kk]*bfhi(hh[kk]); }
      }
    } else {
      float m = -INFINITY;
      for(int i=lane;i<deg;i+=64){
        float xx = s0b[csrc[base+i]] + dv + e0b[base+i];
        xx = xx>0.f ? xx : 0.2f*xx;
        m = fmaxf(m, xx);
      }
      m = waveMax(m);
      float den = 0.f;
      for(int i=lane;i<deg;i+=64){
        float xx = s0b[csrc[base+i]] + dv + e0b[base+i];
        xx = xx>0.f ? xx : 0.2f*xx;
        den += __expf(xx-m);
      }
      den = waveSum(den) + 1e-16f;
      for(int i=0;i<deg;i++){
        int s = csrc[base+i];
        float xx = s0b[s] + dv + e0b[base+i];
        xx = xx>0.f ? xx : 0.2f*xx;
        float a = __expf(xx-m)/den;
        unsigned h = h0b[s*64 + lane];
        acc0 += a*bflo(h);
        acc1 += a*bfhi(h);
      }
    }
  }
  float2 bi = *(const float2*)&bias[2*lane];
  float v0 = acc0 + bi.x;
  float v1 = acc1 + bi.y;
  v0 = v0>0.f ? v0 : (__expf(v0)-1.f);
  v1 = v1>0.f ? v1 : (__expf(v1)-1.f);
  HELUu[(size_t)gid*64 + lane] = pack_bf2(v0, v1);
  float2 wsv = *(const float2*)&WS1[2*lane];
  float2 wdv = *(const float2*)&WD1[2*lane];
  float sv1 = waveSum(v0*wsv.x + v1*wsv.y);
  float dv1 = waveSum(v0*wdv.x + v1*wdv.y);
  if(lane==0){ S1o[gid]=sv1; D1o[gid]=dv1; }
}

// K6: H1 = HELU(40000x128 bf16) @ W1g(128x64) via MFMA. H1 out bf16 u16[n][64].
__launch_bounds__(256)
__global__ void k_h1(const unsigned* __restrict__ HELUu, const u16* __restrict__ BT1,
                     u16* __restrict__ H1u){
  __shared__ u16 Ald[64*136];
  __shared__ u16 Bld[64*136];
  int t = threadIdx.x;
  int n0 = blockIdx.x*64;
  #pragma unroll
  for(int ii=0; ii<4; ii++){
    int c2 = ii*256 + t;               // 1024 uint4 chunks
    int r = c2 >> 4, q = c2 & 15;
    *(uint4*)&Ald[r*136 + q*8] = ((const uint4*)(HELUu + (size_t)(n0+r)*64))[q];
  }
  for(int i=t; i<1088; i+=256) ((uint4*)Bld)[i] = ((const uint4*)BT1)[i];
  __syncthreads();
  int w = t>>6, lane = t&63;
  int lo = lane & 15, hi = lane >> 4;
  f32x4 acc0 = {0.f,0.f,0.f,0.f}, acc1 = acc0, acc2 = acc0, acc3 = acc0;
  #pragma unroll
  for(int ks=0; ks<4; ks++){
    bf16x8 a = *(const bf16x8*)&Ald[(w*16+lo)*136 + ks*32 + hi*8];
    bf16x8 b0 = *(const bf16x8*)&Bld[(0*16+lo)*136 + ks*32 + hi*8];
    bf16x8 b1 = *(const bf16x8*)&Bld[(1*16+lo)*136 + ks*32 + hi*8];
    bf16x8 b2 = *(const bf16x8*)&Bld[(2*16+lo)*136 + ks*32 + hi*8];
    bf16x8 b3 = *(const bf16x8*)&Bld[(3*16+lo)*136 + ks*32 + hi*8];
    acc0 = __builtin_amdgcn_mfma_f32_16x16x32_bf16(a, b0, acc0, 0,0,0);
    acc1 = __builtin_amdgcn_mfma_f32_16x16x32_bf16(a, b1, acc1, 0,0,0);
    acc2 = __builtin_amdgcn_mfma_f32_16x16x32_bf16(a, b2, acc2, 0,0,0);
    acc3 = __builtin_amdgcn_mfma_f32_16x16x32_bf16(a, b3, acc3, 0,0,0);
  }
  int rowb = n0 + w*16 + hi*4;
  #pragma unroll
  for(int r=0;r<4;r++){
    H1u[(size_t)(rowb+r)*64 +  0 + lo] = bf16r(acc0[r]);
    H1u[(size_t)(rowb+r)*64 + 16 + lo] = bf16r(acc1[r]);
    H1u[(size_t)(rowb+r)*64 + 32 + lo] = bf16r(acc2[r]);
    H1u[(size_t)(rowb+r)*64 + 48 + lo] = bf16r(acc3[r]);
  }
}

// K7: GAT1 aggregation over bf16 H1.
__launch_bounds__(256)
__global__ void k_gat1(const u16* __restrict__ H1u, const float* __restrict__ S1,
                       const float* __restrict__ D1, const float* __restrict__ E1p,
                       const int* __restrict__ off, const int* __restrict__ csrc,
                       const float* __restrict__ bias, float* __restrict__ out){
  int t = threadIdx.x, w = t>>6, lane = t&63;
  int b = blockIdx.x & 7, c = blockIdx.x >> 3;
  int n = c*4 + w;
  int gid = b*NN + n;
  int base = off[n], deg = off[n+1]-base;
  const float* s1b = S1 + b*NN;
  const float* e1b = E1p + b*EE;
  const u16* h1b = H1u + (size_t)b*NN*64;
  float dv = D1[gid];
  float acc = 0.f;
  if(deg > 0){
    if(deg <= 64){
      float lg = -INFINITY; int sidx = 0;
      if(lane < deg){
        sidx = csrc[base+lane];
        float xx = s1b[sidx] + dv + e1b[base+lane];
        lg = xx>0.f ? xx : 0.2f*xx;
      }
      float m = waveMax(lg);
      float ex = (lane<deg)? __expf(lg-m) : 0.f;
      float den = waveSum(ex);
      float al = ex / (den + 1e-16f);
      int nb8 = (deg+7)>>3;
      for(int b8=0;b8<nb8;b8++){
        int i0 = b8*8;
        int ss[8]; float aa[8]; unsigned hh[8];
        #pragma unroll
        for(int kk=0;kk<8;kk++){ ss[kk]=rlanei(sidx, i0+kk); aa[kk]=rlanef(al, i0+kk); }
        #pragma unroll
        for(int kk=0;kk<8;kk++){ hh[kk]=h1b[ss[kk]*64 + lane]; }
        #pragma unroll
        for(int kk=0;kk<8;kk++){ acc += aa[kk]*__uint_as_float(hh[kk]<<16); }
      }
    } else {
      float m = -INFINITY;
      for(int i=lane;i<deg;i+=64){
        float xx = s1b[csrc[base+i]] + dv + e1b[base+i];
        xx = xx>0.f ? xx : 0.2f*xx;
        m = fmaxf(m, xx);
      }
      m = waveMax(m);
      float den = 0.f;
      for(int i=lane;i<deg;i+=64){
        float xx = s1b[csrc[base+i]] + dv + e1b[base+i];
        xx = xx>0.f ? xx : 0.2f*xx;
        den += __expf(xx-m);
      }
      den = waveSum(den) + 1e-16f;
      for(int i=0;i<deg;i++){
        int s = csrc[base+i];
        float xx = s1b[s] + dv + e1b[base+i];
        xx = xx>0.f ? xx : 0.2f*xx;
        float a = __expf(xx-m)/den;
        acc += a*__uint_as_float(((unsigned)h1b[s*64 + lane])<<16);
      }
    }
  }
  out[(size_t)gid*EMBED + lane] = acc + bias[lane];
}

// K8: per-graph mean/max pooling partials. 32 blocks per graph.
__launch_bounds__(256)
__global__ void k_pool(const float* __restrict__ EMBp, float* __restrict__ PSUM,
                       float* __restrict__ PMAX){
  int blk = blockIdx.x & 31, b = blockIdx.x >> 5;
  int t = threadIdx.x;
  int dim = t & 63, chunk = t >> 6;
  int n0 = blk*157, n1 = n0+157 < NN ? n0+157 : NN;
  float sm = 0.f, mx = -INFINITY;
  for(int n=n0+chunk; n<n1; n+=4){
    float v = EMBp[((size_t)(b*NN+n))*EMBED + dim];
    sm += v; mx = fmaxf(mx, v);
  }
  __shared__ float ssum[256], smax[256];
  ssum[t]=sm; smax[t]=mx;
  __syncthreads();
  if(t < 64){
    float S = ssum[t]+ssum[t+64]+ssum[t+128]+ssum[t+192];
    float M = fmaxf(fmaxf(smax[t],smax[t+64]), fmaxf(smax[t+128],smax[t+192]));
    PSUM[(b*32+blk)*64 + t] = S;
    PMAX[(b*32+blk)*64 + t] = M;
  }
}

// K9: reduce partials -> ctx; ctx_proj[b] = b1 + ctx[b] @ W1[144:272]
__launch_bounds__(128)
__global__ void k_ctxp(const float* __restrict__ PSUM, const float* __restrict__ PMAX,
                       const float* __restrict__ W1, const float* __restrict__ b1,
                       float* __restrict__ CTXP){
  int b = blockIdx.x, c = threadIdx.x;
  __shared__ float cl[128];
  if(c < 64){
    float S = 0.f;
    for(int k=0;k<32;k++) S += PSUM[(b*32+k)*64 + c];
    cl[c] = S*(1.f/NN);
  } else {
    float M = -INFINITY;
    for(int k=0;k<32;k++) M = fmaxf(M, PMAX[(b*32+k)*64 + (c-64)]);
    cl[c] = M;
  }
  __syncthreads();
  float a = b1[c];
  for(int j=0;j<128;j++) a += cl[j]*W1[(144+j)*HIDDEN + c];
  CTXP[b*128+c] = a;
}

// K10: PS/PD = EMB @ [W1src|W1dst] via MFMA + 0.5*ctxp fold; bf16 u16[n][128].
__launch_bounds__(256)
__global__ void k_psd(const float* __restrict__ EMB, const u16* __restrict__ BT2,
                      const float* __restrict__ CTXP,
                      u16* __restrict__ PSu, u16* __restrict__ PDu){
  __shared__ u16 Ald[64*72];
  __shared__ u16 Bld[256*72];
  int t = threadIdx.x;
  int n0 = blockIdx.x*64;
  #pragma unroll
  for(int ii=0; ii<2; ii++){
    int c2 = ii*256 + t;
    int r = c2 >> 3, q = c2 & 7;
    const float4* src = (const float4*)(EMB + (size_t)(n0+r)*EMBED + q*8);
    float4 f0 = src[0], f1 = src[1];
    uint4 pk = make_uint4(pack_bf2(f0.x,f0.y), pack_bf2(f0.z,f0.w),
                          pack_bf2(f1.x,f1.y), pack_bf2(f1.z,f1.w));
    *(uint4*)&Ald[r*72 + q*8] = pk;
  }
  for(int i=t; i<2304; i+=256) ((uint4*)Bld)[i] = ((const uint4*)BT2)[i];
  __syncthreads();
  int w = t>>6, lane = t&63;
  int lo = lane & 15, hi = lane >> 4;
  f32x4 acc[16];
  #pragma unroll
  for(int i=0;i<16;i++) acc[i] = (f32x4){0.f,0.f,0.f,0.f};
  #pragma unroll
  for(int ks=0; ks<2; ks++){
    bf16x8 a = *(const bf16x8*)&Ald[(w*16+lo)*72 + ks*32 + hi*8];
    #pragma unroll
    for(int nt=0; nt<16; nt++){
      bf16x8 b = *(const bf16x8*)&Bld[(nt*16+lo)*72 + ks*32 + hi*8];
      acc[nt] = __builtin_amdgcn_mfma_f32_16x16x32_bf16(a, b, acc[nt], 0,0,0);
    }
  }
  int rowb = n0 + w*16 + hi*4;
  #pragma unroll
  for(int r=0;r<4;r++){
    int row = rowb + r;
    int bg = row / NN;                         // graph of this node row
    const float* cp = CTXP + bg*128;
    #pragma unroll
    for(int nt=0; nt<16; nt++){
      int dim = (nt & 7)*16 + lo;
      u16 u = bf16r(acc[nt][r] + 0.5f*cp[dim]);
      if(nt < 8) PSu[(size_t)row*HIDDEN + dim] = u;
      else       PDu[(size_t)row*HIDDEN + dim] = u;
    }
  }
}

// K11: per-edge MLP via MFMA. 16 edges/wave. PS rows staged cooperatively
// into wave-local LDS (full-line coalesced); PD direct gather (CSR dedup).
__launch_bounds__(256)
__global__ void k_final(const u16* __restrict__ EAb, const int* __restrict__ csrc,
                        const int* __restrict__ cdst, const int* __restrict__ ceid,
                        const u16* __restrict__ PS, const u16* __restrict__ PD,
                        const u16* __restrict__ AT1e,
                        const float* __restrict__ W2, const float* __restrict__ b2,
                        float* __restrict__ out){
  __shared__ unsigned ldsPS[4][16][66];       // wave, edge-row, 64 dwords + 2 pad
  int t = threadIdx.x, w = t>>6, lane = t&63;
  int lo = lane & 15, hi = lane >> 4;
  int b = blockIdx.x & 7, c = blockIdx.x >> 3;
  int pg = c*64 + w*16;                       // 16 edges per wave
  bf16x8 afr[8];
  #pragma unroll
  for(int mt=0;mt<8;mt++) afr[mt] = ld8_or_zero(&AT1e[(mt*16+lo)*16 + hi*8], hi<2);
  float4 w2r[8];
  #pragma unroll
  for(int mt=0;mt<8;mt++) w2r[mt] = *(const float4*)&W2[mt*16 + hi*4];
  float bias2 = b2[0];
  const unsigned* PSb32 = (const unsigned*)(PS + (size_t)b*NN*HIDDEN);
  const u16* PDb = PD + (size_t)b*NN*HIDDEN;
  int s = csrc[pg + lo];
  int d = cdst[pg + lo];
  // cooperative stage of 16 PS rows (256B each, fully coalesced)
  unsigned vs[16];
  #pragma unroll
  for(int k=0;k<16;k++){
    int sk = rlanei(s, k);
    vs[k] = PSb32[(size_t)sk*64 + lane];
  }
  // direct PD gather (CSR-ordered: few distinct rows, coalescer dedups)
  const u16* qr = PDb + (size_t)d*HIDDEN + hi*4;
  uint2 pdv[8];
  #pragma unroll
  for(int mt=0;mt<8;mt++) pdv[mt] = *(const uint2*)(qr + mt*16);
  bf16x8 bfr = ld8_or_zero(&EAb[((size_t)b*EE + pg + lo)*16 + hi*8], hi<2);
  #pragma unroll
  for(int k=0;k<16;k++) ldsPS[w][k][lane] = vs[k];
  f32x4 acc[8];
  #pragma unroll
  for(int mt=0;mt<8;mt++){
    f32x4 z = {0.f,0.f,0.f,0.f};
    acc[mt] = __builtin_amdgcn_mfma_f32_16x16x32_bf16(afr[mt], bfr, z, 0,0,0);
  }
  float qp = 0.f;
  #pragma unroll
  for(int mt=0;mt<8;mt++){
    uint2 psv = *(const uint2*)&ldsPS[w][lo][hi*2 + mt*8];
    float h0 = acc[mt][0] + bflo(psv.x) + bflo(pdv[mt].x);
    float h1 = acc[mt][1] + bfhi(psv.x) + bfhi(pdv[mt].x);
    float h2 = acc[mt][2] + bflo(psv.y) + bflo(pdv[mt].y);
    float h3 = acc[mt][3] + bfhi(psv.y) + bfhi(pdv[mt].y);
    qp += fmaxf(h0,0.f)*w2r[mt].x + fmaxf(h1,0.f)*w2r[mt].y
        + fmaxf(h2,0.f)*w2r[mt].z + fmaxf(h3,0.f)*w2r[mt].w;
  }
  qp += __shfl_xor(qp, 16);
  qp += __shfl_xor(qp, 32);
  if(lane < 16){
    int ev = ceid[pg + lane];
    out[(size_t)b*EE + ev] = qp + bias2;
  }
}

extern "C" void kernel_launch(void* const* d_in, const int* in_sizes, int n_in,
                              void* d_out, int out_size, void* d_ws, size_t ws_size,
                              hipStream_t stream) {
  const float* node_x   = (const float*)d_in[0];
  const float* edge_attr= (const float*)d_in[1];
  const int*   edge_idx = (const int*)d_in[2];
  const float* ln_ng    = (const float*)d_in[3];
  const float* ln_nb    = (const float*)d_in[4];
  const float* ln_eg    = (const float*)d_in[5];
  const float* ln_eb    = (const float*)d_in[6];
  const float* g0_W     = (const float*)d_in[7];
  const float* g0_We    = (const float*)d_in[8];
  const float* g0_asrc  = (const float*)d_in[9];
  const float* g0_adst  = (const float*)d_in[10];
  const float* g0_ae    = (const float*)d_in[11];
  const float* g0_b     = (const float*)d_in[12];
  const float* g1_W     = (const float*)d_in[13];
  const float* g1_We    = (const float*)d_in[14];
  const float* g1_asrc  = (const float*)d_in[15];
  const float* g1_adst  = (const float*)d_in[16];
  const float* g1_ae    = (const float*)d_in[17];
  const float* g1_b     = (const float*)d_in[18];
  const float* mlp_W1   = (const float*)d_in[19];
  const float* mlp_b1   = (const float*)d_in[20];
  const float* mlp_W2   = (const float*)d_in[21];
  const float* mlp_b2   = (const float*)d_in[22];
  float* out = (float*)d_out;

  // workspace layout (32-bit words)
  float* ws   = (float*)d_ws;
  float* EAp  = ws;                       // region — EAb16
  float* E0p  = EAp  + (size_t)BE*EDGE_IN;// 640,000
  float* E1p  = E0p  + BE;                // 640,000
  float* H0   = E1p  + BE;                // region — H0u then PS
  float* HELU = H0   + (size_t)BN*HIDDEN; // region — HELUu then PD
  float* H1   = HELU + (size_t)BN*HIDDEN; // region — H1u16
  float* EMBa = H1   + (size_t)BN*EMBED;  // 2,560,000
  float* S0   = EMBa + (size_t)BN*EMBED;  // 40,000
  float* D0   = S0 + BN;
  float* S1   = D0 + BN;
  float* D1   = S1 + BN;
  float* CTX  = D1 + BN;                  // 1024 (unused)
  float* CTXP = CTX + 1024;               // 1024
  float* WAE  = CTXP + 1024;              // 32
  int* CSR_OFF = (int*)(WAE + 32);        // 5004
  int* CSR_CUR = CSR_OFF + (NN+4);        // 5000
  int* CSR_SRC = CSR_CUR + NN;            // 80000
  int* CSR_DST = CSR_SRC + EE;            // 80000
  int* CSR_EID = CSR_DST + EE;            // 80000
  int* EPOS    = CSR_EID + EE;            // 80000
  float* WS1   = (float*)(EPOS + EE);     // 128
  float* WD1   = WS1 + 128;               // 128
  u16* BT1u    = (u16*)(WD1 + 128);       // 64*136 u16
  u16* BT2u    = BT1u + 64*136;           // 256*72 u16
  float* PSUM  = (float*)(BT2u + 256*72); // 16384
  float* PMAX  = PSUM + 256*64;           // 16384
  u16* AT1e    = (u16*)(PMAX + 256*64);   // 2048 u16
  u16* EAb16      = (u16*)EAp;            // BE*16 u16
  unsigned* H0u   = (unsigned*)H0;        // BN*64 dwords
  unsigned* HELUu = (unsigned*)HELU;      // BN*64 dwords
  u16*      H1u   = (u16*)H1;             // BN*64 u16
  u16* PS = (u16*)H0;                     // bf16 [node][128] (after H0u consumed)
  u16* PD = (u16*)HELU;

  hipMemsetAsync(CSR_CUR, 0, NN*sizeof(int), stream);
  k_prep<<<17, 256, 0, stream>>>(g0_We, g0_ae, g1_We, g1_ae, g1_W, g1_asrc, g1_adst,
                                 mlp_W1, WAE, WS1, WD1, BT1u, BT2u, AT1e);
  k_count<<<(EE+255)/256, 256, 0, stream>>>(edge_idx, CSR_CUR);
  k_scan<<<1, 1024, 0, stream>>>(CSR_OFF, CSR_CUR);
  k_fill<<<(EE+255)/256, 256, 0, stream>>>(edge_idx, CSR_CUR, CSR_SRC, CSR_DST, CSR_EID, EPOS);
  k_node<<<1024, 256, 0, stream>>>(node_x, ln_ng, ln_nb, g0_W, g0_asrc, g0_adst, H0u, S0, D0);
  k_edge<<<BE/256, 256, 0, stream>>>(edge_attr, ln_eg, ln_eb, WAE, EPOS, EAb16, E0p, E1p);
  k_gat0<<<BN/4, 256, 0, stream>>>(H0u, S0, D0, E0p, CSR_OFF, CSR_SRC, g0_b, WS1, WD1, HELUu, S1, D1);
  k_h1<<<BN/64, 256, 0, stream>>>(HELUu, BT1u, H1u);
  k_gat1<<<BN/4, 256, 0, stream>>>(H1u, S1, D1, E1p, CSR_OFF, CSR_SRC, g1_b, EMBa);
  k_pool<<<256, 256, 0, stream>>>(EMBa, PSUM, PMAX);
  k_ctxp<<<BB, 128, 0, stream>>>(PSUM, PMAX, mlp_W1, mlp_b1, CTXP);
  k_psd<<<BN/64, 256, 0, stream>>>(EMBa, BT2u, CTXP, PS, PD);
  k_final<<<BE/64, 256, 0, stream>>>(EAb16, CSR_SRC, CSR_DST, CSR_EID, PS, PD, AT1e, mlp_W2, mlp_b2, out);
}